// Round 15
// baseline (329.798 us; speedup 1.0000x reference)
//
#include <hip/hip_runtime.h>

#define DD 256
#define HH 8
#define CC 32

typedef __attribute__((ext_vector_type(8))) short short8;
typedef __attribute__((ext_vector_type(4))) float f32x4;

static __device__ __forceinline__ unsigned short f2b(float f){
  unsigned u = __float_as_uint(f);
  u = u + 0x7FFFu + ((u >> 16) & 1u);          // RNE
  return (unsigned short)(u >> 16);
}
static __device__ __forceinline__ float b2f(unsigned short s){
  return __uint_as_float(((unsigned)s) << 16);
}

// global->LDS direct DMA: 16B/lane, wave-uniform LDS base, lane l lands at base+l*16.
static __device__ __forceinline__ void gload16(const void* g, void* l){
  using gpt = const __attribute__((address_space(1))) unsigned int*;
  using lpt = __attribute__((address_space(3))) unsigned int*;
  __builtin_amdgcn_global_load_lds((gpt)(unsigned long long)g, (lpt)(unsigned long long)l, 16, 0, 0);
}

// ---------------- utility ----------------
__global__ void k_zero_i(int* p, int n){ int i=blockIdx.x*blockDim.x+threadIdx.x; if(i<n) p[i]=0; }

// ---------------- CSR build ----------------
__global__ void k_count(const int* __restrict__ dstE, int E, int N, int* cnt){
  int e=blockIdx.x*blockDim.x+threadIdx.x;
  if(e<E+N){ int d=(e<E)? dstE[e] : (e-E); atomicAdd(&cnt[d],1); }
}

__global__ __launch_bounds__(1024) void k_scan(const int* __restrict__ cnt, int N, int* row_off, int* cursor){
  __shared__ int part[1024];
  int t=threadIdx.x;
  int chunk=(N+1023)>>10;
  int s=0;
  for(int j=0;j<chunk;j++){ int i=t*chunk+j; if(i<N) s+=cnt[i]; }
  part[t]=s; __syncthreads();
  for(int off=1; off<1024; off<<=1){
    int v=(t>=off)? part[t-off]:0;
    __syncthreads();
    part[t]+=v;
    __syncthreads();
  }
  int run=(t==0)?0:part[t-1];
  for(int j=0;j<chunk;j++){ int i=t*chunk+j; if(i<N){ row_off[i]=run; cursor[i]=run; run+=cnt[i]; } }
  if(t==1023) row_off[N]=part[1023];
}

// fill CSR: scatter src, edge-type AND edge-attr into CSR (dst-sorted) order.
__global__ void k_fill(const int* __restrict__ srcE, const int* __restrict__ dstE,
                       const float* __restrict__ ea, const int* __restrict__ et,
                       int E, int N, int* cursor,
                       int* esrc, int* etP, float* eaP){
  int e=blockIdx.x*blockDim.x+threadIdx.x;
  if(e>=E+N) return;
  int s,d,ty;
  float4 q0,q1,q2,q3;
  if(e<E){
    s=srcE[e]; d=dstE[e]; ty=et[e];
    q0=*(const float4*)&ea[(size_t)e*16+0];
    q1=*(const float4*)&ea[(size_t)e*16+4];
    q2=*(const float4*)&ea[(size_t)e*16+8];
    q3=*(const float4*)&ea[(size_t)e*16+12];
  }else{
    s=e-E; d=s; ty=6;
    q0=q1=q2=q3=make_float4(1.f,1.f,1.f,1.f);
  }
  int pos=atomicAdd(&cursor[d],1);
  esrc[pos]=s; etP[pos]=ty;
  float* o=&eaP[(size_t)pos*16];
  *(float4*)(o+0)=q0; *(float4*)(o+4)=q1; *(float4*)(o+8)=q2; *(float4*)(o+12)=q3;
}

// ---------------- 4x weight transpose + bf16 convert in one launch ----------------
__global__ void k_cvt_wT4(const float* __restrict__ W0, const float* __restrict__ W1,
                          const float* __restrict__ W2, const float* __restrict__ W3,
                          unsigned short* __restrict__ T0, unsigned short* __restrict__ T1,
                          unsigned short* __restrict__ T2, unsigned short* __restrict__ T3){
  int m=blockIdx.y, c=blockIdx.x, k=threadIdx.x;
  const float* W = (m==0)?W0:(m==1)?W1:(m==2)?W2:W3;
  unsigned short* T = (m==0)?T0:(m==1)?T1:(m==2)?T2:T3;
  T[(size_t)c*DD+k] = f2b(W[(size_t)k*DD+c]);
}

// ---------------- folded logit weights (both layers) ----------------
__global__ void k_pre2(const float* __restrict__ Wd1, const float* __restrict__ as1,
                       const float* __restrict__ We1, const float* __restrict__ ae1,
                       const float* __restrict__ te1,
                       const float* __restrict__ Wd2, const float* __restrict__ as2,
                       const float* __restrict__ We2, const float* __restrict__ ae2,
                       const float* __restrict__ te2,
                       float* wd_as1, float* v_e1, float* t_a1,
                       float* wd_as2, float* v_e2, float* t_a2){
  int L=blockIdx.x;
  const float* Wd=L?Wd2:Wd1; const float* as_=L?as2:as1;
  const float* We=L?We2:We1; const float* ae=L?ae2:ae1; const float* te=L?te2:te1;
  float* wd_as=L?wd_as2:wd_as1; float* v_e=L?v_e2:v_e1; float* t_a=L?t_a2:t_a1;
  int t=threadIdx.x;
  for(int idx=t; idx<DD*HH; idx+=256){
    int k=idx>>3, h=idx&7;
    const float* w=&Wd[k*DD+h*CC]; const float* a=&as_[h*CC];
    float s=0;
    #pragma unroll
    for(int c=0;c<CC;c++) s+=w[c]*a[c];
    wd_as[idx]=s;
  }
  for(int idx=t; idx<16*HH; idx+=256){
    int k=idx>>3, h=idx&7;
    const float* w=&We[k*DD+h*CC]; const float* a=&ae[h*CC];
    float s=0;
    #pragma unroll
    for(int c=0;c<CC;c++) s+=w[c]*a[c];
    v_e[idx]=s;
  }
  for(int idx=t; idx<7*HH; idx+=256){
    int k=idx>>3, h=idx&7;
    const float* w=&te[k*DD+h*CC]; const float* a=&ae[h*CC];
    float s=0;
    #pragma unroll
    for(int c=0;c<CC;c++) s+=w[c]*a[c];
    t_a[idx]=s;
  }
}

// ---------------- x -> bf16 + a_i (wave-per-row, float4, shuffle reduce) ----------------
#define NB_BA 1024
__global__ __launch_bounds__(256) void k_cvt_x2(const float* __restrict__ xin, const float* __restrict__ wd_as,
                         unsigned short* __restrict__ xb, float* __restrict__ a_i, int N){
  int b=blockIdx.x, tid=threadIdx.x, wv=tid>>6, l=tid&63;
  int c0=4*l;
  float wa[4][8];
  #pragma unroll
  for(int j=0;j<4;j++)
    #pragma unroll
    for(int h=0;h<8;h++) wa[j][h]=wd_as[(c0+j)*8+h];
  for(int n=b*4+wv; n<N; n+=NB_BA*4){
    float4 v=*(const float4*)&xin[(size_t)n*DD+c0];
    ushort4 xo; xo.x=f2b(v.x); xo.y=f2b(v.y); xo.z=f2b(v.z); xo.w=f2b(v.w);
    *(ushort4*)&xb[(size_t)n*DD+c0]=xo;
    float ai[8];
    #pragma unroll
    for(int h=0;h<8;h++) ai[h]=v.x*wa[0][h]+v.y*wa[1][h]+v.z*wa[2][h]+v.w*wa[3][h];
    #pragma unroll
    for(int off=1;off<64;off<<=1){
      #pragma unroll
      for(int h=0;h<8;h++) ai[h]+=__shfl_xor(ai[h],off);
    }
    if(l==0){
      float4 A; A.x=ai[0];A.y=ai[1];A.z=ai[2];A.w=ai[3];
      float4 B; B.x=ai[4];B.y=ai[5];B.z=ai[6];B.w=ai[7];
      *(float4*)&a_i[(size_t)n*HH]=A;
      *(float4*)&a_i[(size_t)n*HH+4]=B;
    }
  }
}

// ---------------- GEMM1: C[N,256]=A@B, bf16 out + fused a_j ----------------
template<bool AJ>
__global__ __launch_bounds__(256) void k_gemm1(const unsigned short* __restrict__ A,
                                               const unsigned short* __restrict__ Bt,
                                               const float* __restrict__ ad, float* __restrict__ a_j,
                                               unsigned short* __restrict__ Cout, int N){
  __shared__ char lds[2*12288];   // per buf: A 64x32 (4KB) + B 128x32 (8KB)
  int tid=threadIdx.x;
  int w=tid>>6, l=tid&63;
  int row0=blockIdx.y*64, col0=blockIdx.x*128;

  int lr=l>>2;
  int kc=(l&3)^((l>>3)&3);
  const unsigned short* ga  = &A [(size_t)(row0+16*w+lr)*DD + kc*8];
  const unsigned short* gb0 = &Bt[(size_t)(col0+32*w+lr)*DD + kc*8];
  const unsigned short* gb1 = &Bt[(size_t)(col0+32*w+16+lr)*DD + kc*8];
  int laoff =      w*1024;
  int lboff0=4096+(32*w)*64;
  int lboff1=4096+(32*w+16)*64;

  int x15=l&15;
  int lp=x15*64 + ((l>>4)^((x15>>1)&3))*16;

  f32x4 acc[4][2];
  #pragma unroll
  for(int i=0;i<4;i++){ acc[i][0]=(f32x4)0.f; acc[i][1]=(f32x4)0.f; }

  gload16(ga,  lds+laoff);
  gload16(gb0, lds+lboff0);
  gload16(gb1, lds+lboff1);
  __syncthreads();
  int cur=0;
  for(int kt=0;kt<DD;kt+=32){
    int nxt=cur^1;
    if(kt+32<DD){
      gload16(ga +kt+32, lds+nxt*12288+laoff);
      gload16(gb0+kt+32, lds+nxt*12288+lboff0);
      gload16(gb1+kt+32, lds+nxt*12288+lboff1);
    }
    char* base=lds+cur*12288;
    short8 af[4], bf[2];
    #pragma unroll
    for(int mf=0;mf<4;mf++) af[mf]=*(short8*)(base + mf*1024 + lp);
    #pragma unroll
    for(int nf=0;nf<2;nf++) bf[nf]=*(short8*)(base + 4096 + (32*w+16*nf)*64 + lp);
    #pragma unroll
    for(int mf=0;mf<4;mf++)
      #pragma unroll
      for(int nf=0;nf<2;nf++)
        acc[mf][nf]=__builtin_amdgcn_mfma_f32_16x16x32_bf16(af[mf],bf[nf],acc[mf][nf],0,0,0);
    __syncthreads();
    cur=nxt;
  }

  int lcol=x15, lrow4=(l>>4)*4;
  float ad0=0.f, ad1=0.f;
  if(AJ){ ad0=ad[col0+32*w+lcol]; ad1=ad[col0+32*w+16+lcol]; }
  int head=(col0>>5)+w;
  #pragma unroll
  for(int mf=0;mf<4;mf++){
    #pragma unroll
    for(int nf=0;nf<2;nf++){
      int col=col0 + 32*w + 16*nf + lcol;
      #pragma unroll
      for(int rr=0;rr<4;rr++){
        int row=row0 + 16*mf + lrow4 + rr;
        if(row<N) Cout[(size_t)row*DD+col]=f2b(acc[mf][nf][rr]);
      }
    }
    if(AJ){
      #pragma unroll
      for(int rr=0;rr<4;rr++){
        float t=acc[mf][0][rr]*ad0 + acc[mf][1][rr]*ad1;
        t+=__shfl_xor(t,1); t+=__shfl_xor(t,2);
        t+=__shfl_xor(t,4); t+=__shfl_xor(t,8);
        int row=row0 + 16*mf + lrow4 + rr;
        if(x15==0 && row<N) a_j[(size_t)row*HH+head]=t;
      }
    }
  }
}

// ---------------- GEMM2 fused: bias + LayerNorm + residual + BN partials --------
__global__ __launch_bounds__(256) void k_gemm_ln(const unsigned short* __restrict__ A,
                                                 const unsigned short* __restrict__ Bt,
                                                 const float* __restrict__ bo, const float* __restrict__ bvec,
                                                 const float* __restrict__ xin,
                                                 const float* __restrict__ lg, const float* __restrict__ lb,
                                                 float* __restrict__ hout,
                                                 float* __restrict__ psum, float* __restrict__ psq, int N){
  __shared__ char lds[2*18432];   // per buf: A 32x32 (2KB) + B 256x32 (16KB)
  int tid=threadIdx.x;
  int w=tid>>6, l=tid&63;
  int row0=blockIdx.x*32;

  int lr=l>>2;
  int kc=(l&3)^((l>>3)&3);
  const unsigned short* ga = &A[(size_t)(row0+16*w+lr)*DD + kc*8];   // waves 0,1 only
  const unsigned short* gb0=&Bt[(size_t)(64*w   +lr)*DD + kc*8];
  const unsigned short* gb1=&Bt[(size_t)(64*w+16+lr)*DD + kc*8];
  const unsigned short* gb2=&Bt[(size_t)(64*w+32+lr)*DD + kc*8];
  const unsigned short* gb3=&Bt[(size_t)(64*w+48+lr)*DD + kc*8];
  int laoff =      w*1024;
  int lboff0=2048+(64*w   )*64;
  int lboff1=2048+(64*w+16)*64;
  int lboff2=2048+(64*w+32)*64;
  int lboff3=2048+(64*w+48)*64;

  int x15=l&15;
  int lp=x15*64 + ((l>>4)^((x15>>1)&3))*16;

  f32x4 acc[2][4];
  #pragma unroll
  for(int i=0;i<2;i++)
    #pragma unroll
    for(int j=0;j<4;j++) acc[i][j]=(f32x4)0.f;

  if(w<2) gload16(ga, lds+laoff);
  gload16(gb0, lds+lboff0);
  gload16(gb1, lds+lboff1);
  gload16(gb2, lds+lboff2);
  gload16(gb3, lds+lboff3);
  __syncthreads();
  int cur=0;
  for(int kt=0;kt<DD;kt+=32){
    int nxt=cur^1;
    if(kt+32<DD){
      char* nb=lds+nxt*18432;
      if(w<2) gload16(ga+kt+32, nb+laoff);
      gload16(gb0+kt+32, nb+lboff0);
      gload16(gb1+kt+32, nb+lboff1);
      gload16(gb2+kt+32, nb+lboff2);
      gload16(gb3+kt+32, nb+lboff3);
    }
    char* base=lds+cur*18432;
    short8 af[2], bf[4];
    #pragma unroll
    for(int mf=0;mf<2;mf++) af[mf]=*(short8*)(base + mf*1024 + lp);
    #pragma unroll
    for(int nf=0;nf<4;nf++) bf[nf]=*(short8*)(base + 2048 + (64*w+16*nf)*64 + lp);
    #pragma unroll
    for(int mf=0;mf<2;mf++)
      #pragma unroll
      for(int nf=0;nf<4;nf++)
        acc[mf][nf]=__builtin_amdgcn_mfma_f32_16x16x32_bf16(af[mf],bf[nf],acc[mf][nf],0,0,0);
    __syncthreads();
    cur=nxt;
  }

  // ---- epilogue ----
  int lrow4=(l>>4)*4;
  float lgv[4], lbv[4];
  #pragma unroll
  for(int nf=0;nf<4;nf++){
    int col=64*w+16*nf+x15;
    float badd=bo[col]+bvec[col];
    lgv[nf]=lg[col]; lbv[nf]=lb[col];
    #pragma unroll
    for(int mf=0;mf<2;mf++)
      #pragma unroll
      for(int rr=0;rr<4;rr++) acc[mf][nf][rr]+=badd;
  }
  __syncthreads();   // GEMM LDS dead; repurpose
  float* rs   =(float*)lds;            // [4][32]
  float* rq   =(float*)(lds+512);      // [4][32]
  float* mus  =(float*)(lds+1024);     // [32]
  float* rstds=(float*)(lds+1152);     // [32]
  #pragma unroll
  for(int mf=0;mf<2;mf++){
    #pragma unroll
    for(int rr=0;rr<4;rr++){
      float t=acc[mf][0][rr]+acc[mf][1][rr]+acc[mf][2][rr]+acc[mf][3][rr];
      float q=acc[mf][0][rr]*acc[mf][0][rr]+acc[mf][1][rr]*acc[mf][1][rr]
             +acc[mf][2][rr]*acc[mf][2][rr]+acc[mf][3][rr]*acc[mf][3][rr];
      t+=__shfl_xor(t,1); q+=__shfl_xor(q,1);
      t+=__shfl_xor(t,2); q+=__shfl_xor(q,2);
      t+=__shfl_xor(t,4); q+=__shfl_xor(q,4);
      t+=__shfl_xor(t,8); q+=__shfl_xor(q,8);
      if(x15==0){
        int row=16*mf+lrow4+rr;
        rs[w*32+row]=t; rq[w*32+row]=q;
      }
    }
  }
  __syncthreads();
  if(tid<32){
    float S=rs[tid]+rs[32+tid]+rs[64+tid]+rs[96+tid];
    float Q=rq[tid]+rq[32+tid]+rq[64+tid]+rq[96+tid];
    float mu=S*(1.f/DD);
    float var=Q*(1.f/DD)-mu*mu;
    mus[tid]=mu;
    rstds[tid]=rsqrtf(var+1e-5f);
  }
  __syncthreads();
  float cps[4]={0.f,0.f,0.f,0.f}, cqs[4]={0.f,0.f,0.f,0.f};
  #pragma unroll
  for(int mf=0;mf<2;mf++){
    #pragma unroll
    for(int rr=0;rr<4;rr++){
      int row=16*mf+lrow4+rr;
      int grow=row0+row;
      bool ok=(grow<N);
      float mu=mus[row], rstd=rstds[row];
      #pragma unroll
      for(int nf=0;nf<4;nf++){
        int col=64*w+16*nf+x15;
        float h=0.f;
        if(ok){
          h=(acc[mf][nf][rr]-mu)*rstd*lgv[nf]+lbv[nf]+xin[(size_t)grow*DD+col];
          hout[(size_t)grow*DD+col]=h;
        }
        cps[nf]+=h; cqs[nf]+=h*h;
      }
    }
  }
  #pragma unroll
  for(int nf=0;nf<4;nf++){
    cps[nf]+=__shfl_xor(cps[nf],16); cqs[nf]+=__shfl_xor(cqs[nf],16);
    cps[nf]+=__shfl_xor(cps[nf],32); cqs[nf]+=__shfl_xor(cqs[nf],32);
  }
  if(l<16){
    #pragma unroll
    for(int nf=0;nf<4;nf++){
      int col=64*w+16*nf+l;
      psum[(size_t)blockIdx.x*DD+col]=cps[nf];
      psq [(size_t)blockIdx.x*DD+col]=cqs[nf];
    }
  }
}

// ---------------- FUSED edge-logit + online softmax + aggregation: TWO WAVES PER NODE ----
// Block = 4 waves = 2 nodes. Wave half ph processes chunks base=ph*8, step 16 with an
// independent online-softmax state; halves merge once via LDS (exact flash-merge).
__global__ __launch_bounds__(256) void k_agg(const int* __restrict__ row_off,
                      const int* __restrict__ esrc, const int* __restrict__ etP,
                      const float* __restrict__ eaP,
                      const float* __restrict__ a_i, const float* __restrict__ a_j,
                      const float* __restrict__ v_e, const float* __restrict__ t_a,
                      const unsigned short* __restrict__ ysb, unsigned short* __restrict__ aggb, int N){
  __shared__ float comb[2][6][64];    // [pair][field][lane] from half 1; 3KB
  int wv=threadIdx.x>>6, l=threadIdx.x&63;
  int pr=wv>>1, ph=wv&1;
  int n=blockIdx.x*2+pr;
  int slotL=l>>3, headL=l&7;
  int ghead=l>>3;
  float m=-3e38f, ssum=0.f, acc0=0.f, acc1=0.f, acc2=0.f, acc3=0.f;
  if(n<N){
    int beg=row_off[n], deg=row_off[n+1]-beg;
    float veh[16];
    #pragma unroll
    for(int k=0;k<16;k++) veh[k]=v_e[k*8+headL];
    float aih=a_i[(size_t)n*HH+headL];
    for(int base=ph*8; base<deg; base+=16){
      int i=base+slotL;
      bool ok=(i<deg);
      int ic=ok?i:(deg-1);
      size_t pos=(size_t)(beg+ic);
      int src=esrc[pos];
      float v=-3e38f;
      {
        int ty=etP[pos];
        float aj=a_j[(size_t)src*HH+headL];
        const float* eap=&eaP[pos*16];
        float4 q0=*(const float4*)(eap+0);
        float4 q1=*(const float4*)(eap+4);
        float4 q2=*(const float4*)(eap+8);
        float4 q3=*(const float4*)(eap+12);
        float t=aih+aj+t_a[ty*8+headL];
        t+=q0.x*veh[0]+q0.y*veh[1]+q0.z*veh[2]+q0.w*veh[3];
        t+=q1.x*veh[4]+q1.y*veh[5]+q1.z*veh[6]+q1.w*veh[7];
        t+=q2.x*veh[8]+q2.y*veh[9]+q2.z*veh[10]+q2.w*veh[11];
        t+=q3.x*veh[12]+q3.y*veh[13]+q3.z*veh[14]+q3.w*veh[15];
        t=(t>=0.f)? t : 0.2f*t;
        if(ok) v=t;
      }
      float cm=v;
      cm=fmaxf(cm,__shfl_xor(cm,8));
      cm=fmaxf(cm,__shfl_xor(cm,16));
      cm=fmaxf(cm,__shfl_xor(cm,32));
      float cmg=__shfl(cm,ghead);
      float mnew=fmaxf(m,cmg);
      float f=__expf(m-mnew);
      ssum*=f; acc0*=f; acc1*=f; acc2*=f; acc3*=f;
      m=mnew;
      int cnt=min(8,deg-base);
      #pragma unroll
      for(int u=0;u<8;u++){
        if(u<cnt){
          float vu=__shfl(v,(u<<3)|ghead);
          int   si=__shfl(src,(u<<3));
          float wgt=__expf(vu-m);
          ssum+=wgt;
          ushort4 y=*(const ushort4*)&ysb[(size_t)si*DD+4*l];
          acc0+=wgt*b2f(y.x); acc1+=wgt*b2f(y.y); acc2+=wgt*b2f(y.z); acc3+=wgt*b2f(y.w);
        }
      }
    }
    if(ph==1){
      comb[pr][0][l]=m;    comb[pr][1][l]=ssum;
      comb[pr][2][l]=acc0; comb[pr][3][l]=acc1;
      comb[pr][4][l]=acc2; comb[pr][5][l]=acc3;
    }
  }
  __syncthreads();
  if(n<N && ph==0){
    float m1=comb[pr][0][l], s1=comb[pr][1][l];
    float ms=fmaxf(m,m1);
    float f0=__expf(m-ms), f1=__expf(m1-ms);
    float S=ssum*f0+s1*f1;
    float o0=acc0*f0+comb[pr][2][l]*f1;
    float o1=acc1*f0+comb[pr][3][l]*f1;
    float o2=acc2*f0+comb[pr][4][l]*f1;
    float o3=acc3*f0+comb[pr][5][l]*f1;
    float inv=1.f/(S+1e-16f);
    ushort4 o;
    o.x=f2b(o0*inv); o.y=f2b(o1*inv); o.z=f2b(o2*inv); o.w=f2b(o3*inv);
    *(ushort4*)&aggb[(size_t)n*DD+4*l]=o;
  }
}

// ---------------- BN finalize from nb per-block partials: one block PER COLUMN ----------------
__global__ __launch_bounds__(256) void k_bnfin(const float* __restrict__ psum, const float* __restrict__ psq,
                        const float* __restrict__ g, const float* __restrict__ b,
                        float* scale, float* shift, int N, int nb){
  __shared__ float rs[256], rq[256];
  int c=blockIdx.x, tid=threadIdx.x;
  float s=0.f,q=0.f;
  for(int i=tid;i<nb;i+=256){ s+=psum[(size_t)i*DD+c]; q+=psq[(size_t)i*DD+c]; }
  rs[tid]=s; rq[tid]=q;
  __syncthreads();
  #pragma unroll
  for(int off=128;off>0;off>>=1){
    if(tid<off){ rs[tid]+=rs[tid+off]; rq[tid]+=rq[tid+off]; }
    __syncthreads();
  }
  if(tid==0){
    float inv=1.f/(float)N;
    float mu=rs[0]*inv;
    float var=rq[0]*inv - mu*mu;
    float sc=g[c]*rsqrtf(var+1e-5f);
    scale[c]=sc;
    shift[c]=b[c]-mu*sc;
  }
}

// out = relu(h*scale + shift [+ res]); wave-per-row, float4, shuffle-reduced a_i.
template<bool RES, bool CVT>
__global__ __launch_bounds__(256) void k_bnapply(const float* __restrict__ hm, const float* __restrict__ scale,
                          const float* __restrict__ shift, const float* __restrict__ res,
                          float* __restrict__ outp, unsigned short* __restrict__ xb,
                          const float* __restrict__ wd_as, float* __restrict__ a_i, int N){
  int b=blockIdx.x, tid=threadIdx.x, wv=tid>>6, l=tid&63;
  int c0=4*l;
  float4 sc=*(const float4*)&scale[c0];
  float4 sh=*(const float4*)&shift[c0];
  float wa[4][8];
  if(CVT){
    #pragma unroll
    for(int j=0;j<4;j++)
      #pragma unroll
      for(int h=0;h<8;h++) wa[j][h]=wd_as[(c0+j)*8+h];
  }
  for(int n=b*4+wv; n<N; n+=NB_BA*4){
    float4 v=*(const float4*)&hm[(size_t)n*DD+c0];
    v.x=v.x*sc.x+sh.x; v.y=v.y*sc.y+sh.y; v.z=v.z*sc.z+sh.z; v.w=v.w*sc.w+sh.w;
    if(RES){
      float4 rr=*(const float4*)&res[(size_t)n*DD+c0];
      v.x+=rr.x; v.y+=rr.y; v.z+=rr.z; v.w+=rr.w;
    }
    v.x=fmaxf(v.x,0.f); v.y=fmaxf(v.y,0.f); v.z=fmaxf(v.z,0.f); v.w=fmaxf(v.w,0.f);
    *(float4*)&outp[(size_t)n*DD+c0]=v;
    if(CVT){
      ushort4 xo; xo.x=f2b(v.x); xo.y=f2b(v.y); xo.z=f2b(v.z); xo.w=f2b(v.w);
      *(ushort4*)&xb[(size_t)n*DD+c0]=xo;
      float ai[8];
      #pragma unroll
      for(int h=0;h<8;h++) ai[h]=v.x*wa[0][h]+v.y*wa[1][h]+v.z*wa[2][h]+v.w*wa[3][h];
      #pragma unroll
      for(int off=1;off<64;off<<=1){
        #pragma unroll
        for(int h=0;h<8;h++) ai[h]+=__shfl_xor(ai[h],off);
      }
      if(l==0){
        float4 A; A.x=ai[0];A.y=ai[1];A.z=ai[2];A.w=ai[3];
        float4 B; B.x=ai[4];B.y=ai[5];B.z=ai[6];B.w=ai[7];
        *(float4*)&a_i[(size_t)n*HH]=A;
        *(float4*)&a_i[(size_t)n*HH+4]=B;
      }
    }
  }
}

extern "C" void kernel_launch(void* const* d_in, const int* in_sizes, int n_in,
                              void* d_out, int out_size, void* d_ws, size_t ws_size,
                              hipStream_t stream) {
  const float* x  = (const float*)d_in[0];
  const int*   ei = (const int*)d_in[1];
  const float* ea = (const float*)d_in[2];
  const int*   et = (const int*)d_in[3];
  int N = in_sizes[0]/DD;
  int E = in_sizes[3];
  int Etot = E+N;
  const int* srcE = ei;
  const int* dstE = ei + E;

  const float* Ws1=(const float*)d_in[4];  const float* Wd1=(const float*)d_in[5];
  const float* as1=(const float*)d_in[6];  const float* ad1=(const float*)d_in[7];
  const float* We1=(const float*)d_in[8];  const float* ae1=(const float*)d_in[9];
  const float* te1=(const float*)d_in[10]; const float* Wo1=(const float*)d_in[11];
  const float* bo1=(const float*)d_in[12]; const float* b1 =(const float*)d_in[13];
  const float* lg1=(const float*)d_in[14]; const float* lb1=(const float*)d_in[15];
  const float* Ws2=(const float*)d_in[16]; const float* Wd2=(const float*)d_in[17];
  const float* as2=(const float*)d_in[18]; const float* ad2=(const float*)d_in[19];
  const float* We2=(const float*)d_in[20]; const float* ae2=(const float*)d_in[21];
  const float* te2=(const float*)d_in[22]; const float* Wo2=(const float*)d_in[23];
  const float* bo2=(const float*)d_in[24]; const float* b2 =(const float*)d_in[25];
  const float* lg2=(const float*)d_in[26]; const float* lb2=(const float*)d_in[27];
  const float* bng1=(const float*)d_in[28]; const float* bnb1=(const float*)d_in[29];
  const float* bng2=(const float*)d_in[30]; const float* bnb2=(const float*)d_in[31];

  char* p=(char*)d_ws;
  auto alloc=[&](size_t bytes)->void*{ void* r=(void*)p; p+=(bytes+255)&~(size_t)255; return r; };
  unsigned short* xb   =(unsigned short*)alloc((size_t)N*DD*2);
  unsigned short* ysb  =(unsigned short*)alloc((size_t)N*DD*2);
  unsigned short* aggb =(unsigned short*)alloc((size_t)N*DD*2);
  float* eaP   =(float*)alloc((size_t)Etot*16*4);
  int*   etP   =(int*)alloc((size_t)Etot*4);
  float* xout1 =(float*)alloc((size_t)N*DD*4);
  float* a_i   =(float*)alloc((size_t)N*HH*4);
  float* a_j   =(float*)alloc((size_t)N*HH*4);
  float* wd_as1=(float*)alloc(DD*HH*4);
  float* v_e1  =(float*)alloc(16*HH*4);
  float* t_a1  =(float*)alloc(7*HH*4);
  float* wd_as2=(float*)alloc(DD*HH*4);
  float* v_e2  =(float*)alloc(16*HH*4);
  float* t_a2  =(float*)alloc(7*HH*4);
  int nbLN=(N+31)/32;
  float* psum  =(float*)alloc((size_t)nbLN*DD*4);
  float* psq   =(float*)alloc((size_t)nbLN*DD*4);
  float* scl   =(float*)alloc(256*4);
  float* shf   =(float*)alloc(256*4);
  unsigned short* Wsb1T=(unsigned short*)alloc((size_t)DD*DD*2);
  unsigned short* Wob1T=(unsigned short*)alloc((size_t)DD*DD*2);
  unsigned short* Wsb2T=(unsigned short*)alloc((size_t)DD*DD*2);
  unsigned short* Wob2T=(unsigned short*)alloc((size_t)DD*DD*2);
  int* cnt     =(int*)alloc((size_t)N*4);
  int* row_off =(int*)alloc((size_t)(N+1)*4);
  int* cursor  =(int*)alloc((size_t)N*4);
  int* esrc    =(int*)alloc((size_t)Etot*4);
  float* hbuf  =(float*)d_out;

  dim3 gg(2,(N+63)/64);
  int aggGrid=(N+1)/2;

  // upfront: CSR (with permuted edge data) + weight prep (both layers)
  k_zero_i<<<(N+255)/256,256,0,stream>>>(cnt,N);
  k_count<<<(Etot+255)/256,256,0,stream>>>(dstE,E,N,cnt);
  k_scan<<<1,1024,0,stream>>>(cnt,N,row_off,cursor);
  k_fill<<<(Etot+255)/256,256,0,stream>>>(srcE,dstE,ea,et,E,N,cursor,esrc,etP,eaP);
  k_cvt_wT4<<<dim3(DD,4),DD,0,stream>>>(Ws1,Wo1,Ws2,Wo2,Wsb1T,Wob1T,Wsb2T,Wob2T);
  k_pre2<<<2,256,0,stream>>>(Wd1,as1,We1,ae1,te1,Wd2,as2,We2,ae2,te2,
                             wd_as1,v_e1,t_a1,wd_as2,v_e2,t_a2);

  // ---- layer 1 ----
  k_cvt_x2<<<NB_BA,256,0,stream>>>(x,wd_as1,xb,a_i,N);
  k_gemm1<true><<<gg,256,0,stream>>>(xb,Wsb1T,ad1,a_j,ysb,N);
  k_agg<<<aggGrid,256,0,stream>>>(row_off,esrc,etP,eaP,a_i,a_j,v_e1,t_a1,ysb,aggb,N);
  k_gemm_ln<<<nbLN,256,0,stream>>>(aggb,Wob1T,bo1,b1,x,lg1,lb1,hbuf,psum,psq,N);
  k_bnfin<<<DD,256,0,stream>>>(psum,psq,bng1,bnb1,scl,shf,N,nbLN);
  k_bnapply<false,true><<<NB_BA,256,0,stream>>>(hbuf,scl,shf,nullptr,xout1,xb,wd_as2,a_i,N);

  // ---- layer 2 ----
  k_gemm1<true><<<gg,256,0,stream>>>(xb,Wsb2T,ad2,a_j,ysb,N);
  k_agg<<<aggGrid,256,0,stream>>>(row_off,esrc,etP,eaP,a_i,a_j,v_e2,t_a2,ysb,aggb,N);
  k_gemm_ln<<<nbLN,256,0,stream>>>(aggb,Wob2T,bo2,b2,xout1,lg2,lb2,hbuf,psum,psq,N);
  k_bnfin<<<DD,256,0,stream>>>(psum,psq,bng2,bnb2,scl,shf,N,nbLN);
  k_bnapply<true,false><<<NB_BA,256,0,stream>>>(hbuf,scl,shf,x,(float*)d_out,nullptr,nullptr,nullptr,N);
}

// Round 17
// 311.396 us; speedup vs baseline: 1.0591x; 1.0591x over previous
//
#include <hip/hip_runtime.h>

#define DD 256
#define HH 8
#define CC 32

typedef __attribute__((ext_vector_type(8))) short short8;
typedef __attribute__((ext_vector_type(4))) float f32x4;

static __device__ __forceinline__ unsigned short f2b(float f){
  unsigned u = __float_as_uint(f);
  u = u + 0x7FFFu + ((u >> 16) & 1u);          // RNE
  return (unsigned short)(u >> 16);
}
static __device__ __forceinline__ float b2f(unsigned short s){
  return __uint_as_float(((unsigned)s) << 16);
}

// global->LDS direct DMA: 16B/lane, wave-uniform LDS base, lane l lands at base+l*16.
static __device__ __forceinline__ void gload16(const void* g, void* l){
  using gpt = const __attribute__((address_space(1))) unsigned int*;
  using lpt = __attribute__((address_space(3))) unsigned int*;
  __builtin_amdgcn_global_load_lds((gpt)(unsigned long long)g, (lpt)(unsigned long long)l, 16, 0, 0);
}

// ---------------- utility ----------------
__global__ void k_zero_i(int* p, int n){ int i=blockIdx.x*blockDim.x+threadIdx.x; if(i<n) p[i]=0; }

// ---------------- CSR build ----------------
__global__ void k_count(const int* __restrict__ dstE, int E, int N, int* cnt){
  int e=blockIdx.x*blockDim.x+threadIdx.x;
  if(e<E+N){ int d=(e<E)? dstE[e] : (e-E); atomicAdd(&cnt[d],1); }
}

__global__ __launch_bounds__(1024) void k_scan(const int* __restrict__ cnt, int N, int* row_off, int* cursor){
  __shared__ int part[1024];
  int t=threadIdx.x;
  int chunk=(N+1023)>>10;
  int s=0;
  for(int j=0;j<chunk;j++){ int i=t*chunk+j; if(i<N) s+=cnt[i]; }
  part[t]=s; __syncthreads();
  for(int off=1; off<1024; off<<=1){
    int v=(t>=off)? part[t-off]:0;
    __syncthreads();
    part[t]+=v;
    __syncthreads();
  }
  int run=(t==0)?0:part[t-1];
  for(int j=0;j<chunk;j++){ int i=t*chunk+j; if(i<N){ row_off[i]=run; cursor[i]=run; run+=cnt[i]; } }
  if(t==1023) row_off[N]=part[1023];
}

// fill CSR: scatter src, edge-type AND edge-attr into CSR (dst-sorted) order.
__global__ void k_fill(const int* __restrict__ srcE, const int* __restrict__ dstE,
                       const float* __restrict__ ea, const int* __restrict__ et,
                       int E, int N, int* cursor,
                       int* esrc, int* etP, float* eaP){
  int e=blockIdx.x*blockDim.x+threadIdx.x;
  if(e>=E+N) return;
  int s,d,ty;
  float4 q0,q1,q2,q3;
  if(e<E){
    s=srcE[e]; d=dstE[e]; ty=et[e];
    q0=*(const float4*)&ea[(size_t)e*16+0];
    q1=*(const float4*)&ea[(size_t)e*16+4];
    q2=*(const float4*)&ea[(size_t)e*16+8];
    q3=*(const float4*)&ea[(size_t)e*16+12];
  }else{
    s=e-E; d=s; ty=6;
    q0=q1=q2=q3=make_float4(1.f,1.f,1.f,1.f);
  }
  int pos=atomicAdd(&cursor[d],1);
  esrc[pos]=s; etP[pos]=ty;
  float* o=&eaP[(size_t)pos*16];
  *(float4*)(o+0)=q0; *(float4*)(o+4)=q1; *(float4*)(o+8)=q2; *(float4*)(o+12)=q3;
}

// ---------------- 4x weight transpose + bf16 convert in one launch ----------------
__global__ void k_cvt_wT4(const float* __restrict__ W0, const float* __restrict__ W1,
                          const float* __restrict__ W2, const float* __restrict__ W3,
                          unsigned short* __restrict__ T0, unsigned short* __restrict__ T1,
                          unsigned short* __restrict__ T2, unsigned short* __restrict__ T3){
  int m=blockIdx.y, c=blockIdx.x, k=threadIdx.x;
  const float* W = (m==0)?W0:(m==1)?W1:(m==2)?W2:W3;
  unsigned short* T = (m==0)?T0:(m==1)?T1:(m==2)?T2:T3;
  T[(size_t)c*DD+k] = f2b(W[(size_t)k*DD+c]);
}

// ---------------- folded logit weights (both layers) ----------------
__global__ void k_pre2(const float* __restrict__ Wd1, const float* __restrict__ as1,
                       const float* __restrict__ We1, const float* __restrict__ ae1,
                       const float* __restrict__ te1,
                       const float* __restrict__ Wd2, const float* __restrict__ as2,
                       const float* __restrict__ We2, const float* __restrict__ ae2,
                       const float* __restrict__ te2,
                       float* wd_as1, float* v_e1, float* t_a1,
                       float* wd_as2, float* v_e2, float* t_a2){
  int L=blockIdx.x;
  const float* Wd=L?Wd2:Wd1; const float* as_=L?as2:as1;
  const float* We=L?We2:We1; const float* ae=L?ae2:ae1; const float* te=L?te2:te1;
  float* wd_as=L?wd_as2:wd_as1; float* v_e=L?v_e2:v_e1; float* t_a=L?t_a2:t_a1;
  int t=threadIdx.x;
  for(int idx=t; idx<DD*HH; idx+=256){
    int k=idx>>3, h=idx&7;
    const float* w=&Wd[k*DD+h*CC]; const float* a=&as_[h*CC];
    float s=0;
    #pragma unroll
    for(int c=0;c<CC;c++) s+=w[c]*a[c];
    wd_as[idx]=s;
  }
  for(int idx=t; idx<16*HH; idx+=256){
    int k=idx>>3, h=idx&7;
    const float* w=&We[k*DD+h*CC]; const float* a=&ae[h*CC];
    float s=0;
    #pragma unroll
    for(int c=0;c<CC;c++) s+=w[c]*a[c];
    v_e[idx]=s;
  }
  for(int idx=t; idx<7*HH; idx+=256){
    int k=idx>>3, h=idx&7;
    const float* w=&te[k*DD+h*CC]; const float* a=&ae[h*CC];
    float s=0;
    #pragma unroll
    for(int c=0;c<CC;c++) s+=w[c]*a[c];
    t_a[idx]=s;
  }
}

// ---------------- x -> bf16 + a_i (wave-per-row, float4, shuffle reduce) ----------------
#define NB_BA 1024
__global__ __launch_bounds__(256) void k_cvt_x2(const float* __restrict__ xin, const float* __restrict__ wd_as,
                         unsigned short* __restrict__ xb, float* __restrict__ a_i, int N){
  int b=blockIdx.x, tid=threadIdx.x, wv=tid>>6, l=tid&63;
  int c0=4*l;
  float wa[4][8];
  #pragma unroll
  for(int j=0;j<4;j++)
    #pragma unroll
    for(int h=0;h<8;h++) wa[j][h]=wd_as[(c0+j)*8+h];
  for(int n=b*4+wv; n<N; n+=NB_BA*4){
    float4 v=*(const float4*)&xin[(size_t)n*DD+c0];
    ushort4 xo; xo.x=f2b(v.x); xo.y=f2b(v.y); xo.z=f2b(v.z); xo.w=f2b(v.w);
    *(ushort4*)&xb[(size_t)n*DD+c0]=xo;
    float ai[8];
    #pragma unroll
    for(int h=0;h<8;h++) ai[h]=v.x*wa[0][h]+v.y*wa[1][h]+v.z*wa[2][h]+v.w*wa[3][h];
    #pragma unroll
    for(int off=1;off<64;off<<=1){
      #pragma unroll
      for(int h=0;h<8;h++) ai[h]+=__shfl_xor(ai[h],off);
    }
    if(l==0){
      float4 A; A.x=ai[0];A.y=ai[1];A.z=ai[2];A.w=ai[3];
      float4 B; B.x=ai[4];B.y=ai[5];B.z=ai[6];B.w=ai[7];
      *(float4*)&a_i[(size_t)n*HH]=A;
      *(float4*)&a_i[(size_t)n*HH+4]=B;
    }
  }
}

// ---------------- GEMM1: C[N,256]=A@B, bf16 out + fused a_j ----------------
template<bool AJ>
__global__ __launch_bounds__(256) void k_gemm1(const unsigned short* __restrict__ A,
                                               const unsigned short* __restrict__ Bt,
                                               const float* __restrict__ ad, float* __restrict__ a_j,
                                               unsigned short* __restrict__ Cout, int N){
  __shared__ char lds[2*12288];   // per buf: A 64x32 (4KB) + B 128x32 (8KB)
  int tid=threadIdx.x;
  int w=tid>>6, l=tid&63;
  int row0=blockIdx.y*64, col0=blockIdx.x*128;

  int lr=l>>2;
  int kc=(l&3)^((l>>3)&3);
  const unsigned short* ga  = &A [(size_t)(row0+16*w+lr)*DD + kc*8];
  const unsigned short* gb0 = &Bt[(size_t)(col0+32*w+lr)*DD + kc*8];
  const unsigned short* gb1 = &Bt[(size_t)(col0+32*w+16+lr)*DD + kc*8];
  int laoff =      w*1024;
  int lboff0=4096+(32*w)*64;
  int lboff1=4096+(32*w+16)*64;

  int x15=l&15;
  int lp=x15*64 + ((l>>4)^((x15>>1)&3))*16;

  f32x4 acc[4][2];
  #pragma unroll
  for(int i=0;i<4;i++){ acc[i][0]=(f32x4)0.f; acc[i][1]=(f32x4)0.f; }

  gload16(ga,  lds+laoff);
  gload16(gb0, lds+lboff0);
  gload16(gb1, lds+lboff1);
  __syncthreads();
  int cur=0;
  for(int kt=0;kt<DD;kt+=32){
    int nxt=cur^1;
    if(kt+32<DD){
      gload16(ga +kt+32, lds+nxt*12288+laoff);
      gload16(gb0+kt+32, lds+nxt*12288+lboff0);
      gload16(gb1+kt+32, lds+nxt*12288+lboff1);
    }
    char* base=lds+cur*12288;
    short8 af[4], bf[2];
    #pragma unroll
    for(int mf=0;mf<4;mf++) af[mf]=*(short8*)(base + mf*1024 + lp);
    #pragma unroll
    for(int nf=0;nf<2;nf++) bf[nf]=*(short8*)(base + 4096 + (32*w+16*nf)*64 + lp);
    #pragma unroll
    for(int mf=0;mf<4;mf++)
      #pragma unroll
      for(int nf=0;nf<2;nf++)
        acc[mf][nf]=__builtin_amdgcn_mfma_f32_16x16x32_bf16(af[mf],bf[nf],acc[mf][nf],0,0,0);
    __syncthreads();
    cur=nxt;
  }

  int lcol=x15, lrow4=(l>>4)*4;
  float ad0=0.f, ad1=0.f;
  if(AJ){ ad0=ad[col0+32*w+lcol]; ad1=ad[col0+32*w+16+lcol]; }
  int head=(col0>>5)+w;
  #pragma unroll
  for(int mf=0;mf<4;mf++){
    #pragma unroll
    for(int nf=0;nf<2;nf++){
      int col=col0 + 32*w + 16*nf + lcol;
      #pragma unroll
      for(int rr=0;rr<4;rr++){
        int row=row0 + 16*mf + lrow4 + rr;
        if(row<N) Cout[(size_t)row*DD+col]=f2b(acc[mf][nf][rr]);
      }
    }
    if(AJ){
      #pragma unroll
      for(int rr=0;rr<4;rr++){
        float t=acc[mf][0][rr]*ad0 + acc[mf][1][rr]*ad1;
        t+=__shfl_xor(t,1); t+=__shfl_xor(t,2);
        t+=__shfl_xor(t,4); t+=__shfl_xor(t,8);
        int row=row0 + 16*mf + lrow4 + rr;
        if(x15==0 && row<N) a_j[(size_t)row*HH+head]=t;
      }
    }
  }
}

// ---------------- GEMM2 fused: bias + LayerNorm + residual + BN partials --------
__global__ __launch_bounds__(256) void k_gemm_ln(const unsigned short* __restrict__ A,
                                                 const unsigned short* __restrict__ Bt,
                                                 const float* __restrict__ bo, const float* __restrict__ bvec,
                                                 const float* __restrict__ xin,
                                                 const float* __restrict__ lg, const float* __restrict__ lb,
                                                 float* __restrict__ hout,
                                                 float* __restrict__ psum, float* __restrict__ psq, int N){
  __shared__ char lds[2*18432];   // per buf: A 32x32 (2KB) + B 256x32 (16KB)
  int tid=threadIdx.x;
  int w=tid>>6, l=tid&63;
  int row0=blockIdx.x*32;

  int lr=l>>2;
  int kc=(l&3)^((l>>3)&3);
  const unsigned short* ga = &A[(size_t)(row0+16*w+lr)*DD + kc*8];   // waves 0,1 only
  const unsigned short* gb0=&Bt[(size_t)(64*w   +lr)*DD + kc*8];
  const unsigned short* gb1=&Bt[(size_t)(64*w+16+lr)*DD + kc*8];
  const unsigned short* gb2=&Bt[(size_t)(64*w+32+lr)*DD + kc*8];
  const unsigned short* gb3=&Bt[(size_t)(64*w+48+lr)*DD + kc*8];
  int laoff =      w*1024;
  int lboff0=2048+(64*w   )*64;
  int lboff1=2048+(64*w+16)*64;
  int lboff2=2048+(64*w+32)*64;
  int lboff3=2048+(64*w+48)*64;

  int x15=l&15;
  int lp=x15*64 + ((l>>4)^((x15>>1)&3))*16;

  f32x4 acc[2][4];
  #pragma unroll
  for(int i=0;i<2;i++)
    #pragma unroll
    for(int j=0;j<4;j++) acc[i][j]=(f32x4)0.f;

  if(w<2) gload16(ga, lds+laoff);
  gload16(gb0, lds+lboff0);
  gload16(gb1, lds+lboff1);
  gload16(gb2, lds+lboff2);
  gload16(gb3, lds+lboff3);
  __syncthreads();
  int cur=0;
  for(int kt=0;kt<DD;kt+=32){
    int nxt=cur^1;
    if(kt+32<DD){
      char* nb=lds+nxt*18432;
      if(w<2) gload16(ga+kt+32, nb+laoff);
      gload16(gb0+kt+32, nb+lboff0);
      gload16(gb1+kt+32, nb+lboff1);
      gload16(gb2+kt+32, nb+lboff2);
      gload16(gb3+kt+32, nb+lboff3);
    }
    char* base=lds+cur*18432;
    short8 af[2], bf[4];
    #pragma unroll
    for(int mf=0;mf<2;mf++) af[mf]=*(short8*)(base + mf*1024 + lp);
    #pragma unroll
    for(int nf=0;nf<4;nf++) bf[nf]=*(short8*)(base + 2048 + (64*w+16*nf)*64 + lp);
    #pragma unroll
    for(int mf=0;mf<2;mf++)
      #pragma unroll
      for(int nf=0;nf<4;nf++)
        acc[mf][nf]=__builtin_amdgcn_mfma_f32_16x16x32_bf16(af[mf],bf[nf],acc[mf][nf],0,0,0);
    __syncthreads();
    cur=nxt;
  }

  // ---- epilogue ----
  int lrow4=(l>>4)*4;
  float lgv[4], lbv[4];
  #pragma unroll
  for(int nf=0;nf<4;nf++){
    int col=64*w+16*nf+x15;
    float badd=bo[col]+bvec[col];
    lgv[nf]=lg[col]; lbv[nf]=lb[col];
    #pragma unroll
    for(int mf=0;mf<2;mf++)
      #pragma unroll
      for(int rr=0;rr<4;rr++) acc[mf][nf][rr]+=badd;
  }
  __syncthreads();   // GEMM LDS dead; repurpose
  float* rs   =(float*)lds;            // [4][32]
  float* rq   =(float*)(lds+512);      // [4][32]
  float* mus  =(float*)(lds+1024);     // [32]
  float* rstds=(float*)(lds+1152);     // [32]
  #pragma unroll
  for(int mf=0;mf<2;mf++){
    #pragma unroll
    for(int rr=0;rr<4;rr++){
      float t=acc[mf][0][rr]+acc[mf][1][rr]+acc[mf][2][rr]+acc[mf][3][rr];
      float q=acc[mf][0][rr]*acc[mf][0][rr]+acc[mf][1][rr]*acc[mf][1][rr]
             +acc[mf][2][rr]*acc[mf][2][rr]+acc[mf][3][rr]*acc[mf][3][rr];
      t+=__shfl_xor(t,1); q+=__shfl_xor(q,1);
      t+=__shfl_xor(t,2); q+=__shfl_xor(q,2);
      t+=__shfl_xor(t,4); q+=__shfl_xor(q,4);
      t+=__shfl_xor(t,8); q+=__shfl_xor(q,8);
      if(x15==0){
        int row=16*mf+lrow4+rr;
        rs[w*32+row]=t; rq[w*32+row]=q;
      }
    }
  }
  __syncthreads();
  if(tid<32){
    float S=rs[tid]+rs[32+tid]+rs[64+tid]+rs[96+tid];
    float Q=rq[tid]+rq[32+tid]+rq[64+tid]+rq[96+tid];
    float mu=S*(1.f/DD);
    float var=Q*(1.f/DD)-mu*mu;
    mus[tid]=mu;
    rstds[tid]=rsqrtf(var+1e-5f);
  }
  __syncthreads();
  float cps[4]={0.f,0.f,0.f,0.f}, cqs[4]={0.f,0.f,0.f,0.f};
  #pragma unroll
  for(int mf=0;mf<2;mf++){
    #pragma unroll
    for(int rr=0;rr<4;rr++){
      int row=16*mf+lrow4+rr;
      int grow=row0+row;
      bool ok=(grow<N);
      float mu=mus[row], rstd=rstds[row];
      #pragma unroll
      for(int nf=0;nf<4;nf++){
        int col=64*w+16*nf+x15;
        float h=0.f;
        if(ok){
          h=(acc[mf][nf][rr]-mu)*rstd*lgv[nf]+lbv[nf]+xin[(size_t)grow*DD+col];
          hout[(size_t)grow*DD+col]=h;
        }
        cps[nf]+=h; cqs[nf]+=h*h;
      }
    }
  }
  #pragma unroll
  for(int nf=0;nf<4;nf++){
    cps[nf]+=__shfl_xor(cps[nf],16); cqs[nf]+=__shfl_xor(cqs[nf],16);
    cps[nf]+=__shfl_xor(cps[nf],32); cqs[nf]+=__shfl_xor(cqs[nf],32);
  }
  if(l<16){
    #pragma unroll
    for(int nf=0;nf<4;nf++){
      int col=64*w+16*nf+l;
      psum[(size_t)blockIdx.x*DD+col]=cps[nf];
      psq [(size_t)blockIdx.x*DD+col]=cqs[nf];
    }
  }
}

// ---------------- FUSED edge-logit + online softmax + aggregation ----------------
// One wave per node, single pass. Logit: lane (slot=l>>3, head=l&7). Gather: two
// 32-lane halves; lane-in-half lk covers cols 8lk..8lk+7 (head hh=lk>>2); half h
// takes edges u+h of each pair. Shuffles HOISTED out of the divergent guard
// (wave-uniform exec for cross-lane ops); only loads/accumulation are guarded.
__global__ __launch_bounds__(256) void k_agg(const int* __restrict__ row_off,
                      const int* __restrict__ esrc, const int* __restrict__ etP,
                      const float* __restrict__ eaP,
                      const float* __restrict__ a_i, const float* __restrict__ a_j,
                      const float* __restrict__ v_e, const float* __restrict__ t_a,
                      const unsigned short* __restrict__ ysb, unsigned short* __restrict__ aggb, int N){
  int wv=threadIdx.x>>6, l=threadIdx.x&63;
  int n=blockIdx.x*4+wv;
  if(n>=N) return;
  int beg=row_off[n], deg=row_off[n+1]-beg;
  int slotL=l>>3, headL=l&7;
  int half=l>>5, lk=l&31;
  int hh=lk>>2;                      // gather head: cols 8lk..8lk+7 all in head lk>>2
  float veh[16];
  #pragma unroll
  for(int k=0;k<16;k++) veh[k]=v_e[k*8+headL];
  float aih=a_i[(size_t)n*HH+headL];
  float m=-3e38f, ssum=0.f;
  float acc[8];
  #pragma unroll
  for(int j=0;j<8;j++) acc[j]=0.f;
  for(int base=0;base<deg;base+=8){
    int i=base+slotL;
    bool ok=(i<deg);
    int ic=ok?i:(deg-1);
    size_t pos=(size_t)(beg+ic);
    int src=esrc[pos];
    float v=-3e38f;
    {
      int ty=etP[pos];
      float aj=a_j[(size_t)src*HH+headL];
      const float* eap=&eaP[pos*16];
      float4 q0=*(const float4*)(eap+0);
      float4 q1=*(const float4*)(eap+4);
      float4 q2=*(const float4*)(eap+8);
      float4 q3=*(const float4*)(eap+12);
      float t=aih+aj+t_a[ty*8+headL];
      t+=q0.x*veh[0]+q0.y*veh[1]+q0.z*veh[2]+q0.w*veh[3];
      t+=q1.x*veh[4]+q1.y*veh[5]+q1.z*veh[6]+q1.w*veh[7];
      t+=q2.x*veh[8]+q2.y*veh[9]+q2.z*veh[10]+q2.w*veh[11];
      t+=q3.x*veh[12]+q3.y*veh[13]+q3.z*veh[14]+q3.w*veh[15];
      t=(t>=0.f)? t : 0.2f*t;
      if(ok) v=t;
    }
    // per-head chunk max (butterfly over slot bits); uniform exec
    float cm=v;
    cm=fmaxf(cm,__shfl_xor(cm,8));
    cm=fmaxf(cm,__shfl_xor(cm,16));
    cm=fmaxf(cm,__shfl_xor(cm,32));
    float cmg=__shfl(cm,hh);          // lane hh (headL==hh) holds head hh's max
    float mnew=fmaxf(m,cmg);
    float f=__expf(m-mnew);           // first chunk: exp(-inf)=0, state already 0
    ssum*=f;
    #pragma unroll
    for(int j=0;j<8;j++) acc[j]*=f;
    m=mnew;
    int cnt=min(8,deg-base);
    #pragma unroll
    for(int u=0;u<8;u+=2){
      int e=u+half;
      // cross-lane ops OUTSIDE the divergent guard (all 64 lanes active)
      float vu=__shfl(v,(e<<3)|hh);
      int   si=__shfl(src,(e<<3));
      if(e<cnt){
        float wgt=__expf(vu-m);
        ssum+=wgt;
        short8 y=*(const short8*)&ysb[(size_t)si*DD+8*lk];
        #pragma unroll
        for(int j=0;j<8;j++) acc[j]+=wgt*b2f((unsigned short)y[j]);
      }
    }
  }
  // merge halves (same m on both -> plain add); uniform exec
  ssum+=__shfl_xor(ssum,32);
  #pragma unroll
  for(int j=0;j<8;j++) acc[j]+=__shfl_xor(acc[j],32);
  if(half==0){
    float inv=1.f/(ssum+1e-16f);
    short8 o;
    #pragma unroll
    for(int j=0;j<8;j++) o[j]=(short)f2b(acc[j]*inv);
    *(short8*)&aggb[(size_t)n*DD+8*lk]=o;
  }
}

// ---------------- BN finalize from nb per-block partials: one block PER COLUMN ----------------
__global__ __launch_bounds__(256) void k_bnfin(const float* __restrict__ psum, const float* __restrict__ psq,
                        const float* __restrict__ g, const float* __restrict__ b,
                        float* scale, float* shift, int N, int nb){
  __shared__ float rs[256], rq[256];
  int c=blockIdx.x, tid=threadIdx.x;
  float s=0.f,q=0.f;
  for(int i=tid;i<nb;i+=256){ s+=psum[(size_t)i*DD+c]; q+=psq[(size_t)i*DD+c]; }
  rs[tid]=s; rq[tid]=q;
  __syncthreads();
  #pragma unroll
  for(int off=128;off>0;off>>=1){
    if(tid<off){ rs[tid]+=rs[tid+off]; rq[tid]+=rq[tid+off]; }
    __syncthreads();
  }
  if(tid==0){
    float inv=1.f/(float)N;
    float mu=rs[0]*inv;
    float var=rq[0]*inv - mu*mu;
    float sc=g[c]*rsqrtf(var+1e-5f);
    scale[c]=sc;
    shift[c]=b[c]-mu*sc;
  }
}

// out = relu(h*scale + shift [+ res]); wave-per-row, float4, shuffle-reduced a_i.
template<bool RES, bool CVT>
__global__ __launch_bounds__(256) void k_bnapply(const float* __restrict__ hm, const float* __restrict__ scale,
                          const float* __restrict__ shift, const float* __restrict__ res,
                          float* __restrict__ outp, unsigned short* __restrict__ xb,
                          const float* __restrict__ wd_as, float* __restrict__ a_i, int N){
  int b=blockIdx.x, tid=threadIdx.x, wv=tid>>6, l=tid&63;
  int c0=4*l;
  float4 sc=*(const float4*)&scale[c0];
  float4 sh=*(const float4*)&shift[c0];
  float wa[4][8];
  if(CVT){
    #pragma unroll
    for(int j=0;j<4;j++)
      #pragma unroll
      for(int h=0;h<8;h++) wa[j][h]=wd_as[(c0+j)*8+h];
  }
  for(int n=b*4+wv; n<N; n+=NB_BA*4){
    float4 v=*(const float4*)&hm[(size_t)n*DD+c0];
    v.x=v.x*sc.x+sh.x; v.y=v.y*sc.y+sh.y; v.z=v.z*sc.z+sh.z; v.w=v.w*sc.w+sh.w;
    if(RES){
      float4 rr=*(const float4*)&res[(size_t)n*DD+c0];
      v.x+=rr.x; v.y+=rr.y; v.z+=rr.z; v.w+=rr.w;
    }
    v.x=fmaxf(v.x,0.f); v.y=fmaxf(v.y,0.f); v.z=fmaxf(v.z,0.f); v.w=fmaxf(v.w,0.f);
    *(float4*)&outp[(size_t)n*DD+c0]=v;
    if(CVT){
      ushort4 xo; xo.x=f2b(v.x); xo.y=f2b(v.y); xo.z=f2b(v.z); xo.w=f2b(v.w);
      *(ushort4*)&xb[(size_t)n*DD+c0]=xo;
      float ai[8];
      #pragma unroll
      for(int h=0;h<8;h++) ai[h]=v.x*wa[0][h]+v.y*wa[1][h]+v.z*wa[2][h]+v.w*wa[3][h];
      #pragma unroll
      for(int off=1;off<64;off<<=1){
        #pragma unroll
        for(int h=0;h<8;h++) ai[h]+=__shfl_xor(ai[h],off);
      }
      if(l==0){
        float4 A; A.x=ai[0];A.y=ai[1];A.z=ai[2];A.w=ai[3];
        float4 B; B.x=ai[4];B.y=ai[5];B.z=ai[6];B.w=ai[7];
        *(float4*)&a_i[(size_t)n*HH]=A;
        *(float4*)&a_i[(size_t)n*HH+4]=B;
      }
    }
  }
}

extern "C" void kernel_launch(void* const* d_in, const int* in_sizes, int n_in,
                              void* d_out, int out_size, void* d_ws, size_t ws_size,
                              hipStream_t stream) {
  const float* x  = (const float*)d_in[0];
  const int*   ei = (const int*)d_in[1];
  const float* ea = (const float*)d_in[2];
  const int*   et = (const int*)d_in[3];
  int N = in_sizes[0]/DD;
  int E = in_sizes[3];
  int Etot = E+N;
  const int* srcE = ei;
  const int* dstE = ei + E;

  const float* Ws1=(const float*)d_in[4];  const float* Wd1=(const float*)d_in[5];
  const float* as1=(const float*)d_in[6];  const float* ad1=(const float*)d_in[7];
  const float* We1=(const float*)d_in[8];  const float* ae1=(const float*)d_in[9];
  const float* te1=(const float*)d_in[10]; const float* Wo1=(const float*)d_in[11];
  const float* bo1=(const float*)d_in[12]; const float* b1 =(const float*)d_in[13];
  const float* lg1=(const float*)d_in[14]; const float* lb1=(const float*)d_in[15];
  const float* Ws2=(const float*)d_in[16]; const float* Wd2=(const float*)d_in[17];
  const float* as2=(const float*)d_in[18]; const float* ad2=(const float*)d_in[19];
  const float* We2=(const float*)d_in[20]; const float* ae2=(const float*)d_in[21];
  const float* te2=(const float*)d_in[22]; const float* Wo2=(const float*)d_in[23];
  const float* bo2=(const float*)d_in[24]; const float* b2 =(const float*)d_in[25];
  const float* lg2=(const float*)d_in[26]; const float* lb2=(const float*)d_in[27];
  const float* bng1=(const float*)d_in[28]; const float* bnb1=(const float*)d_in[29];
  const float* bng2=(const float*)d_in[30]; const float* bnb2=(const float*)d_in[31];

  char* p=(char*)d_ws;
  auto alloc=[&](size_t bytes)->void*{ void* r=(void*)p; p+=(bytes+255)&~(size_t)255; return r; };
  unsigned short* xb   =(unsigned short*)alloc((size_t)N*DD*2);
  unsigned short* ysb  =(unsigned short*)alloc((size_t)N*DD*2);
  unsigned short* aggb =(unsigned short*)alloc((size_t)N*DD*2);
  float* eaP   =(float*)alloc((size_t)Etot*16*4);
  int*   etP   =(int*)alloc((size_t)Etot*4);
  float* xout1 =(float*)alloc((size_t)N*DD*4);
  float* a_i   =(float*)alloc((size_t)N*HH*4);
  float* a_j   =(float*)alloc((size_t)N*HH*4);
  float* wd_as1=(float*)alloc(DD*HH*4);
  float* v_e1  =(float*)alloc(16*HH*4);
  float* t_a1  =(float*)alloc(7*HH*4);
  float* wd_as2=(float*)alloc(DD*HH*4);
  float* v_e2  =(float*)alloc(16*HH*4);
  float* t_a2  =(float*)alloc(7*HH*4);
  int nbLN=(N+31)/32;
  float* psum  =(float*)alloc((size_t)nbLN*DD*4);
  float* psq   =(float*)alloc((size_t)nbLN*DD*4);
  float* scl   =(float*)alloc(256*4);
  float* shf   =(float*)alloc(256*4);
  unsigned short* Wsb1T=(unsigned short*)alloc((size_t)DD*DD*2);
  unsigned short* Wob1T=(unsigned short*)alloc((size_t)DD*DD*2);
  unsigned short* Wsb2T=(unsigned short*)alloc((size_t)DD*DD*2);
  unsigned short* Wob2T=(unsigned short*)alloc((size_t)DD*DD*2);
  int* cnt     =(int*)alloc((size_t)N*4);
  int* row_off =(int*)alloc((size_t)(N+1)*4);
  int* cursor  =(int*)alloc((size_t)N*4);
  int* esrc    =(int*)alloc((size_t)Etot*4);
  float* hbuf  =(float*)d_out;

  dim3 gg(2,(N+63)/64);
  int aggGrid=(N+3)/4;

  // upfront: CSR (with permuted edge data) + weight prep (both layers)
  k_zero_i<<<(N+255)/256,256,0,stream>>>(cnt,N);
  k_count<<<(Etot+255)/256,256,0,stream>>>(dstE,E,N,cnt);
  k_scan<<<1,1024,0,stream>>>(cnt,N,row_off,cursor);
  k_fill<<<(Etot+255)/256,256,0,stream>>>(srcE,dstE,ea,et,E,N,cursor,esrc,etP,eaP);
  k_cvt_wT4<<<dim3(DD,4),DD,0,stream>>>(Ws1,Wo1,Ws2,Wo2,Wsb1T,Wob1T,Wsb2T,Wob2T);
  k_pre2<<<2,256,0,stream>>>(Wd1,as1,We1,ae1,te1,Wd2,as2,We2,ae2,te2,
                             wd_as1,v_e1,t_a1,wd_as2,v_e2,t_a2);

  // ---- layer 1 ----
  k_cvt_x2<<<NB_BA,256,0,stream>>>(x,wd_as1,xb,a_i,N);
  k_gemm1<true><<<gg,256,0,stream>>>(xb,Wsb1T,ad1,a_j,ysb,N);
  k_agg<<<aggGrid,256,0,stream>>>(row_off,esrc,etP,eaP,a_i,a_j,v_e1,t_a1,ysb,aggb,N);
  k_gemm_ln<<<nbLN,256,0,stream>>>(aggb,Wob1T,bo1,b1,x,lg1,lb1,hbuf,psum,psq,N);
  k_bnfin<<<DD,256,0,stream>>>(psum,psq,bng1,bnb1,scl,shf,N,nbLN);
  k_bnapply<false,true><<<NB_BA,256,0,stream>>>(hbuf,scl,shf,nullptr,xout1,xb,wd_as2,a_i,N);

  // ---- layer 2 ----
  k_gemm1<true><<<gg,256,0,stream>>>(xb,Wsb2T,ad2,a_j,ysb,N);
  k_agg<<<aggGrid,256,0,stream>>>(row_off,esrc,etP,eaP,a_i,a_j,v_e2,t_a2,ysb,aggb,N);
  k_gemm_ln<<<nbLN,256,0,stream>>>(aggb,Wob2T,bo2,b2,xout1,lg2,lb2,hbuf,psum,psq,N);
  k_bnfin<<<DD,256,0,stream>>>(psum,psq,bng2,bnb2,scl,shf,N,nbLN);
  k_bnapply<true,false><<<NB_BA,256,0,stream>>>(hbuf,scl,shf,x,(float*)d_out,nullptr,nullptr,nullptr,N);
}

// Round 18
// 297.897 us; speedup vs baseline: 1.1071x; 1.0453x over previous
//
#include <hip/hip_runtime.h>

#define DD 256
#define HH 8
#define CC 32

typedef __attribute__((ext_vector_type(8))) short short8;
typedef __attribute__((ext_vector_type(4))) float f32x4;

static __device__ __forceinline__ unsigned short f2b(float f){
  unsigned u = __float_as_uint(f);
  u = u + 0x7FFFu + ((u >> 16) & 1u);          // RNE
  return (unsigned short)(u >> 16);
}
static __device__ __forceinline__ float b2f(unsigned short s){
  return __uint_as_float(((unsigned)s) << 16);
}

// global->LDS direct DMA: 16B/lane, wave-uniform LDS base, lane l lands at base+l*16.
static __device__ __forceinline__ void gload16(const void* g, void* l){
  using gpt = const __attribute__((address_space(1))) unsigned int*;
  using lpt = __attribute__((address_space(3))) unsigned int*;
  __builtin_amdgcn_global_load_lds((gpt)(unsigned long long)g, (lpt)(unsigned long long)l, 16, 0, 0);
}

// ---------------- utility ----------------
__global__ void k_zero_i(int* p, int n){ int i=blockIdx.x*blockDim.x+threadIdx.x; if(i<n) p[i]=0; }

// ---------------- CSR build ----------------
__global__ void k_count(const int* __restrict__ dstE, int E, int N, int* cnt){
  int e=blockIdx.x*blockDim.x+threadIdx.x;
  if(e<E+N){ int d=(e<E)? dstE[e] : (e-E); atomicAdd(&cnt[d],1); }
}

__global__ __launch_bounds__(1024) void k_scan(const int* __restrict__ cnt, int N, int* row_off, int* cursor){
  __shared__ int part[1024];
  int t=threadIdx.x;
  int chunk=(N+1023)>>10;
  int s=0;
  for(int j=0;j<chunk;j++){ int i=t*chunk+j; if(i<N) s+=cnt[i]; }
  part[t]=s; __syncthreads();
  for(int off=1; off<1024; off<<=1){
    int v=(t>=off)? part[t-off]:0;
    __syncthreads();
    part[t]+=v;
    __syncthreads();
  }
  int run=(t==0)?0:part[t-1];
  for(int j=0;j<chunk;j++){ int i=t*chunk+j; if(i<N){ row_off[i]=run; cursor[i]=run; run+=cnt[i]; } }
  if(t==1023) row_off[N]=part[1023];
}

// fill CSR: scatter packed src|type and bf16 edge-attr into CSR (dst-sorted) order.
__global__ void k_fill(const int* __restrict__ srcE, const int* __restrict__ dstE,
                       const float* __restrict__ ea, const int* __restrict__ et,
                       int E, int N, int* cursor,
                       int* stP, unsigned short* eaPb){
  int e=blockIdx.x*blockDim.x+threadIdx.x;
  if(e>=E+N) return;
  int s,d,ty;
  float q[16];
  if(e<E){
    s=srcE[e]; d=dstE[e]; ty=et[e];
    float4 q0=*(const float4*)&ea[(size_t)e*16+0];
    float4 q1=*(const float4*)&ea[(size_t)e*16+4];
    float4 q2=*(const float4*)&ea[(size_t)e*16+8];
    float4 q3=*(const float4*)&ea[(size_t)e*16+12];
    q[0]=q0.x;q[1]=q0.y;q[2]=q0.z;q[3]=q0.w;
    q[4]=q1.x;q[5]=q1.y;q[6]=q1.z;q[7]=q1.w;
    q[8]=q2.x;q[9]=q2.y;q[10]=q2.z;q[11]=q2.w;
    q[12]=q3.x;q[13]=q3.y;q[14]=q3.z;q[15]=q3.w;
  }else{
    s=e-E; d=s; ty=6;
    #pragma unroll
    for(int j=0;j<16;j++) q[j]=1.f;
  }
  int pos=atomicAdd(&cursor[d],1);
  stP[pos]= s | (ty<<24);               // N << 2^24
  short8 o0,o1;
  #pragma unroll
  for(int j=0;j<8;j++){ o0[j]=(short)f2b(q[j]); o1[j]=(short)f2b(q[8+j]); }
  *(short8*)&eaPb[(size_t)pos*16]=o0;
  *(short8*)&eaPb[(size_t)pos*16+8]=o1;
}

// ---------------- 4x weight transpose + bf16 convert in one launch ----------------
__global__ void k_cvt_wT4(const float* __restrict__ W0, const float* __restrict__ W1,
                          const float* __restrict__ W2, const float* __restrict__ W3,
                          unsigned short* __restrict__ T0, unsigned short* __restrict__ T1,
                          unsigned short* __restrict__ T2, unsigned short* __restrict__ T3){
  int m=blockIdx.y, c=blockIdx.x, k=threadIdx.x;
  const float* W = (m==0)?W0:(m==1)?W1:(m==2)?W2:W3;
  unsigned short* T = (m==0)?T0:(m==1)?T1:(m==2)?T2:T3;
  T[(size_t)c*DD+k] = f2b(W[(size_t)k*DD+c]);
}

// ---------------- folded logit weights (both layers) ----------------
__global__ void k_pre2(const float* __restrict__ Wd1, const float* __restrict__ as1,
                       const float* __restrict__ We1, const float* __restrict__ ae1,
                       const float* __restrict__ te1,
                       const float* __restrict__ Wd2, const float* __restrict__ as2,
                       const float* __restrict__ We2, const float* __restrict__ ae2,
                       const float* __restrict__ te2,
                       float* wd_as1, float* v_e1, float* t_a1,
                       float* wd_as2, float* v_e2, float* t_a2){
  int L=blockIdx.x;
  const float* Wd=L?Wd2:Wd1; const float* as_=L?as2:as1;
  const float* We=L?We2:We1; const float* ae=L?ae2:ae1; const float* te=L?te2:te1;
  float* wd_as=L?wd_as2:wd_as1; float* v_e=L?v_e2:v_e1; float* t_a=L?t_a2:t_a1;
  int t=threadIdx.x;
  for(int idx=t; idx<DD*HH; idx+=256){
    int k=idx>>3, h=idx&7;
    const float* w=&Wd[k*DD+h*CC]; const float* a=&as_[h*CC];
    float s=0;
    #pragma unroll
    for(int c=0;c<CC;c++) s+=w[c]*a[c];
    wd_as[idx]=s;
  }
  for(int idx=t; idx<16*HH; idx+=256){
    int k=idx>>3, h=idx&7;
    const float* w=&We[k*DD+h*CC]; const float* a=&ae[h*CC];
    float s=0;
    #pragma unroll
    for(int c=0;c<CC;c++) s+=w[c]*a[c];
    v_e[idx]=s;
  }
  for(int idx=t; idx<7*HH; idx+=256){
    int k=idx>>3, h=idx&7;
    const float* w=&te[k*DD+h*CC]; const float* a=&ae[h*CC];
    float s=0;
    #pragma unroll
    for(int c=0;c<CC;c++) s+=w[c]*a[c];
    t_a[idx]=s;
  }
}

// ---------------- x -> bf16 + a_i (wave-per-row, float4, shuffle reduce) ----------------
#define NB_BA 1024
__global__ __launch_bounds__(256) void k_cvt_x2(const float* __restrict__ xin, const float* __restrict__ wd_as,
                         unsigned short* __restrict__ xb, float* __restrict__ a_i, int N){
  int b=blockIdx.x, tid=threadIdx.x, wv=tid>>6, l=tid&63;
  int c0=4*l;
  float wa[4][8];
  #pragma unroll
  for(int j=0;j<4;j++)
    #pragma unroll
    for(int h=0;h<8;h++) wa[j][h]=wd_as[(c0+j)*8+h];
  for(int n=b*4+wv; n<N; n+=NB_BA*4){
    float4 v=*(const float4*)&xin[(size_t)n*DD+c0];
    ushort4 xo; xo.x=f2b(v.x); xo.y=f2b(v.y); xo.z=f2b(v.z); xo.w=f2b(v.w);
    *(ushort4*)&xb[(size_t)n*DD+c0]=xo;
    float ai[8];
    #pragma unroll
    for(int h=0;h<8;h++) ai[h]=v.x*wa[0][h]+v.y*wa[1][h]+v.z*wa[2][h]+v.w*wa[3][h];
    #pragma unroll
    for(int off=1;off<64;off<<=1){
      #pragma unroll
      for(int h=0;h<8;h++) ai[h]+=__shfl_xor(ai[h],off);
    }
    if(l==0){
      float4 A; A.x=ai[0];A.y=ai[1];A.z=ai[2];A.w=ai[3];
      float4 B; B.x=ai[4];B.y=ai[5];B.z=ai[6];B.w=ai[7];
      *(float4*)&a_i[(size_t)n*HH]=A;
      *(float4*)&a_i[(size_t)n*HH+4]=B;
    }
  }
}

// ---------------- GEMM1: C[N,256]=A@B, bf16 out + fused a_j ----------------
template<bool AJ>
__global__ __launch_bounds__(256) void k_gemm1(const unsigned short* __restrict__ A,
                                               const unsigned short* __restrict__ Bt,
                                               const float* __restrict__ ad, float* __restrict__ a_j,
                                               unsigned short* __restrict__ Cout, int N){
  __shared__ char lds[2*12288];   // per buf: A 64x32 (4KB) + B 128x32 (8KB)
  int tid=threadIdx.x;
  int w=tid>>6, l=tid&63;
  int row0=blockIdx.y*64, col0=blockIdx.x*128;

  int lr=l>>2;
  int kc=(l&3)^((l>>3)&3);
  const unsigned short* ga  = &A [(size_t)(row0+16*w+lr)*DD + kc*8];
  const unsigned short* gb0 = &Bt[(size_t)(col0+32*w+lr)*DD + kc*8];
  const unsigned short* gb1 = &Bt[(size_t)(col0+32*w+16+lr)*DD + kc*8];
  int laoff =      w*1024;
  int lboff0=4096+(32*w)*64;
  int lboff1=4096+(32*w+16)*64;

  int x15=l&15;
  int lp=x15*64 + ((l>>4)^((x15>>1)&3))*16;

  f32x4 acc[4][2];
  #pragma unroll
  for(int i=0;i<4;i++){ acc[i][0]=(f32x4)0.f; acc[i][1]=(f32x4)0.f; }

  gload16(ga,  lds+laoff);
  gload16(gb0, lds+lboff0);
  gload16(gb1, lds+lboff1);
  __syncthreads();
  int cur=0;
  for(int kt=0;kt<DD;kt+=32){
    int nxt=cur^1;
    if(kt+32<DD){
      gload16(ga +kt+32, lds+nxt*12288+laoff);
      gload16(gb0+kt+32, lds+nxt*12288+lboff0);
      gload16(gb1+kt+32, lds+nxt*12288+lboff1);
    }
    char* base=lds+cur*12288;
    short8 af[4], bf[2];
    #pragma unroll
    for(int mf=0;mf<4;mf++) af[mf]=*(short8*)(base + mf*1024 + lp);
    #pragma unroll
    for(int nf=0;nf<2;nf++) bf[nf]=*(short8*)(base + 4096 + (32*w+16*nf)*64 + lp);
    #pragma unroll
    for(int mf=0;mf<4;mf++)
      #pragma unroll
      for(int nf=0;nf<2;nf++)
        acc[mf][nf]=__builtin_amdgcn_mfma_f32_16x16x32_bf16(af[mf],bf[nf],acc[mf][nf],0,0,0);
    __syncthreads();
    cur=nxt;
  }

  int lcol=x15, lrow4=(l>>4)*4;
  float ad0=0.f, ad1=0.f;
  if(AJ){ ad0=ad[col0+32*w+lcol]; ad1=ad[col0+32*w+16+lcol]; }
  int head=(col0>>5)+w;
  #pragma unroll
  for(int mf=0;mf<4;mf++){
    #pragma unroll
    for(int nf=0;nf<2;nf++){
      int col=col0 + 32*w + 16*nf + lcol;
      #pragma unroll
      for(int rr=0;rr<4;rr++){
        int row=row0 + 16*mf + lrow4 + rr;
        if(row<N) Cout[(size_t)row*DD+col]=f2b(acc[mf][nf][rr]);
      }
    }
    if(AJ){
      #pragma unroll
      for(int rr=0;rr<4;rr++){
        float t=acc[mf][0][rr]*ad0 + acc[mf][1][rr]*ad1;
        t+=__shfl_xor(t,1); t+=__shfl_xor(t,2);
        t+=__shfl_xor(t,4); t+=__shfl_xor(t,8);
        int row=row0 + 16*mf + lrow4 + rr;
        if(x15==0 && row<N) a_j[(size_t)row*HH+head]=t;
      }
    }
  }
}

// ---------------- GEMM2 fused: bias + LayerNorm + residual + BN partials --------
__global__ __launch_bounds__(256) void k_gemm_ln(const unsigned short* __restrict__ A,
                                                 const unsigned short* __restrict__ Bt,
                                                 const float* __restrict__ bo, const float* __restrict__ bvec,
                                                 const float* __restrict__ xin,
                                                 const float* __restrict__ lg, const float* __restrict__ lb,
                                                 float* __restrict__ hout,
                                                 float* __restrict__ psum, float* __restrict__ psq, int N){
  __shared__ char lds[2*18432];   // per buf: A 32x32 (2KB) + B 256x32 (16KB)
  int tid=threadIdx.x;
  int w=tid>>6, l=tid&63;
  int row0=blockIdx.x*32;

  int lr=l>>2;
  int kc=(l&3)^((l>>3)&3);
  const unsigned short* ga = &A[(size_t)(row0+16*w+lr)*DD + kc*8];   // waves 0,1 only
  const unsigned short* gb0=&Bt[(size_t)(64*w   +lr)*DD + kc*8];
  const unsigned short* gb1=&Bt[(size_t)(64*w+16+lr)*DD + kc*8];
  const unsigned short* gb2=&Bt[(size_t)(64*w+32+lr)*DD + kc*8];
  const unsigned short* gb3=&Bt[(size_t)(64*w+48+lr)*DD + kc*8];
  int laoff =      w*1024;
  int lboff0=2048+(64*w   )*64;
  int lboff1=2048+(64*w+16)*64;
  int lboff2=2048+(64*w+32)*64;
  int lboff3=2048+(64*w+48)*64;

  int x15=l&15;
  int lp=x15*64 + ((l>>4)^((x15>>1)&3))*16;

  f32x4 acc[2][4];
  #pragma unroll
  for(int i=0;i<2;i++)
    #pragma unroll
    for(int j=0;j<4;j++) acc[i][j]=(f32x4)0.f;

  if(w<2) gload16(ga, lds+laoff);
  gload16(gb0, lds+lboff0);
  gload16(gb1, lds+lboff1);
  gload16(gb2, lds+lboff2);
  gload16(gb3, lds+lboff3);
  __syncthreads();
  int cur=0;
  for(int kt=0;kt<DD;kt+=32){
    int nxt=cur^1;
    if(kt+32<DD){
      char* nb=lds+nxt*18432;
      if(w<2) gload16(ga+kt+32, nb+laoff);
      gload16(gb0+kt+32, nb+lboff0);
      gload16(gb1+kt+32, nb+lboff1);
      gload16(gb2+kt+32, nb+lboff2);
      gload16(gb3+kt+32, nb+lboff3);
    }
    char* base=lds+cur*18432;
    short8 af[2], bf[4];
    #pragma unroll
    for(int mf=0;mf<2;mf++) af[mf]=*(short8*)(base + mf*1024 + lp);
    #pragma unroll
    for(int nf=0;nf<4;nf++) bf[nf]=*(short8*)(base + 2048 + (64*w+16*nf)*64 + lp);
    #pragma unroll
    for(int mf=0;mf<2;mf++)
      #pragma unroll
      for(int nf=0;nf<4;nf++)
        acc[mf][nf]=__builtin_amdgcn_mfma_f32_16x16x32_bf16(af[mf],bf[nf],acc[mf][nf],0,0,0);
    __syncthreads();
    cur=nxt;
  }

  // ---- epilogue ----
  int lrow4=(l>>4)*4;
  float lgv[4], lbv[4];
  #pragma unroll
  for(int nf=0;nf<4;nf++){
    int col=64*w+16*nf+x15;
    float badd=bo[col]+bvec[col];
    lgv[nf]=lg[col]; lbv[nf]=lb[col];
    #pragma unroll
    for(int mf=0;mf<2;mf++)
      #pragma unroll
      for(int rr=0;rr<4;rr++) acc[mf][nf][rr]+=badd;
  }
  __syncthreads();   // GEMM LDS dead; repurpose
  float* rs   =(float*)lds;            // [4][32]
  float* rq   =(float*)(lds+512);      // [4][32]
  float* mus  =(float*)(lds+1024);     // [32]
  float* rstds=(float*)(lds+1152);     // [32]
  #pragma unroll
  for(int mf=0;mf<2;mf++){
    #pragma unroll
    for(int rr=0;rr<4;rr++){
      float t=acc[mf][0][rr]+acc[mf][1][rr]+acc[mf][2][rr]+acc[mf][3][rr];
      float q=acc[mf][0][rr]*acc[mf][0][rr]+acc[mf][1][rr]*acc[mf][1][rr]
             +acc[mf][2][rr]*acc[mf][2][rr]+acc[mf][3][rr]*acc[mf][3][rr];
      t+=__shfl_xor(t,1); q+=__shfl_xor(q,1);
      t+=__shfl_xor(t,2); q+=__shfl_xor(q,2);
      t+=__shfl_xor(t,4); q+=__shfl_xor(q,4);
      t+=__shfl_xor(t,8); q+=__shfl_xor(q,8);
      if(x15==0){
        int row=16*mf+lrow4+rr;
        rs[w*32+row]=t; rq[w*32+row]=q;
      }
    }
  }
  __syncthreads();
  if(tid<32){
    float S=rs[tid]+rs[32+tid]+rs[64+tid]+rs[96+tid];
    float Q=rq[tid]+rq[32+tid]+rq[64+tid]+rq[96+tid];
    float mu=S*(1.f/DD);
    float var=Q*(1.f/DD)-mu*mu;
    mus[tid]=mu;
    rstds[tid]=rsqrtf(var+1e-5f);
  }
  __syncthreads();
  float cps[4]={0.f,0.f,0.f,0.f}, cqs[4]={0.f,0.f,0.f,0.f};
  #pragma unroll
  for(int mf=0;mf<2;mf++){
    #pragma unroll
    for(int rr=0;rr<4;rr++){
      int row=16*mf+lrow4+rr;
      int grow=row0+row;
      bool ok=(grow<N);
      float mu=mus[row], rstd=rstds[row];
      #pragma unroll
      for(int nf=0;nf<4;nf++){
        int col=64*w+16*nf+x15;
        float h=0.f;
        if(ok){
          h=(acc[mf][nf][rr]-mu)*rstd*lgv[nf]+lbv[nf]+xin[(size_t)grow*DD+col];
          hout[(size_t)grow*DD+col]=h;
        }
        cps[nf]+=h; cqs[nf]+=h*h;
      }
    }
  }
  #pragma unroll
  for(int nf=0;nf<4;nf++){
    cps[nf]+=__shfl_xor(cps[nf],16); cqs[nf]+=__shfl_xor(cqs[nf],16);
    cps[nf]+=__shfl_xor(cps[nf],32); cqs[nf]+=__shfl_xor(cqs[nf],32);
  }
  if(l<16){
    #pragma unroll
    for(int nf=0;nf<4;nf++){
      int col=64*w+16*nf+l;
      psum[(size_t)blockIdx.x*DD+col]=cps[nf];
      psq [(size_t)blockIdx.x*DD+col]=cqs[nf];
    }
  }
}

// ---------------- FUSED edge-logit + online softmax + aggregation ----------------
// One wave per node, single pass, software-pipelined metadata (st/eaPb/a_j of chunk
// k+1 issued before chunk k's logit+gather). Logit: lane (slot=l>>3, head=l&7), bf16
// edge-attrs. Gather: two 32-lane halves, lane-in-half lk covers cols 8lk..8lk+7
// (head hh=lk>>2); shuffles kept in uniform control flow.
__global__ __launch_bounds__(256) void k_agg(const int* __restrict__ row_off,
                      const int* __restrict__ stP, const unsigned short* __restrict__ eaPb,
                      const float* __restrict__ a_i, const float* __restrict__ a_j,
                      const float* __restrict__ v_e, const float* __restrict__ t_a,
                      const unsigned short* __restrict__ ysb, unsigned short* __restrict__ aggb, int N){
  int wv=threadIdx.x>>6, l=threadIdx.x&63;
  int n=blockIdx.x*4+wv;
  if(n>=N) return;
  int beg=row_off[n], deg=row_off[n+1]-beg;
  int slotL=l>>3, headL=l&7;
  int half=l>>5, lk=l&31;
  int hh=lk>>2;
  float veh[16];
  #pragma unroll
  for(int k=0;k<16;k++) veh[k]=v_e[k*8+headL];
  float aih=a_i[(size_t)n*HH+headL];
  float m=-3e38f, ssum=0.f;
  float acc[8];
  #pragma unroll
  for(int j=0;j<8;j++) acc[j]=0.f;

  // prefetch chunk 0 metadata (deg>=1: self-loop)
  int ic0 = (slotL<deg)? slotL : (deg-1);
  size_t pos0=(size_t)(beg+ic0);
  int st_c = stP[pos0];
  short8 e0_c=*(const short8*)&eaPb[pos0*16];
  short8 e1_c=*(const short8*)&eaPb[pos0*16+8];
  float aj_c = a_j[(size_t)(st_c&0xFFFFFF)*HH+headL];

  for(int base=0;base<deg;base+=8){
    bool ok=(base+slotL)<deg;
    // issue next-chunk metadata loads (overlap with compute below)
    int in_=base+8+slotL;
    int icn=(in_<deg)? in_ : (deg-1);
    size_t posn=(size_t)(beg+icn);
    int st_n = stP[posn];
    short8 e0_n=*(const short8*)&eaPb[posn*16];
    short8 e1_n=*(const short8*)&eaPb[posn*16+8];
    float aj_n = a_j[(size_t)(st_n&0xFFFFFF)*HH+headL];
    // logit for current chunk
    int src = st_c & 0xFFFFFF;
    int ty  = ((unsigned)st_c) >> 24;
    float t = aih + aj_c + t_a[ty*8+headL];
    #pragma unroll
    for(int j=0;j<8;j++) t += b2f((unsigned short)e0_c[j])*veh[j];
    #pragma unroll
    for(int j=0;j<8;j++) t += b2f((unsigned short)e1_c[j])*veh[8+j];
    t=(t>=0.f)? t : 0.2f*t;
    float v = ok ? t : -3e38f;
    // per-head chunk max (butterfly over slot bits); uniform exec
    float cm=v;
    cm=fmaxf(cm,__shfl_xor(cm,8));
    cm=fmaxf(cm,__shfl_xor(cm,16));
    cm=fmaxf(cm,__shfl_xor(cm,32));
    float cmg=__shfl(cm,hh);
    float mnew=fmaxf(m,cmg);
    float f=__expf(m-mnew);
    ssum*=f;
    #pragma unroll
    for(int j=0;j<8;j++) acc[j]*=f;
    m=mnew;
    int cnt=min(8,deg-base);
    #pragma unroll
    for(int u=0;u<8;u+=2){
      int e=u+half;
      // cross-lane ops OUTSIDE the divergent guard
      float vu=__shfl(v,(e<<3)|hh);
      int   si=__shfl(src,(e<<3));
      if(e<cnt){
        float wgt=__expf(vu-m);
        ssum+=wgt;
        short8 y=*(const short8*)&ysb[(size_t)si*DD+8*lk];
        #pragma unroll
        for(int j=0;j<8;j++) acc[j]+=wgt*b2f((unsigned short)y[j]);
      }
    }
    st_c=st_n; e0_c=e0_n; e1_c=e1_n; aj_c=aj_n;
  }
  // merge halves (same m on both -> plain add); uniform exec
  ssum+=__shfl_xor(ssum,32);
  #pragma unroll
  for(int j=0;j<8;j++) acc[j]+=__shfl_xor(acc[j],32);
  if(half==0){
    float inv=1.f/(ssum+1e-16f);
    short8 o;
    #pragma unroll
    for(int j=0;j<8;j++) o[j]=(short)f2b(acc[j]*inv);
    *(short8*)&aggb[(size_t)n*DD+8*lk]=o;
  }
}

// ---------------- BN finalize from nb per-block partials: one block PER COLUMN ----------------
__global__ __launch_bounds__(256) void k_bnfin(const float* __restrict__ psum, const float* __restrict__ psq,
                        const float* __restrict__ g, const float* __restrict__ b,
                        float* scale, float* shift, int N, int nb){
  __shared__ float rs[256], rq[256];
  int c=blockIdx.x, tid=threadIdx.x;
  float s=0.f,q=0.f;
  for(int i=tid;i<nb;i+=256){ s+=psum[(size_t)i*DD+c]; q+=psq[(size_t)i*DD+c]; }
  rs[tid]=s; rq[tid]=q;
  __syncthreads();
  #pragma unroll
  for(int off=128;off>0;off>>=1){
    if(tid<off){ rs[tid]+=rs[tid+off]; rq[tid]+=rq[tid+off]; }
    __syncthreads();
  }
  if(tid==0){
    float inv=1.f/(float)N;
    float mu=rs[0]*inv;
    float var=rq[0]*inv - mu*mu;
    float sc=g[c]*rsqrtf(var+1e-5f);
    scale[c]=sc;
    shift[c]=b[c]-mu*sc;
  }
}

// out = relu(h*scale + shift [+ res]); wave-per-row, float4, shuffle-reduced a_i.
template<bool RES, bool CVT>
__global__ __launch_bounds__(256) void k_bnapply(const float* __restrict__ hm, const float* __restrict__ scale,
                          const float* __restrict__ shift, const float* __restrict__ res,
                          float* __restrict__ outp, unsigned short* __restrict__ xb,
                          const float* __restrict__ wd_as, float* __restrict__ a_i, int N){
  int b=blockIdx.x, tid=threadIdx.x, wv=tid>>6, l=tid&63;
  int c0=4*l;
  float4 sc=*(const float4*)&scale[c0];
  float4 sh=*(const float4*)&shift[c0];
  float wa[4][8];
  if(CVT){
    #pragma unroll
    for(int j=0;j<4;j++)
      #pragma unroll
      for(int h=0;h<8;h++) wa[j][h]=wd_as[(c0+j)*8+h];
  }
  for(int n=b*4+wv; n<N; n+=NB_BA*4){
    float4 v=*(const float4*)&hm[(size_t)n*DD+c0];
    v.x=v.x*sc.x+sh.x; v.y=v.y*sc.y+sh.y; v.z=v.z*sc.z+sh.z; v.w=v.w*sc.w+sh.w;
    if(RES){
      float4 rr=*(const float4*)&res[(size_t)n*DD+c0];
      v.x+=rr.x; v.y+=rr.y; v.z+=rr.z; v.w+=rr.w;
    }
    v.x=fmaxf(v.x,0.f); v.y=fmaxf(v.y,0.f); v.z=fmaxf(v.z,0.f); v.w=fmaxf(v.w,0.f);
    *(float4*)&outp[(size_t)n*DD+c0]=v;
    if(CVT){
      ushort4 xo; xo.x=f2b(v.x); xo.y=f2b(v.y); xo.z=f2b(v.z); xo.w=f2b(v.w);
      *(ushort4*)&xb[(size_t)n*DD+c0]=xo;
      float ai[8];
      #pragma unroll
      for(int h=0;h<8;h++) ai[h]=v.x*wa[0][h]+v.y*wa[1][h]+v.z*wa[2][h]+v.w*wa[3][h];
      #pragma unroll
      for(int off=1;off<64;off<<=1){
        #pragma unroll
        for(int h=0;h<8;h++) ai[h]+=__shfl_xor(ai[h],off);
      }
      if(l==0){
        float4 A; A.x=ai[0];A.y=ai[1];A.z=ai[2];A.w=ai[3];
        float4 B; B.x=ai[4];B.y=ai[5];B.z=ai[6];B.w=ai[7];
        *(float4*)&a_i[(size_t)n*HH]=A;
        *(float4*)&a_i[(size_t)n*HH+4]=B;
      }
    }
  }
}

extern "C" void kernel_launch(void* const* d_in, const int* in_sizes, int n_in,
                              void* d_out, int out_size, void* d_ws, size_t ws_size,
                              hipStream_t stream) {
  const float* x  = (const float*)d_in[0];
  const int*   ei = (const int*)d_in[1];
  const float* ea = (const float*)d_in[2];
  const int*   et = (const int*)d_in[3];
  int N = in_sizes[0]/DD;
  int E = in_sizes[3];
  int Etot = E+N;
  const int* srcE = ei;
  const int* dstE = ei + E;

  const float* Ws1=(const float*)d_in[4];  const float* Wd1=(const float*)d_in[5];
  const float* as1=(const float*)d_in[6];  const float* ad1=(const float*)d_in[7];
  const float* We1=(const float*)d_in[8];  const float* ae1=(const float*)d_in[9];
  const float* te1=(const float*)d_in[10]; const float* Wo1=(const float*)d_in[11];
  const float* bo1=(const float*)d_in[12]; const float* b1 =(const float*)d_in[13];
  const float* lg1=(const float*)d_in[14]; const float* lb1=(const float*)d_in[15];
  const float* Ws2=(const float*)d_in[16]; const float* Wd2=(const float*)d_in[17];
  const float* as2=(const float*)d_in[18]; const float* ad2=(const float*)d_in[19];
  const float* We2=(const float*)d_in[20]; const float* ae2=(const float*)d_in[21];
  const float* te2=(const float*)d_in[22]; const float* Wo2=(const float*)d_in[23];
  const float* bo2=(const float*)d_in[24]; const float* b2 =(const float*)d_in[25];
  const float* lg2=(const float*)d_in[26]; const float* lb2=(const float*)d_in[27];
  const float* bng1=(const float*)d_in[28]; const float* bnb1=(const float*)d_in[29];
  const float* bng2=(const float*)d_in[30]; const float* bnb2=(const float*)d_in[31];

  char* p=(char*)d_ws;
  auto alloc=[&](size_t bytes)->void*{ void* r=(void*)p; p+=(bytes+255)&~(size_t)255; return r; };
  unsigned short* xb   =(unsigned short*)alloc((size_t)N*DD*2);
  unsigned short* ysb  =(unsigned short*)alloc((size_t)N*DD*2);
  unsigned short* aggb =(unsigned short*)alloc((size_t)N*DD*2);
  unsigned short* eaPb =(unsigned short*)alloc((size_t)Etot*16*2);
  int*   stP   =(int*)alloc((size_t)Etot*4);
  float* xout1 =(float*)alloc((size_t)N*DD*4);
  float* a_i   =(float*)alloc((size_t)N*HH*4);
  float* a_j   =(float*)alloc((size_t)N*HH*4);
  float* wd_as1=(float*)alloc(DD*HH*4);
  float* v_e1  =(float*)alloc(16*HH*4);
  float* t_a1  =(float*)alloc(7*HH*4);
  float* wd_as2=(float*)alloc(DD*HH*4);
  float* v_e2  =(float*)alloc(16*HH*4);
  float* t_a2  =(float*)alloc(7*HH*4);
  int nbLN=(N+31)/32;
  float* psum  =(float*)alloc((size_t)nbLN*DD*4);
  float* psq   =(float*)alloc((size_t)nbLN*DD*4);
  float* scl   =(float*)alloc(256*4);
  float* shf   =(float*)alloc(256*4);
  unsigned short* Wsb1T=(unsigned short*)alloc((size_t)DD*DD*2);
  unsigned short* Wob1T=(unsigned short*)alloc((size_t)DD*DD*2);
  unsigned short* Wsb2T=(unsigned short*)alloc((size_t)DD*DD*2);
  unsigned short* Wob2T=(unsigned short*)alloc((size_t)DD*DD*2);
  int* cnt     =(int*)alloc((size_t)N*4);
  int* row_off =(int*)alloc((size_t)(N+1)*4);
  int* cursor  =(int*)alloc((size_t)N*4);
  float* hbuf  =(float*)d_out;

  dim3 gg(2,(N+63)/64);
  int aggGrid=(N+3)/4;

  // upfront: CSR (with packed+bf16 edge data) + weight prep (both layers)
  k_zero_i<<<(N+255)/256,256,0,stream>>>(cnt,N);
  k_count<<<(Etot+255)/256,256,0,stream>>>(dstE,E,N,cnt);
  k_scan<<<1,1024,0,stream>>>(cnt,N,row_off,cursor);
  k_fill<<<(Etot+255)/256,256,0,stream>>>(srcE,dstE,ea,et,E,N,cursor,stP,eaPb);
  k_cvt_wT4<<<dim3(DD,4),DD,0,stream>>>(Ws1,Wo1,Ws2,Wo2,Wsb1T,Wob1T,Wsb2T,Wob2T);
  k_pre2<<<2,256,0,stream>>>(Wd1,as1,We1,ae1,te1,Wd2,as2,We2,ae2,te2,
                             wd_as1,v_e1,t_a1,wd_as2,v_e2,t_a2);

  // ---- layer 1 ----
  k_cvt_x2<<<NB_BA,256,0,stream>>>(x,wd_as1,xb,a_i,N);
  k_gemm1<true><<<gg,256,0,stream>>>(xb,Wsb1T,ad1,a_j,ysb,N);
  k_agg<<<aggGrid,256,0,stream>>>(row_off,stP,eaPb,a_i,a_j,v_e1,t_a1,ysb,aggb,N);
  k_gemm_ln<<<nbLN,256,0,stream>>>(aggb,Wob1T,bo1,b1,x,lg1,lb1,hbuf,psum,psq,N);
  k_bnfin<<<DD,256,0,stream>>>(psum,psq,bng1,bnb1,scl,shf,N,nbLN);
  k_bnapply<false,true><<<NB_BA,256,0,stream>>>(hbuf,scl,shf,nullptr,xout1,xb,wd_as2,a_i,N);

  // ---- layer 2 ----
  k_gemm1<true><<<gg,256,0,stream>>>(xb,Wsb2T,ad2,a_j,ysb,N);
  k_agg<<<aggGrid,256,0,stream>>>(row_off,stP,eaPb,a_i,a_j,v_e2,t_a2,ysb,aggb,N);
  k_gemm_ln<<<nbLN,256,0,stream>>>(aggb,Wob2T,bo2,b2,xout1,lg2,lb2,hbuf,psum,psq,N);
  k_bnfin<<<DD,256,0,stream>>>(psum,psq,bng2,bnb2,scl,shf,N,nbLN);
  k_bnapply<true,false><<<NB_BA,256,0,stream>>>(hbuf,scl,shf,x,(float*)d_out,nullptr,nullptr,nullptr,N);
}

// Round 19
// 292.414 us; speedup vs baseline: 1.1278x; 1.0188x over previous
//
#include <hip/hip_runtime.h>

#define DD 256
#define HH 8
#define CC 32

typedef __attribute__((ext_vector_type(8))) short short8;
typedef __attribute__((ext_vector_type(4))) float f32x4;

static __device__ __forceinline__ unsigned short f2b(float f){
  unsigned u = __float_as_uint(f);
  u = u + 0x7FFFu + ((u >> 16) & 1u);          // RNE
  return (unsigned short)(u >> 16);
}
static __device__ __forceinline__ float b2f(unsigned short s){
  return __uint_as_float(((unsigned)s) << 16);
}

// global->LDS direct DMA: 16B/lane, wave-uniform LDS base, lane l lands at base+l*16.
static __device__ __forceinline__ void gload16(const void* g, void* l){
  using gpt = const __attribute__((address_space(1))) unsigned int*;
  using lpt = __attribute__((address_space(3))) unsigned int*;
  __builtin_amdgcn_global_load_lds((gpt)(unsigned long long)g, (lpt)(unsigned long long)l, 16, 0, 0);
}

// ---------------- utility ----------------
__global__ void k_zero_i(int* p, int n){ int i=blockIdx.x*blockDim.x+threadIdx.x; if(i<n) p[i]=0; }

// ---------------- CSR build ----------------
__global__ void k_count(const int* __restrict__ dstE, int E, int N, int* cnt){
  int e=blockIdx.x*blockDim.x+threadIdx.x;
  if(e<E+N){ int d=(e<E)? dstE[e] : (e-E); atomicAdd(&cnt[d],1); }
}

__global__ __launch_bounds__(1024) void k_scan(const int* __restrict__ cnt, int N, int* row_off, int* cursor){
  __shared__ int part[1024];
  int t=threadIdx.x;
  int chunk=(N+1023)>>10;
  int s=0;
  for(int j=0;j<chunk;j++){ int i=t*chunk+j; if(i<N) s+=cnt[i]; }
  part[t]=s; __syncthreads();
  for(int off=1; off<1024; off<<=1){
    int v=(t>=off)? part[t-off]:0;
    __syncthreads();
    part[t]+=v;
    __syncthreads();
  }
  int run=(t==0)?0:part[t-1];
  for(int j=0;j<chunk;j++){ int i=t*chunk+j; if(i<N){ row_off[i]=run; cursor[i]=run; run+=cnt[i]; } }
  if(t==1023) row_off[N]=part[1023];
}

// fill CSR: scatter packed src|type and bf16 edge-attr into CSR (dst-sorted) order.
__global__ void k_fill(const int* __restrict__ srcE, const int* __restrict__ dstE,
                       const float* __restrict__ ea, const int* __restrict__ et,
                       int E, int N, int* cursor,
                       int* stP, unsigned short* eaPb){
  int e=blockIdx.x*blockDim.x+threadIdx.x;
  if(e>=E+N) return;
  int s,d,ty;
  float q[16];
  if(e<E){
    s=srcE[e]; d=dstE[e]; ty=et[e];
    float4 q0=*(const float4*)&ea[(size_t)e*16+0];
    float4 q1=*(const float4*)&ea[(size_t)e*16+4];
    float4 q2=*(const float4*)&ea[(size_t)e*16+8];
    float4 q3=*(const float4*)&ea[(size_t)e*16+12];
    q[0]=q0.x;q[1]=q0.y;q[2]=q0.z;q[3]=q0.w;
    q[4]=q1.x;q[5]=q1.y;q[6]=q1.z;q[7]=q1.w;
    q[8]=q2.x;q[9]=q2.y;q[10]=q2.z;q[11]=q2.w;
    q[12]=q3.x;q[13]=q3.y;q[14]=q3.z;q[15]=q3.w;
  }else{
    s=e-E; d=s; ty=6;
    #pragma unroll
    for(int j=0;j<16;j++) q[j]=1.f;
  }
  int pos=atomicAdd(&cursor[d],1);
  stP[pos]= s | (ty<<24);               // N << 2^24
  short8 o0,o1;
  #pragma unroll
  for(int j=0;j<8;j++){ o0[j]=(short)f2b(q[j]); o1[j]=(short)f2b(q[8+j]); }
  *(short8*)&eaPb[(size_t)pos*16]=o0;
  *(short8*)&eaPb[(size_t)pos*16+8]=o1;
}

// ---------------- 4x weight transpose + bf16 convert in one launch ----------------
__global__ void k_cvt_wT4(const float* __restrict__ W0, const float* __restrict__ W1,
                          const float* __restrict__ W2, const float* __restrict__ W3,
                          unsigned short* __restrict__ T0, unsigned short* __restrict__ T1,
                          unsigned short* __restrict__ T2, unsigned short* __restrict__ T3){
  int m=blockIdx.y, c=blockIdx.x, k=threadIdx.x;
  const float* W = (m==0)?W0:(m==1)?W1:(m==2)?W2:W3;
  unsigned short* T = (m==0)?T0:(m==1)?T1:(m==2)?T2:T3;
  T[(size_t)c*DD+k] = f2b(W[(size_t)k*DD+c]);
}

// ---------------- folded logit weights (both layers) ----------------
__global__ void k_pre2(const float* __restrict__ Wd1, const float* __restrict__ as1,
                       const float* __restrict__ We1, const float* __restrict__ ae1,
                       const float* __restrict__ te1,
                       const float* __restrict__ Wd2, const float* __restrict__ as2,
                       const float* __restrict__ We2, const float* __restrict__ ae2,
                       const float* __restrict__ te2,
                       float* wd_as1, float* v_e1, float* t_a1,
                       float* wd_as2, float* v_e2, float* t_a2){
  int L=blockIdx.x;
  const float* Wd=L?Wd2:Wd1; const float* as_=L?as2:as1;
  const float* We=L?We2:We1; const float* ae=L?ae2:ae1; const float* te=L?te2:te1;
  float* wd_as=L?wd_as2:wd_as1; float* v_e=L?v_e2:v_e1; float* t_a=L?t_a2:t_a1;
  int t=threadIdx.x;
  for(int idx=t; idx<DD*HH; idx+=256){
    int k=idx>>3, h=idx&7;
    const float* w=&Wd[k*DD+h*CC]; const float* a=&as_[h*CC];
    float s=0;
    #pragma unroll
    for(int c=0;c<CC;c++) s+=w[c]*a[c];
    wd_as[idx]=s;
  }
  for(int idx=t; idx<16*HH; idx+=256){
    int k=idx>>3, h=idx&7;
    const float* w=&We[k*DD+h*CC]; const float* a=&ae[h*CC];
    float s=0;
    #pragma unroll
    for(int c=0;c<CC;c++) s+=w[c]*a[c];
    v_e[idx]=s;
  }
  for(int idx=t; idx<7*HH; idx+=256){
    int k=idx>>3, h=idx&7;
    const float* w=&te[k*DD+h*CC]; const float* a=&ae[h*CC];
    float s=0;
    #pragma unroll
    for(int c=0;c<CC;c++) s+=w[c]*a[c];
    t_a[idx]=s;
  }
}

// ---------------- x -> bf16 + a_i (wave-per-row, float4, shuffle reduce) ----------------
#define NB_BA 1024
__global__ __launch_bounds__(256) void k_cvt_x2(const float* __restrict__ xin, const float* __restrict__ wd_as,
                         unsigned short* __restrict__ xb, float* __restrict__ a_i, int N){
  int b=blockIdx.x, tid=threadIdx.x, wv=tid>>6, l=tid&63;
  int c0=4*l;
  float wa[4][8];
  #pragma unroll
  for(int j=0;j<4;j++)
    #pragma unroll
    for(int h=0;h<8;h++) wa[j][h]=wd_as[(c0+j)*8+h];
  for(int n=b*4+wv; n<N; n+=NB_BA*4){
    float4 v=*(const float4*)&xin[(size_t)n*DD+c0];
    ushort4 xo; xo.x=f2b(v.x); xo.y=f2b(v.y); xo.z=f2b(v.z); xo.w=f2b(v.w);
    *(ushort4*)&xb[(size_t)n*DD+c0]=xo;
    float ai[8];
    #pragma unroll
    for(int h=0;h<8;h++) ai[h]=v.x*wa[0][h]+v.y*wa[1][h]+v.z*wa[2][h]+v.w*wa[3][h];
    #pragma unroll
    for(int off=1;off<64;off<<=1){
      #pragma unroll
      for(int h=0;h<8;h++) ai[h]+=__shfl_xor(ai[h],off);
    }
    if(l==0){
      float4 A; A.x=ai[0];A.y=ai[1];A.z=ai[2];A.w=ai[3];
      float4 B; B.x=ai[4];B.y=ai[5];B.z=ai[6];B.w=ai[7];
      *(float4*)&a_i[(size_t)n*HH]=A;
      *(float4*)&a_i[(size_t)n*HH+4]=B;
    }
  }
}

// ---------------- GEMM1: C[N,256]=A@B, bf16 out + fused a_j ----------------
template<bool AJ>
__global__ __launch_bounds__(256) void k_gemm1(const unsigned short* __restrict__ A,
                                               const unsigned short* __restrict__ Bt,
                                               const float* __restrict__ ad, float* __restrict__ a_j,
                                               unsigned short* __restrict__ Cout, int N){
  __shared__ char lds[2*12288];   // per buf: A 64x32 (4KB) + B 128x32 (8KB)
  int tid=threadIdx.x;
  int w=tid>>6, l=tid&63;
  int row0=blockIdx.y*64, col0=blockIdx.x*128;

  int lr=l>>2;
  int kc=(l&3)^((l>>3)&3);
  const unsigned short* ga  = &A [(size_t)(row0+16*w+lr)*DD + kc*8];
  const unsigned short* gb0 = &Bt[(size_t)(col0+32*w+lr)*DD + kc*8];
  const unsigned short* gb1 = &Bt[(size_t)(col0+32*w+16+lr)*DD + kc*8];
  int laoff =      w*1024;
  int lboff0=4096+(32*w)*64;
  int lboff1=4096+(32*w+16)*64;

  int x15=l&15;
  int lp=x15*64 + ((l>>4)^((x15>>1)&3))*16;

  f32x4 acc[4][2];
  #pragma unroll
  for(int i=0;i<4;i++){ acc[i][0]=(f32x4)0.f; acc[i][1]=(f32x4)0.f; }

  gload16(ga,  lds+laoff);
  gload16(gb0, lds+lboff0);
  gload16(gb1, lds+lboff1);
  __syncthreads();
  int cur=0;
  for(int kt=0;kt<DD;kt+=32){
    int nxt=cur^1;
    if(kt+32<DD){
      gload16(ga +kt+32, lds+nxt*12288+laoff);
      gload16(gb0+kt+32, lds+nxt*12288+lboff0);
      gload16(gb1+kt+32, lds+nxt*12288+lboff1);
    }
    char* base=lds+cur*12288;
    short8 af[4], bf[2];
    #pragma unroll
    for(int mf=0;mf<4;mf++) af[mf]=*(short8*)(base + mf*1024 + lp);
    #pragma unroll
    for(int nf=0;nf<2;nf++) bf[nf]=*(short8*)(base + 4096 + (32*w+16*nf)*64 + lp);
    #pragma unroll
    for(int mf=0;mf<4;mf++)
      #pragma unroll
      for(int nf=0;nf<2;nf++)
        acc[mf][nf]=__builtin_amdgcn_mfma_f32_16x16x32_bf16(af[mf],bf[nf],acc[mf][nf],0,0,0);
    __syncthreads();
    cur=nxt;
  }

  int lcol=x15, lrow4=(l>>4)*4;
  float ad0=0.f, ad1=0.f;
  if(AJ){ ad0=ad[col0+32*w+lcol]; ad1=ad[col0+32*w+16+lcol]; }
  int head=(col0>>5)+w;
  #pragma unroll
  for(int mf=0;mf<4;mf++){
    #pragma unroll
    for(int nf=0;nf<2;nf++){
      int col=col0 + 32*w + 16*nf + lcol;
      #pragma unroll
      for(int rr=0;rr<4;rr++){
        int row=row0 + 16*mf + lrow4 + rr;
        if(row<N) Cout[(size_t)row*DD+col]=f2b(acc[mf][nf][rr]);
      }
    }
    if(AJ){
      #pragma unroll
      for(int rr=0;rr<4;rr++){
        float t=acc[mf][0][rr]*ad0 + acc[mf][1][rr]*ad1;
        t+=__shfl_xor(t,1); t+=__shfl_xor(t,2);
        t+=__shfl_xor(t,4); t+=__shfl_xor(t,8);
        int row=row0 + 16*mf + lrow4 + rr;
        if(x15==0 && row<N) a_j[(size_t)row*HH+head]=t;
      }
    }
  }
}

// ---------------- GEMM2 fused: bias + LayerNorm + residual + BN partials --------
// RESBF16: residual stream is bf16 (layer 2 uses xb written by layer-1 bnapply).
template<bool RESBF16>
__global__ __launch_bounds__(256) void k_gemm_ln(const unsigned short* __restrict__ A,
                                                 const unsigned short* __restrict__ Bt,
                                                 const float* __restrict__ bo, const float* __restrict__ bvec,
                                                 const void* __restrict__ xin,
                                                 const float* __restrict__ lg, const float* __restrict__ lb,
                                                 float* __restrict__ hout,
                                                 float* __restrict__ psum, float* __restrict__ psq, int N){
  __shared__ char lds[2*18432];   // per buf: A 32x32 (2KB) + B 256x32 (16KB)
  int tid=threadIdx.x;
  int w=tid>>6, l=tid&63;
  int row0=blockIdx.x*32;

  int lr=l>>2;
  int kc=(l&3)^((l>>3)&3);
  const unsigned short* ga = &A[(size_t)(row0+16*w+lr)*DD + kc*8];   // waves 0,1 only
  const unsigned short* gb0=&Bt[(size_t)(64*w   +lr)*DD + kc*8];
  const unsigned short* gb1=&Bt[(size_t)(64*w+16+lr)*DD + kc*8];
  const unsigned short* gb2=&Bt[(size_t)(64*w+32+lr)*DD + kc*8];
  const unsigned short* gb3=&Bt[(size_t)(64*w+48+lr)*DD + kc*8];
  int laoff =      w*1024;
  int lboff0=2048+(64*w   )*64;
  int lboff1=2048+(64*w+16)*64;
  int lboff2=2048+(64*w+32)*64;
  int lboff3=2048+(64*w+48)*64;

  int x15=l&15;
  int lp=x15*64 + ((l>>4)^((x15>>1)&3))*16;

  f32x4 acc[2][4];
  #pragma unroll
  for(int i=0;i<2;i++)
    #pragma unroll
    for(int j=0;j<4;j++) acc[i][j]=(f32x4)0.f;

  if(w<2) gload16(ga, lds+laoff);
  gload16(gb0, lds+lboff0);
  gload16(gb1, lds+lboff1);
  gload16(gb2, lds+lboff2);
  gload16(gb3, lds+lboff3);
  __syncthreads();
  int cur=0;
  for(int kt=0;kt<DD;kt+=32){
    int nxt=cur^1;
    if(kt+32<DD){
      char* nb=lds+nxt*18432;
      if(w<2) gload16(ga+kt+32, nb+laoff);
      gload16(gb0+kt+32, nb+lboff0);
      gload16(gb1+kt+32, nb+lboff1);
      gload16(gb2+kt+32, nb+lboff2);
      gload16(gb3+kt+32, nb+lboff3);
    }
    char* base=lds+cur*18432;
    short8 af[2], bf[4];
    #pragma unroll
    for(int mf=0;mf<2;mf++) af[mf]=*(short8*)(base + mf*1024 + lp);
    #pragma unroll
    for(int nf=0;nf<4;nf++) bf[nf]=*(short8*)(base + 2048 + (64*w+16*nf)*64 + lp);
    #pragma unroll
    for(int mf=0;mf<2;mf++)
      #pragma unroll
      for(int nf=0;nf<4;nf++)
        acc[mf][nf]=__builtin_amdgcn_mfma_f32_16x16x32_bf16(af[mf],bf[nf],acc[mf][nf],0,0,0);
    __syncthreads();
    cur=nxt;
  }

  // ---- epilogue ----
  int lrow4=(l>>4)*4;
  float lgv[4], lbv[4];
  #pragma unroll
  for(int nf=0;nf<4;nf++){
    int col=64*w+16*nf+x15;
    float badd=bo[col]+bvec[col];
    lgv[nf]=lg[col]; lbv[nf]=lb[col];
    #pragma unroll
    for(int mf=0;mf<2;mf++)
      #pragma unroll
      for(int rr=0;rr<4;rr++) acc[mf][nf][rr]+=badd;
  }
  __syncthreads();   // GEMM LDS dead; repurpose
  float* rs   =(float*)lds;            // [4][32]
  float* rq   =(float*)(lds+512);      // [4][32]
  float* mus  =(float*)(lds+1024);     // [32]
  float* rstds=(float*)(lds+1152);     // [32]
  #pragma unroll
  for(int mf=0;mf<2;mf++){
    #pragma unroll
    for(int rr=0;rr<4;rr++){
      float t=acc[mf][0][rr]+acc[mf][1][rr]+acc[mf][2][rr]+acc[mf][3][rr];
      float q=acc[mf][0][rr]*acc[mf][0][rr]+acc[mf][1][rr]*acc[mf][1][rr]
             +acc[mf][2][rr]*acc[mf][2][rr]+acc[mf][3][rr]*acc[mf][3][rr];
      t+=__shfl_xor(t,1); q+=__shfl_xor(q,1);
      t+=__shfl_xor(t,2); q+=__shfl_xor(q,2);
      t+=__shfl_xor(t,4); q+=__shfl_xor(q,4);
      t+=__shfl_xor(t,8); q+=__shfl_xor(q,8);
      if(x15==0){
        int row=16*mf+lrow4+rr;
        rs[w*32+row]=t; rq[w*32+row]=q;
      }
    }
  }
  __syncthreads();
  if(tid<32){
    float S=rs[tid]+rs[32+tid]+rs[64+tid]+rs[96+tid];
    float Q=rq[tid]+rq[32+tid]+rq[64+tid]+rq[96+tid];
    float mu=S*(1.f/DD);
    float var=Q*(1.f/DD)-mu*mu;
    mus[tid]=mu;
    rstds[tid]=rsqrtf(var+1e-5f);
  }
  __syncthreads();
  float cps[4]={0.f,0.f,0.f,0.f}, cqs[4]={0.f,0.f,0.f,0.f};
  #pragma unroll
  for(int mf=0;mf<2;mf++){
    #pragma unroll
    for(int rr=0;rr<4;rr++){
      int row=16*mf+lrow4+rr;
      int grow=row0+row;
      bool ok=(grow<N);
      float mu=mus[row], rstd=rstds[row];
      #pragma unroll
      for(int nf=0;nf<4;nf++){
        int col=64*w+16*nf+x15;
        float h=0.f;
        if(ok){
          float r = RESBF16 ? b2f(((const unsigned short*)xin)[(size_t)grow*DD+col])
                            : ((const float*)xin)[(size_t)grow*DD+col];
          h=(acc[mf][nf][rr]-mu)*rstd*lgv[nf]+lbv[nf]+r;
          hout[(size_t)grow*DD+col]=h;
        }
        cps[nf]+=h; cqs[nf]+=h*h;
      }
    }
  }
  #pragma unroll
  for(int nf=0;nf<4;nf++){
    cps[nf]+=__shfl_xor(cps[nf],16); cqs[nf]+=__shfl_xor(cqs[nf],16);
    cps[nf]+=__shfl_xor(cps[nf],32); cqs[nf]+=__shfl_xor(cqs[nf],32);
  }
  if(l<16){
    #pragma unroll
    for(int nf=0;nf<4;nf++){
      int col=64*w+16*nf+l;
      psum[(size_t)blockIdx.x*DD+col]=cps[nf];
      psq [(size_t)blockIdx.x*DD+col]=cqs[nf];
    }
  }
}

// ---------------- FUSED edge-logit + online softmax + aggregation ----------------
// One wave per node, single pass, pipelined metadata; gather batches all 4 pair
// loads (vus/sis/y in flight) before the exp/FMA tail -> MLP 4. Shuffles uniform.
__global__ __launch_bounds__(256) void k_agg(const int* __restrict__ row_off,
                      const int* __restrict__ stP, const unsigned short* __restrict__ eaPb,
                      const float* __restrict__ a_i, const float* __restrict__ a_j,
                      const float* __restrict__ v_e, const float* __restrict__ t_a,
                      const unsigned short* __restrict__ ysb, unsigned short* __restrict__ aggb, int N){
  int wv=threadIdx.x>>6, l=threadIdx.x&63;
  int n=blockIdx.x*4+wv;
  if(n>=N) return;
  int beg=row_off[n], deg=row_off[n+1]-beg;
  int slotL=l>>3, headL=l&7;
  int half=l>>5, lk=l&31;
  int hh=lk>>2;
  float veh[16];
  #pragma unroll
  for(int k=0;k<16;k++) veh[k]=v_e[k*8+headL];
  float aih=a_i[(size_t)n*HH+headL];
  float m=-3e38f, ssum=0.f;
  float acc[8];
  #pragma unroll
  for(int j=0;j<8;j++) acc[j]=0.f;

  // prefetch chunk 0 metadata (deg>=1: self-loop)
  int ic0 = (slotL<deg)? slotL : (deg-1);
  size_t pos0=(size_t)(beg+ic0);
  int st_c = stP[pos0];
  short8 e0_c=*(const short8*)&eaPb[pos0*16];
  short8 e1_c=*(const short8*)&eaPb[pos0*16+8];
  float aj_c = a_j[(size_t)(st_c&0xFFFFFF)*HH+headL];

  for(int base=0;base<deg;base+=8){
    bool ok=(base+slotL)<deg;
    // issue next-chunk metadata loads (overlap with compute below)
    int in_=base+8+slotL;
    int icn=(in_<deg)? in_ : (deg-1);
    size_t posn=(size_t)(beg+icn);
    int st_n = stP[posn];
    short8 e0_n=*(const short8*)&eaPb[posn*16];
    short8 e1_n=*(const short8*)&eaPb[posn*16+8];
    float aj_n = a_j[(size_t)(st_n&0xFFFFFF)*HH+headL];
    // logit for current chunk
    int src = st_c & 0xFFFFFF;
    int ty  = ((unsigned)st_c) >> 24;
    float t = aih + aj_c + t_a[ty*8+headL];
    #pragma unroll
    for(int j=0;j<8;j++) t += b2f((unsigned short)e0_c[j])*veh[j];
    #pragma unroll
    for(int j=0;j<8;j++) t += b2f((unsigned short)e1_c[j])*veh[8+j];
    t=(t>=0.f)? t : 0.2f*t;
    float v = ok ? t : -3e38f;
    // per-head chunk max (butterfly over slot bits); uniform exec
    float cm=v;
    cm=fmaxf(cm,__shfl_xor(cm,8));
    cm=fmaxf(cm,__shfl_xor(cm,16));
    cm=fmaxf(cm,__shfl_xor(cm,32));
    float cmg=__shfl(cm,hh);
    float mnew=fmaxf(m,cmg);
    float f=__expf(m-mnew);
    ssum*=f;
    #pragma unroll
    for(int j=0;j<8;j++) acc[j]*=f;
    m=mnew;
    int cnt=min(8,deg-base);
    // batch all 4 pair shuffles + loads (uniform exec for shuffles), then FMA tail
    float vus[4]; int sis[4]; short8 ybuf[4];
    #pragma unroll
    for(int u=0;u<4;u++){
      int e=2*u+half;
      vus[u]=__shfl(v,(e<<3)|hh);
      sis[u]=__shfl(src,(e<<3));
    }
    #pragma unroll
    for(int u=0;u<4;u++){
      int e=2*u+half;
      if(e<cnt) ybuf[u]=*(const short8*)&ysb[(size_t)sis[u]*DD+8*lk];
    }
    #pragma unroll
    for(int u=0;u<4;u++){
      int e=2*u+half;
      if(e<cnt){
        float wgt=__expf(vus[u]-m);
        ssum+=wgt;
        #pragma unroll
        for(int j=0;j<8;j++) acc[j]+=wgt*b2f((unsigned short)ybuf[u][j]);
      }
    }
    st_c=st_n; e0_c=e0_n; e1_c=e1_n; aj_c=aj_n;
  }
  // merge halves (same m on both -> plain add); uniform exec
  ssum+=__shfl_xor(ssum,32);
  #pragma unroll
  for(int j=0;j<8;j++) acc[j]+=__shfl_xor(acc[j],32);
  if(half==0){
    float inv=1.f/(ssum+1e-16f);
    short8 o;
    #pragma unroll
    for(int j=0;j<8;j++) o[j]=(short)f2b(acc[j]*inv);
    *(short8*)&aggb[(size_t)n*DD+8*lk]=o;
  }
}

// ---------------- BN finalize from nb per-block partials: one block PER COLUMN ----------------
__global__ __launch_bounds__(256) void k_bnfin(const float* __restrict__ psum, const float* __restrict__ psq,
                        const float* __restrict__ g, const float* __restrict__ b,
                        float* scale, float* shift, int N, int nb){
  __shared__ float rs[256], rq[256];
  int c=blockIdx.x, tid=threadIdx.x;
  float s=0.f,q=0.f;
  for(int i=tid;i<nb;i+=256){ s+=psum[(size_t)i*DD+c]; q+=psq[(size_t)i*DD+c]; }
  rs[tid]=s; rq[tid]=q;
  __syncthreads();
  #pragma unroll
  for(int off=128;off>0;off>>=1){
    if(tid<off){ rs[tid]+=rs[tid+off]; rq[tid]+=rq[tid+off]; }
    __syncthreads();
  }
  if(tid==0){
    float inv=1.f/(float)N;
    float mu=rs[0]*inv;
    float var=rq[0]*inv - mu*mu;
    float sc=g[c]*rsqrtf(var+1e-5f);
    scale[c]=sc;
    shift[c]=b[c]-mu*sc;
  }
}

// out = relu(h*scale + shift [+ res]); wave-per-row, float4, shuffle-reduced a_i.
// WOUT: write f32 output stream; CVT: write bf16 copy + next-layer a_i.
template<bool RES, bool CVT, bool WOUT>
__global__ __launch_bounds__(256) void k_bnapply(const float* __restrict__ hm, const float* __restrict__ scale,
                          const float* __restrict__ shift, const float* __restrict__ res,
                          float* __restrict__ outp, unsigned short* __restrict__ xb,
                          const float* __restrict__ wd_as, float* __restrict__ a_i, int N){
  int b=blockIdx.x, tid=threadIdx.x, wv=tid>>6, l=tid&63;
  int c0=4*l;
  float4 sc=*(const float4*)&scale[c0];
  float4 sh=*(const float4*)&shift[c0];
  float wa[4][8];
  if(CVT){
    #pragma unroll
    for(int j=0;j<4;j++)
      #pragma unroll
      for(int h=0;h<8;h++) wa[j][h]=wd_as[(c0+j)*8+h];
  }
  for(int n=b*4+wv; n<N; n+=NB_BA*4){
    float4 v=*(const float4*)&hm[(size_t)n*DD+c0];
    v.x=v.x*sc.x+sh.x; v.y=v.y*sc.y+sh.y; v.z=v.z*sc.z+sh.z; v.w=v.w*sc.w+sh.w;
    if(RES){
      float4 rr=*(const float4*)&res[(size_t)n*DD+c0];
      v.x+=rr.x; v.y+=rr.y; v.z+=rr.z; v.w+=rr.w;
    }
    v.x=fmaxf(v.x,0.f); v.y=fmaxf(v.y,0.f); v.z=fmaxf(v.z,0.f); v.w=fmaxf(v.w,0.f);
    if(WOUT) *(float4*)&outp[(size_t)n*DD+c0]=v;
    if(CVT){
      ushort4 xo; xo.x=f2b(v.x); xo.y=f2b(v.y); xo.z=f2b(v.z); xo.w=f2b(v.w);
      *(ushort4*)&xb[(size_t)n*DD+c0]=xo;
      float ai[8];
      #pragma unroll
      for(int h=0;h<8;h++) ai[h]=v.x*wa[0][h]+v.y*wa[1][h]+v.z*wa[2][h]+v.w*wa[3][h];
      #pragma unroll
      for(int off=1;off<64;off<<=1){
        #pragma unroll
        for(int h=0;h<8;h++) ai[h]+=__shfl_xor(ai[h],off);
      }
      if(l==0){
        float4 A; A.x=ai[0];A.y=ai[1];A.z=ai[2];A.w=ai[3];
        float4 B; B.x=ai[4];B.y=ai[5];B.z=ai[6];B.w=ai[7];
        *(float4*)&a_i[(size_t)n*HH]=A;
        *(float4*)&a_i[(size_t)n*HH+4]=B;
      }
    }
  }
}

extern "C" void kernel_launch(void* const* d_in, const int* in_sizes, int n_in,
                              void* d_out, int out_size, void* d_ws, size_t ws_size,
                              hipStream_t stream) {
  const float* x  = (const float*)d_in[0];
  const int*   ei = (const int*)d_in[1];
  const float* ea = (const float*)d_in[2];
  const int*   et = (const int*)d_in[3];
  int N = in_sizes[0]/DD;
  int E = in_sizes[3];
  int Etot = E+N;
  const int* srcE = ei;
  const int* dstE = ei + E;

  const float* Ws1=(const float*)d_in[4];  const float* Wd1=(const float*)d_in[5];
  const float* as1=(const float*)d_in[6];  const float* ad1=(const float*)d_in[7];
  const float* We1=(const float*)d_in[8];  const float* ae1=(const float*)d_in[9];
  const float* te1=(const float*)d_in[10]; const float* Wo1=(const float*)d_in[11];
  const float* bo1=(const float*)d_in[12]; const float* b1 =(const float*)d_in[13];
  const float* lg1=(const float*)d_in[14]; const float* lb1=(const float*)d_in[15];
  const float* Ws2=(const float*)d_in[16]; const float* Wd2=(const float*)d_in[17];
  const float* as2=(const float*)d_in[18]; const float* ad2=(const float*)d_in[19];
  const float* We2=(const float*)d_in[20]; const float* ae2=(const float*)d_in[21];
  const float* te2=(const float*)d_in[22]; const float* Wo2=(const float*)d_in[23];
  const float* bo2=(const float*)d_in[24]; const float* b2 =(const float*)d_in[25];
  const float* lg2=(const float*)d_in[26]; const float* lb2=(const float*)d_in[27];
  const float* bng1=(const float*)d_in[28]; const float* bnb1=(const float*)d_in[29];
  const float* bng2=(const float*)d_in[30]; const float* bnb2=(const float*)d_in[31];

  char* p=(char*)d_ws;
  auto alloc=[&](size_t bytes)->void*{ void* r=(void*)p; p+=(bytes+255)&~(size_t)255; return r; };
  unsigned short* xb   =(unsigned short*)alloc((size_t)N*DD*2);
  unsigned short* ysb  =(unsigned short*)alloc((size_t)N*DD*2);
  unsigned short* aggb =(unsigned short*)alloc((size_t)N*DD*2);
  unsigned short* eaPb =(unsigned short*)alloc((size_t)Etot*16*2);
  int*   stP   =(int*)alloc((size_t)Etot*4);
  float* a_i   =(float*)alloc((size_t)N*HH*4);
  float* a_j   =(float*)alloc((size_t)N*HH*4);
  float* wd_as1=(float*)alloc(DD*HH*4);
  float* v_e1  =(float*)alloc(16*HH*4);
  float* t_a1  =(float*)alloc(7*HH*4);
  float* wd_as2=(float*)alloc(DD*HH*4);
  float* v_e2  =(float*)alloc(16*HH*4);
  float* t_a2  =(float*)alloc(7*HH*4);
  int nbLN=(N+31)/32;
  float* psum  =(float*)alloc((size_t)nbLN*DD*4);
  float* psq   =(float*)alloc((size_t)nbLN*DD*4);
  float* scl   =(float*)alloc(256*4);
  float* shf   =(float*)alloc(256*4);
  unsigned short* Wsb1T=(unsigned short*)alloc((size_t)DD*DD*2);
  unsigned short* Wob1T=(unsigned short*)alloc((size_t)DD*DD*2);
  unsigned short* Wsb2T=(unsigned short*)alloc((size_t)DD*DD*2);
  unsigned short* Wob2T=(unsigned short*)alloc((size_t)DD*DD*2);
  int* cnt     =(int*)alloc((size_t)N*4);
  int* row_off =(int*)alloc((size_t)(N+1)*4);
  int* cursor  =(int*)alloc((size_t)N*4);
  float* hbuf  =(float*)d_out;

  dim3 gg(2,(N+63)/64);
  int aggGrid=(N+3)/4;

  // upfront: CSR (with packed+bf16 edge data) + weight prep (both layers)
  k_zero_i<<<(N+255)/256,256,0,stream>>>(cnt,N);
  k_count<<<(Etot+255)/256,256,0,stream>>>(dstE,E,N,cnt);
  k_scan<<<1,1024,0,stream>>>(cnt,N,row_off,cursor);
  k_fill<<<(Etot+255)/256,256,0,stream>>>(srcE,dstE,ea,et,E,N,cursor,stP,eaPb);
  k_cvt_wT4<<<dim3(DD,4),DD,0,stream>>>(Ws1,Wo1,Ws2,Wo2,Wsb1T,Wob1T,Wsb2T,Wob2T);
  k_pre2<<<2,256,0,stream>>>(Wd1,as1,We1,ae1,te1,Wd2,as2,We2,ae2,te2,
                             wd_as1,v_e1,t_a1,wd_as2,v_e2,t_a2);

  // ---- layer 1 ----
  k_cvt_x2<<<NB_BA,256,0,stream>>>(x,wd_as1,xb,a_i,N);
  k_gemm1<true><<<gg,256,0,stream>>>(xb,Wsb1T,ad1,a_j,ysb,N);
  k_agg<<<aggGrid,256,0,stream>>>(row_off,stP,eaPb,a_i,a_j,v_e1,t_a1,ysb,aggb,N);
  k_gemm_ln<false><<<nbLN,256,0,stream>>>(aggb,Wob1T,bo1,b1,(const void*)x,lg1,lb1,hbuf,psum,psq,N);
  k_bnfin<<<DD,256,0,stream>>>(psum,psq,bng1,bnb1,scl,shf,N,nbLN);
  // layer-1 BN apply: bf16 copy (xb) + next-layer a_i only; no f32 output stream
  k_bnapply<false,true,false><<<NB_BA,256,0,stream>>>(hbuf,scl,shf,nullptr,nullptr,xb,wd_as2,a_i,N);

  // ---- layer 2 (residual = xb, bf16) ----
  k_gemm1<true><<<gg,256,0,stream>>>(xb,Wsb2T,ad2,a_j,ysb,N);
  k_agg<<<aggGrid,256,0,stream>>>(row_off,stP,eaPb,a_i,a_j,v_e2,t_a2,ysb,aggb,N);
  k_gemm_ln<true><<<nbLN,256,0,stream>>>(aggb,Wob2T,bo2,b2,(const void*)xb,lg2,lb2,hbuf,psum,psq,N);
  k_bnfin<<<DD,256,0,stream>>>(psum,psq,bng2,bnb2,scl,shf,N,nbLN);
  k_bnapply<true,false,true><<<NB_BA,256,0,stream>>>(hbuf,scl,shf,x,(float*)d_out,nullptr,nullptr,nullptr,N);
}

// Round 20
// 290.787 us; speedup vs baseline: 1.1342x; 1.0056x over previous
//
#include <hip/hip_runtime.h>

#define DD 256
#define HH 8
#define CC 32

typedef __attribute__((ext_vector_type(8))) short short8;
typedef __attribute__((ext_vector_type(4))) float f32x4;

static __device__ __forceinline__ unsigned short f2b(float f){
  unsigned u = __float_as_uint(f);
  u = u + 0x7FFFu + ((u >> 16) & 1u);          // RNE
  return (unsigned short)(u >> 16);
}
static __device__ __forceinline__ float b2f(unsigned short s){
  return __uint_as_float(((unsigned)s) << 16);
}

// global->LDS direct DMA: 16B/lane, wave-uniform LDS base, lane l lands at base+l*16.
static __device__ __forceinline__ void gload16(const void* g, void* l){
  using gpt = const __attribute__((address_space(1))) unsigned int*;
  using lpt = __attribute__((address_space(3))) unsigned int*;
  __builtin_amdgcn_global_load_lds((gpt)(unsigned long long)g, (lpt)(unsigned long long)l, 16, 0, 0);
}

// ---------------- utility ----------------
__global__ void k_zero_i(int* p, int n){ int i=blockIdx.x*blockDim.x+threadIdx.x; if(i<n) p[i]=0; }

// ---------------- CSR build ----------------
__global__ void k_count(const int* __restrict__ dstE, int E, int N, int* cnt){
  int e=blockIdx.x*blockDim.x+threadIdx.x;
  if(e<E+N){ int d=(e<E)? dstE[e] : (e-E); atomicAdd(&cnt[d],1); }
}

__global__ __launch_bounds__(1024) void k_scan(const int* __restrict__ cnt, int N, int* row_off, int* cursor){
  __shared__ int part[1024];
  int t=threadIdx.x;
  int chunk=(N+1023)>>10;
  int s=0;
  for(int j=0;j<chunk;j++){ int i=t*chunk+j; if(i<N) s+=cnt[i]; }
  part[t]=s; __syncthreads();
  for(int off=1; off<1024; off<<=1){
    int v=(t>=off)? part[t-off]:0;
    __syncthreads();
    part[t]+=v;
    __syncthreads();
  }
  int run=(t==0)?0:part[t-1];
  for(int j=0;j<chunk;j++){ int i=t*chunk+j; if(i<N){ row_off[i]=run; cursor[i]=run; run+=cnt[i]; } }
  if(t==1023) row_off[N]=part[1023];
}

// fill CSR: scatter packed src|type and bf16 edge-attr into CSR (dst-sorted) order.
__global__ void k_fill(const int* __restrict__ srcE, const int* __restrict__ dstE,
                       const float* __restrict__ ea, const int* __restrict__ et,
                       int E, int N, int* cursor,
                       int* stP, unsigned short* eaPb){
  int e=blockIdx.x*blockDim.x+threadIdx.x;
  if(e>=E+N) return;
  int s,d,ty;
  float q[16];
  if(e<E){
    s=srcE[e]; d=dstE[e]; ty=et[e];
    float4 q0=*(const float4*)&ea[(size_t)e*16+0];
    float4 q1=*(const float4*)&ea[(size_t)e*16+4];
    float4 q2=*(const float4*)&ea[(size_t)e*16+8];
    float4 q3=*(const float4*)&ea[(size_t)e*16+12];
    q[0]=q0.x;q[1]=q0.y;q[2]=q0.z;q[3]=q0.w;
    q[4]=q1.x;q[5]=q1.y;q[6]=q1.z;q[7]=q1.w;
    q[8]=q2.x;q[9]=q2.y;q[10]=q2.z;q[11]=q2.w;
    q[12]=q3.x;q[13]=q3.y;q[14]=q3.z;q[15]=q3.w;
  }else{
    s=e-E; d=s; ty=6;
    #pragma unroll
    for(int j=0;j<16;j++) q[j]=1.f;
  }
  int pos=atomicAdd(&cursor[d],1);
  stP[pos]= s | (ty<<24);               // N << 2^24
  short8 o0,o1;
  #pragma unroll
  for(int j=0;j<8;j++){ o0[j]=(short)f2b(q[j]); o1[j]=(short)f2b(q[8+j]); }
  *(short8*)&eaPb[(size_t)pos*16]=o0;
  *(short8*)&eaPb[(size_t)pos*16+8]=o1;
}

// ---------------- 4x weight transpose + bf16 convert in one launch ----------------
__global__ void k_cvt_wT4(const float* __restrict__ W0, const float* __restrict__ W1,
                          const float* __restrict__ W2, const float* __restrict__ W3,
                          unsigned short* __restrict__ T0, unsigned short* __restrict__ T1,
                          unsigned short* __restrict__ T2, unsigned short* __restrict__ T3){
  int m=blockIdx.y, c=blockIdx.x, k=threadIdx.x;
  const float* W = (m==0)?W0:(m==1)?W1:(m==2)?W2:W3;
  unsigned short* T = (m==0)?T0:(m==1)?T1:(m==2)?T2:T3;
  T[(size_t)c*DD+k] = f2b(W[(size_t)k*DD+c]);
}

// ---------------- folded logit weights (both layers) ----------------
__global__ void k_pre2(const float* __restrict__ Wd1, const float* __restrict__ as1,
                       const float* __restrict__ We1, const float* __restrict__ ae1,
                       const float* __restrict__ te1,
                       const float* __restrict__ Wd2, const float* __restrict__ as2,
                       const float* __restrict__ We2, const float* __restrict__ ae2,
                       const float* __restrict__ te2,
                       float* wd_as1, float* v_e1, float* t_a1,
                       float* wd_as2, float* v_e2, float* t_a2){
  int L=blockIdx.x;
  const float* Wd=L?Wd2:Wd1; const float* as_=L?as2:as1;
  const float* We=L?We2:We1; const float* ae=L?ae2:ae1; const float* te=L?te2:te1;
  float* wd_as=L?wd_as2:wd_as1; float* v_e=L?v_e2:v_e1; float* t_a=L?t_a2:t_a1;
  int t=threadIdx.x;
  for(int idx=t; idx<DD*HH; idx+=256){
    int k=idx>>3, h=idx&7;
    const float* w=&Wd[k*DD+h*CC]; const float* a=&as_[h*CC];
    float s=0;
    #pragma unroll
    for(int c=0;c<CC;c++) s+=w[c]*a[c];
    wd_as[idx]=s;
  }
  for(int idx=t; idx<16*HH; idx+=256){
    int k=idx>>3, h=idx&7;
    const float* w=&We[k*DD+h*CC]; const float* a=&ae[h*CC];
    float s=0;
    #pragma unroll
    for(int c=0;c<CC;c++) s+=w[c]*a[c];
    v_e[idx]=s;
  }
  for(int idx=t; idx<7*HH; idx+=256){
    int k=idx>>3, h=idx&7;
    const float* w=&te[k*DD+h*CC]; const float* a=&ae[h*CC];
    float s=0;
    #pragma unroll
    for(int c=0;c<CC;c++) s+=w[c]*a[c];
    t_a[idx]=s;
  }
}

// ---------------- x -> bf16 + a_i (wave-per-row, float4, shuffle reduce) ----------------
#define NB_BA 1024
__global__ __launch_bounds__(256) void k_cvt_x2(const float* __restrict__ xin, const float* __restrict__ wd_as,
                         unsigned short* __restrict__ xb, float* __restrict__ a_i, int N){
  int b=blockIdx.x, tid=threadIdx.x, wv=tid>>6, l=tid&63;
  int c0=4*l;
  float wa[4][8];
  #pragma unroll
  for(int j=0;j<4;j++)
    #pragma unroll
    for(int h=0;h<8;h++) wa[j][h]=wd_as[(c0+j)*8+h];
  for(int n=b*4+wv; n<N; n+=NB_BA*4){
    float4 v=*(const float4*)&xin[(size_t)n*DD+c0];
    ushort4 xo; xo.x=f2b(v.x); xo.y=f2b(v.y); xo.z=f2b(v.z); xo.w=f2b(v.w);
    *(ushort4*)&xb[(size_t)n*DD+c0]=xo;
    float ai[8];
    #pragma unroll
    for(int h=0;h<8;h++) ai[h]=v.x*wa[0][h]+v.y*wa[1][h]+v.z*wa[2][h]+v.w*wa[3][h];
    #pragma unroll
    for(int off=1;off<64;off<<=1){
      #pragma unroll
      for(int h=0;h<8;h++) ai[h]+=__shfl_xor(ai[h],off);
    }
    if(l==0){
      float4 A; A.x=ai[0];A.y=ai[1];A.z=ai[2];A.w=ai[3];
      float4 B; B.x=ai[4];B.y=ai[5];B.z=ai[6];B.w=ai[7];
      *(float4*)&a_i[(size_t)n*HH]=A;
      *(float4*)&a_i[(size_t)n*HH+4]=B;
    }
  }
}

// ---------------- GEMM1: C[N,256]=A@B, bf16 out + fused a_j ----------------
template<bool AJ>
__global__ __launch_bounds__(256) void k_gemm1(const unsigned short* __restrict__ A,
                                               const unsigned short* __restrict__ Bt,
                                               const float* __restrict__ ad, float* __restrict__ a_j,
                                               unsigned short* __restrict__ Cout, int N){
  __shared__ char lds[2*12288];   // per buf: A 64x32 (4KB) + B 128x32 (8KB)
  int tid=threadIdx.x;
  int w=tid>>6, l=tid&63;
  int row0=blockIdx.y*64, col0=blockIdx.x*128;

  int lr=l>>2;
  int kc=(l&3)^((l>>3)&3);
  const unsigned short* ga  = &A [(size_t)(row0+16*w+lr)*DD + kc*8];
  const unsigned short* gb0 = &Bt[(size_t)(col0+32*w+lr)*DD + kc*8];
  const unsigned short* gb1 = &Bt[(size_t)(col0+32*w+16+lr)*DD + kc*8];
  int laoff =      w*1024;
  int lboff0=4096+(32*w)*64;
  int lboff1=4096+(32*w+16)*64;

  int x15=l&15;
  int lp=x15*64 + ((l>>4)^((x15>>1)&3))*16;

  f32x4 acc[4][2];
  #pragma unroll
  for(int i=0;i<4;i++){ acc[i][0]=(f32x4)0.f; acc[i][1]=(f32x4)0.f; }

  gload16(ga,  lds+laoff);
  gload16(gb0, lds+lboff0);
  gload16(gb1, lds+lboff1);
  __syncthreads();
  int cur=0;
  for(int kt=0;kt<DD;kt+=32){
    int nxt=cur^1;
    if(kt+32<DD){
      gload16(ga +kt+32, lds+nxt*12288+laoff);
      gload16(gb0+kt+32, lds+nxt*12288+lboff0);
      gload16(gb1+kt+32, lds+nxt*12288+lboff1);
    }
    char* base=lds+cur*12288;
    short8 af[4], bf[2];
    #pragma unroll
    for(int mf=0;mf<4;mf++) af[mf]=*(short8*)(base + mf*1024 + lp);
    #pragma unroll
    for(int nf=0;nf<2;nf++) bf[nf]=*(short8*)(base + 4096 + (32*w+16*nf)*64 + lp);
    #pragma unroll
    for(int mf=0;mf<4;mf++)
      #pragma unroll
      for(int nf=0;nf<2;nf++)
        acc[mf][nf]=__builtin_amdgcn_mfma_f32_16x16x32_bf16(af[mf],bf[nf],acc[mf][nf],0,0,0);
    __syncthreads();
    cur=nxt;
  }

  int lcol=x15, lrow4=(l>>4)*4;
  float ad0=0.f, ad1=0.f;
  if(AJ){ ad0=ad[col0+32*w+lcol]; ad1=ad[col0+32*w+16+lcol]; }
  int head=(col0>>5)+w;
  #pragma unroll
  for(int mf=0;mf<4;mf++){
    #pragma unroll
    for(int nf=0;nf<2;nf++){
      int col=col0 + 32*w + 16*nf + lcol;
      #pragma unroll
      for(int rr=0;rr<4;rr++){
        int row=row0 + 16*mf + lrow4 + rr;
        if(row<N) Cout[(size_t)row*DD+col]=f2b(acc[mf][nf][rr]);
      }
    }
    if(AJ){
      #pragma unroll
      for(int rr=0;rr<4;rr++){
        float t=acc[mf][0][rr]*ad0 + acc[mf][1][rr]*ad1;
        t+=__shfl_xor(t,1); t+=__shfl_xor(t,2);
        t+=__shfl_xor(t,4); t+=__shfl_xor(t,8);
        int row=row0 + 16*mf + lrow4 + rr;
        if(x15==0 && row<N) a_j[(size_t)row*HH+head]=t;
      }
    }
  }
}

// ---------------- GEMM2 fused: bias + LayerNorm + residual + BN partials --------
// RESBF16: residual stream is bf16 (layer 2 uses xb written by layer-1 bnapply).
template<bool RESBF16>
__global__ __launch_bounds__(256) void k_gemm_ln(const unsigned short* __restrict__ A,
                                                 const unsigned short* __restrict__ Bt,
                                                 const float* __restrict__ bo, const float* __restrict__ bvec,
                                                 const void* __restrict__ xin,
                                                 const float* __restrict__ lg, const float* __restrict__ lb,
                                                 float* __restrict__ hout,
                                                 float* __restrict__ psum, float* __restrict__ psq, int N){
  __shared__ char lds[2*18432];   // per buf: A 32x32 (2KB) + B 256x32 (16KB)
  int tid=threadIdx.x;
  int w=tid>>6, l=tid&63;
  int row0=blockIdx.x*32;

  int lr=l>>2;
  int kc=(l&3)^((l>>3)&3);
  const unsigned short* ga = &A[(size_t)(row0+16*w+lr)*DD + kc*8];   // waves 0,1 only
  const unsigned short* gb0=&Bt[(size_t)(64*w   +lr)*DD + kc*8];
  const unsigned short* gb1=&Bt[(size_t)(64*w+16+lr)*DD + kc*8];
  const unsigned short* gb2=&Bt[(size_t)(64*w+32+lr)*DD + kc*8];
  const unsigned short* gb3=&Bt[(size_t)(64*w+48+lr)*DD + kc*8];
  int laoff =      w*1024;
  int lboff0=2048+(64*w   )*64;
  int lboff1=2048+(64*w+16)*64;
  int lboff2=2048+(64*w+32)*64;
  int lboff3=2048+(64*w+48)*64;

  int x15=l&15;
  int lp=x15*64 + ((l>>4)^((x15>>1)&3))*16;

  f32x4 acc[2][4];
  #pragma unroll
  for(int i=0;i<2;i++)
    #pragma unroll
    for(int j=0;j<4;j++) acc[i][j]=(f32x4)0.f;

  if(w<2) gload16(ga, lds+laoff);
  gload16(gb0, lds+lboff0);
  gload16(gb1, lds+lboff1);
  gload16(gb2, lds+lboff2);
  gload16(gb3, lds+lboff3);
  __syncthreads();
  int cur=0;
  for(int kt=0;kt<DD;kt+=32){
    int nxt=cur^1;
    if(kt+32<DD){
      char* nb=lds+nxt*18432;
      if(w<2) gload16(ga+kt+32, nb+laoff);
      gload16(gb0+kt+32, nb+lboff0);
      gload16(gb1+kt+32, nb+lboff1);
      gload16(gb2+kt+32, nb+lboff2);
      gload16(gb3+kt+32, nb+lboff3);
    }
    char* base=lds+cur*18432;
    short8 af[2], bf[4];
    #pragma unroll
    for(int mf=0;mf<2;mf++) af[mf]=*(short8*)(base + mf*1024 + lp);
    #pragma unroll
    for(int nf=0;nf<4;nf++) bf[nf]=*(short8*)(base + 2048 + (64*w+16*nf)*64 + lp);
    #pragma unroll
    for(int mf=0;mf<2;mf++)
      #pragma unroll
      for(int nf=0;nf<4;nf++)
        acc[mf][nf]=__builtin_amdgcn_mfma_f32_16x16x32_bf16(af[mf],bf[nf],acc[mf][nf],0,0,0);
    __syncthreads();
    cur=nxt;
  }

  // ---- epilogue ----
  int lrow4=(l>>4)*4;
  float lgv[4], lbv[4];
  #pragma unroll
  for(int nf=0;nf<4;nf++){
    int col=64*w+16*nf+x15;
    float badd=bo[col]+bvec[col];
    lgv[nf]=lg[col]; lbv[nf]=lb[col];
    #pragma unroll
    for(int mf=0;mf<2;mf++)
      #pragma unroll
      for(int rr=0;rr<4;rr++) acc[mf][nf][rr]+=badd;
  }
  __syncthreads();   // GEMM LDS dead; repurpose
  float* rs   =(float*)lds;            // [4][32]
  float* rq   =(float*)(lds+512);      // [4][32]
  float* mus  =(float*)(lds+1024);     // [32]
  float* rstds=(float*)(lds+1152);     // [32]
  #pragma unroll
  for(int mf=0;mf<2;mf++){
    #pragma unroll
    for(int rr=0;rr<4;rr++){
      float t=acc[mf][0][rr]+acc[mf][1][rr]+acc[mf][2][rr]+acc[mf][3][rr];
      float q=acc[mf][0][rr]*acc[mf][0][rr]+acc[mf][1][rr]*acc[mf][1][rr]
             +acc[mf][2][rr]*acc[mf][2][rr]+acc[mf][3][rr]*acc[mf][3][rr];
      t+=__shfl_xor(t,1); q+=__shfl_xor(q,1);
      t+=__shfl_xor(t,2); q+=__shfl_xor(q,2);
      t+=__shfl_xor(t,4); q+=__shfl_xor(q,4);
      t+=__shfl_xor(t,8); q+=__shfl_xor(q,8);
      if(x15==0){
        int row=16*mf+lrow4+rr;
        rs[w*32+row]=t; rq[w*32+row]=q;
      }
    }
  }
  __syncthreads();
  if(tid<32){
    float S=rs[tid]+rs[32+tid]+rs[64+tid]+rs[96+tid];
    float Q=rq[tid]+rq[32+tid]+rq[64+tid]+rq[96+tid];
    float mu=S*(1.f/DD);
    float var=Q*(1.f/DD)-mu*mu;
    mus[tid]=mu;
    rstds[tid]=rsqrtf(var+1e-5f);
  }
  __syncthreads();
  float cps[4]={0.f,0.f,0.f,0.f}, cqs[4]={0.f,0.f,0.f,0.f};
  #pragma unroll
  for(int mf=0;mf<2;mf++){
    #pragma unroll
    for(int rr=0;rr<4;rr++){
      int row=16*mf+lrow4+rr;
      int grow=row0+row;
      bool ok=(grow<N);
      float mu=mus[row], rstd=rstds[row];
      #pragma unroll
      for(int nf=0;nf<4;nf++){
        int col=64*w+16*nf+x15;
        float h=0.f;
        if(ok){
          float r = RESBF16 ? b2f(((const unsigned short*)xin)[(size_t)grow*DD+col])
                            : ((const float*)xin)[(size_t)grow*DD+col];
          h=(acc[mf][nf][rr]-mu)*rstd*lgv[nf]+lbv[nf]+r;
          hout[(size_t)grow*DD+col]=h;
        }
        cps[nf]+=h; cqs[nf]+=h*h;
      }
    }
  }
  #pragma unroll
  for(int nf=0;nf<4;nf++){
    cps[nf]+=__shfl_xor(cps[nf],16); cqs[nf]+=__shfl_xor(cqs[nf],16);
    cps[nf]+=__shfl_xor(cps[nf],32); cqs[nf]+=__shfl_xor(cqs[nf],32);
  }
  if(l<16){
    #pragma unroll
    for(int nf=0;nf<4;nf++){
      int col=64*w+16*nf+l;
      psum[(size_t)blockIdx.x*DD+col]=cps[nf];
      psq [(size_t)blockIdx.x*DD+col]=cqs[nf];
    }
  }
}

// ---------------- FUSED edge-logit + online softmax + aggregation ----------------
// One wave per node, single pass. Metadata AND ysb rows prefetched one chunk ahead:
// the next chunk's src indices come from stP (already prefetched), so its 4 gather
// rows are issued at loop top and consumed one iteration later -> gather latency
// hides under logit/butterfly/FMA. All shuffles in uniform control flow.
__global__ __launch_bounds__(256) void k_agg(const int* __restrict__ row_off,
                      const int* __restrict__ stP, const unsigned short* __restrict__ eaPb,
                      const float* __restrict__ a_i, const float* __restrict__ a_j,
                      const float* __restrict__ v_e, const float* __restrict__ t_a,
                      const unsigned short* __restrict__ ysb, unsigned short* __restrict__ aggb, int N){
  int wv=threadIdx.x>>6, l=threadIdx.x&63;
  int n=blockIdx.x*4+wv;
  if(n>=N) return;
  int beg=row_off[n], deg=row_off[n+1]-beg;
  int slotL=l>>3, headL=l&7;
  int half=l>>5, lk=l&31;
  int hh=lk>>2;
  float veh[16];
  #pragma unroll
  for(int k=0;k<16;k++) veh[k]=v_e[k*8+headL];
  float aih=a_i[(size_t)n*HH+headL];
  float m=-3e38f, ssum=0.f;
  float acc[8];
  #pragma unroll
  for(int j=0;j<8;j++) acc[j]=0.f;

  // prefetch chunk 0: metadata + gather rows (deg>=1: self-loop; clamped idx valid)
  int ic0 = (slotL<deg)? slotL : (deg-1);
  size_t pos0=(size_t)(beg+ic0);
  int st_c = stP[pos0];
  short8 e0_c=*(const short8*)&eaPb[pos0*16];
  short8 e1_c=*(const short8*)&eaPb[pos0*16+8];
  float aj_c = a_j[(size_t)(st_c&0xFFFFFF)*HH+headL];
  short8 ybuf_c[4];
  {
    int src0 = st_c & 0xFFFFFF;
    #pragma unroll
    for(int u=0;u<4;u++){
      int si=__shfl(src0,((2*u+half)<<3));
      ybuf_c[u]=*(const short8*)&ysb[(size_t)si*DD+8*lk];
    }
  }

  for(int base=0;base<deg;base+=8){
    bool ok=(base+slotL)<deg;
    // prefetch next chunk: metadata + gather rows (addresses from st_n)
    int in_=base+8+slotL;
    int icn=(in_<deg)? in_ : (deg-1);
    size_t posn=(size_t)(beg+icn);
    int st_n = stP[posn];
    short8 e0_n=*(const short8*)&eaPb[posn*16];
    short8 e1_n=*(const short8*)&eaPb[posn*16+8];
    float aj_n = a_j[(size_t)(st_n&0xFFFFFF)*HH+headL];
    int src_n = st_n & 0xFFFFFF;
    short8 ybuf_n[4];
    #pragma unroll
    for(int u=0;u<4;u++){
      int si=__shfl(src_n,((2*u+half)<<3));
      ybuf_n[u]=*(const short8*)&ysb[(size_t)si*DD+8*lk];
    }
    // logit for current chunk
    int src = st_c & 0xFFFFFF;
    int ty  = ((unsigned)st_c) >> 24;
    float t = aih + aj_c + t_a[ty*8+headL];
    #pragma unroll
    for(int j=0;j<8;j++) t += b2f((unsigned short)e0_c[j])*veh[j];
    #pragma unroll
    for(int j=0;j<8;j++) t += b2f((unsigned short)e1_c[j])*veh[8+j];
    t=(t>=0.f)? t : 0.2f*t;
    float v = ok ? t : -3e38f;
    // per-head chunk max (butterfly over slot bits); uniform exec
    float cm=v;
    cm=fmaxf(cm,__shfl_xor(cm,8));
    cm=fmaxf(cm,__shfl_xor(cm,16));
    cm=fmaxf(cm,__shfl_xor(cm,32));
    float cmg=__shfl(cm,hh);
    float mnew=fmaxf(m,cmg);
    float f=__expf(m-mnew);
    ssum*=f;
    #pragma unroll
    for(int j=0;j<8;j++) acc[j]*=f;
    m=mnew;
    int cnt=min(8,deg-base);
    // weights via shuffles (uniform), then FMA tail on prefetched rows
    float vus[4];
    #pragma unroll
    for(int u=0;u<4;u++){
      int e=2*u+half;
      vus[u]=__shfl(v,(e<<3)|hh);
    }
    #pragma unroll
    for(int u=0;u<4;u++){
      int e=2*u+half;
      if(e<cnt){
        float wgt=__expf(vus[u]-m);
        ssum+=wgt;
        #pragma unroll
        for(int j=0;j<8;j++) acc[j]+=wgt*b2f((unsigned short)ybuf_c[u][j]);
      }
    }
    st_c=st_n; e0_c=e0_n; e1_c=e1_n; aj_c=aj_n;
    #pragma unroll
    for(int u=0;u<4;u++) ybuf_c[u]=ybuf_n[u];
  }
  // merge halves (same m on both -> plain add); uniform exec
  ssum+=__shfl_xor(ssum,32);
  #pragma unroll
  for(int j=0;j<8;j++) acc[j]+=__shfl_xor(acc[j],32);
  if(half==0){
    float inv=1.f/(ssum+1e-16f);
    short8 o;
    #pragma unroll
    for(int j=0;j<8;j++) o[j]=(short)f2b(acc[j]*inv);
    *(short8*)&aggb[(size_t)n*DD+8*lk]=o;
  }
}

// ---------------- BN finalize from nb per-block partials: one block PER COLUMN ----------------
__global__ __launch_bounds__(256) void k_bnfin(const float* __restrict__ psum, const float* __restrict__ psq,
                        const float* __restrict__ g, const float* __restrict__ b,
                        float* scale, float* shift, int N, int nb){
  __shared__ float rs[256], rq[256];
  int c=blockIdx.x, tid=threadIdx.x;
  float s=0.f,q=0.f;
  for(int i=tid;i<nb;i+=256){ s+=psum[(size_t)i*DD+c]; q+=psq[(size_t)i*DD+c]; }
  rs[tid]=s; rq[tid]=q;
  __syncthreads();
  #pragma unroll
  for(int off=128;off>0;off>>=1){
    if(tid<off){ rs[tid]+=rs[tid+off]; rq[tid]+=rq[tid+off]; }
    __syncthreads();
  }
  if(tid==0){
    float inv=1.f/(float)N;
    float mu=rs[0]*inv;
    float var=rq[0]*inv - mu*mu;
    float sc=g[c]*rsqrtf(var+1e-5f);
    scale[c]=sc;
    shift[c]=b[c]-mu*sc;
  }
}

// out = relu(h*scale + shift [+ res]); wave-per-row, float4, shuffle-reduced a_i.
// WOUT: write f32 output stream; CVT: write bf16 copy + next-layer a_i.
template<bool RES, bool CVT, bool WOUT>
__global__ __launch_bounds__(256) void k_bnapply(const float* __restrict__ hm, const float* __restrict__ scale,
                          const float* __restrict__ shift, const float* __restrict__ res,
                          float* __restrict__ outp, unsigned short* __restrict__ xb,
                          const float* __restrict__ wd_as, float* __restrict__ a_i, int N){
  int b=blockIdx.x, tid=threadIdx.x, wv=tid>>6, l=tid&63;
  int c0=4*l;
  float4 sc=*(const float4*)&scale[c0];
  float4 sh=*(const float4*)&shift[c0];
  float wa[4][8];
  if(CVT){
    #pragma unroll
    for(int j=0;j<4;j++)
      #pragma unroll
      for(int h=0;h<8;h++) wa[j][h]=wd_as[(c0+j)*8+h];
  }
  for(int n=b*4+wv; n<N; n+=NB_BA*4){
    float4 v=*(const float4*)&hm[(size_t)n*DD+c0];
    v.x=v.x*sc.x+sh.x; v.y=v.y*sc.y+sh.y; v.z=v.z*sc.z+sh.z; v.w=v.w*sc.w+sh.w;
    if(RES){
      float4 rr=*(const float4*)&res[(size_t)n*DD+c0];
      v.x+=rr.x; v.y+=rr.y; v.z+=rr.z; v.w+=rr.w;
    }
    v.x=fmaxf(v.x,0.f); v.y=fmaxf(v.y,0.f); v.z=fmaxf(v.z,0.f); v.w=fmaxf(v.w,0.f);
    if(WOUT) *(float4*)&outp[(size_t)n*DD+c0]=v;
    if(CVT){
      ushort4 xo; xo.x=f2b(v.x); xo.y=f2b(v.y); xo.z=f2b(v.z); xo.w=f2b(v.w);
      *(ushort4*)&xb[(size_t)n*DD+c0]=xo;
      float ai[8];
      #pragma unroll
      for(int h=0;h<8;h++) ai[h]=v.x*wa[0][h]+v.y*wa[1][h]+v.z*wa[2][h]+v.w*wa[3][h];
      #pragma unroll
      for(int off=1;off<64;off<<=1){
        #pragma unroll
        for(int h=0;h<8;h++) ai[h]+=__shfl_xor(ai[h],off);
      }
      if(l==0){
        float4 A; A.x=ai[0];A.y=ai[1];A.z=ai[2];A.w=ai[3];
        float4 B; B.x=ai[4];B.y=ai[5];B.z=ai[6];B.w=ai[7];
        *(float4*)&a_i[(size_t)n*HH]=A;
        *(float4*)&a_i[(size_t)n*HH+4]=B;
      }
    }
  }
}

extern "C" void kernel_launch(void* const* d_in, const int* in_sizes, int n_in,
                              void* d_out, int out_size, void* d_ws, size_t ws_size,
                              hipStream_t stream) {
  const float* x  = (const float*)d_in[0];
  const int*   ei = (const int*)d_in[1];
  const float* ea = (const float*)d_in[2];
  const int*   et = (const int*)d_in[3];
  int N = in_sizes[0]/DD;
  int E = in_sizes[3];
  int Etot = E+N;
  const int* srcE = ei;
  const int* dstE = ei + E;

  const float* Ws1=(const float*)d_in[4];  const float* Wd1=(const float*)d_in[5];
  const float* as1=(const float*)d_in[6];  const float* ad1=(const float*)d_in[7];
  const float* We1=(const float*)d_in[8];  const float* ae1=(const float*)d_in[9];
  const float* te1=(const float*)d_in[10]; const float* Wo1=(const float*)d_in[11];
  const float* bo1=(const float*)d_in[12]; const float* b1 =(const float*)d_in[13];
  const float* lg1=(const float*)d_in[14]; const float* lb1=(const float*)d_in[15];
  const float* Ws2=(const float*)d_in[16]; const float* Wd2=(const float*)d_in[17];
  const float* as2=(const float*)d_in[18]; const float* ad2=(const float*)d_in[19];
  const float* We2=(const float*)d_in[20]; const float* ae2=(const float*)d_in[21];
  const float* te2=(const float*)d_in[22]; const float* Wo2=(const float*)d_in[23];
  const float* bo2=(const float*)d_in[24]; const float* b2 =(const float*)d_in[25];
  const float* lg2=(const float*)d_in[26]; const float* lb2=(const float*)d_in[27];
  const float* bng1=(const float*)d_in[28]; const float* bnb1=(const float*)d_in[29];
  const float* bng2=(const float*)d_in[30]; const float* bnb2=(const float*)d_in[31];

  char* p=(char*)d_ws;
  auto alloc=[&](size_t bytes)->void*{ void* r=(void*)p; p+=(bytes+255)&~(size_t)255; return r; };
  unsigned short* xb   =(unsigned short*)alloc((size_t)N*DD*2);
  unsigned short* ysb  =(unsigned short*)alloc((size_t)N*DD*2);
  unsigned short* aggb =(unsigned short*)alloc((size_t)N*DD*2);
  unsigned short* eaPb =(unsigned short*)alloc((size_t)Etot*16*2);
  int*   stP   =(int*)alloc((size_t)Etot*4);
  float* a_i   =(float*)alloc((size_t)N*HH*4);
  float* a_j   =(float*)alloc((size_t)N*HH*4);
  float* wd_as1=(float*)alloc(DD*HH*4);
  float* v_e1  =(float*)alloc(16*HH*4);
  float* t_a1  =(float*)alloc(7*HH*4);
  float* wd_as2=(float*)alloc(DD*HH*4);
  float* v_e2  =(float*)alloc(16*HH*4);
  float* t_a2  =(float*)alloc(7*HH*4);
  int nbLN=(N+31)/32;
  float* psum  =(float*)alloc((size_t)nbLN*DD*4);
  float* psq   =(float*)alloc((size_t)nbLN*DD*4);
  float* scl   =(float*)alloc(256*4);
  float* shf   =(float*)alloc(256*4);
  unsigned short* Wsb1T=(unsigned short*)alloc((size_t)DD*DD*2);
  unsigned short* Wob1T=(unsigned short*)alloc((size_t)DD*DD*2);
  unsigned short* Wsb2T=(unsigned short*)alloc((size_t)DD*DD*2);
  unsigned short* Wob2T=(unsigned short*)alloc((size_t)DD*DD*2);
  int* cnt     =(int*)alloc((size_t)N*4);
  int* row_off =(int*)alloc((size_t)(N+1)*4);
  int* cursor  =(int*)alloc((size_t)N*4);
  float* hbuf  =(float*)d_out;

  dim3 gg(2,(N+63)/64);
  int aggGrid=(N+3)/4;

  // upfront: CSR (with packed+bf16 edge data) + weight prep (both layers)
  k_zero_i<<<(N+255)/256,256,0,stream>>>(cnt,N);
  k_count<<<(Etot+255)/256,256,0,stream>>>(dstE,E,N,cnt);
  k_scan<<<1,1024,0,stream>>>(cnt,N,row_off,cursor);
  k_fill<<<(Etot+255)/256,256,0,stream>>>(srcE,dstE,ea,et,E,N,cursor,stP,eaPb);
  k_cvt_wT4<<<dim3(DD,4),DD,0,stream>>>(Ws1,Wo1,Ws2,Wo2,Wsb1T,Wob1T,Wsb2T,Wob2T);
  k_pre2<<<2,256,0,stream>>>(Wd1,as1,We1,ae1,te1,Wd2,as2,We2,ae2,te2,
                             wd_as1,v_e1,t_a1,wd_as2,v_e2,t_a2);

  // ---- layer 1 ----
  k_cvt_x2<<<NB_BA,256,0,stream>>>(x,wd_as1,xb,a_i,N);
  k_gemm1<true><<<gg,256,0,stream>>>(xb,Wsb1T,ad1,a_j,ysb,N);
  k_agg<<<aggGrid,256,0,stream>>>(row_off,stP,eaPb,a_i,a_j,v_e1,t_a1,ysb,aggb,N);
  k_gemm_ln<false><<<nbLN,256,0,stream>>>(aggb,Wob1T,bo1,b1,(const void*)x,lg1,lb1,hbuf,psum,psq,N);
  k_bnfin<<<DD,256,0,stream>>>(psum,psq,bng1,bnb1,scl,shf,N,nbLN);
  // layer-1 BN apply: bf16 copy (xb) + next-layer a_i only; no f32 output stream
  k_bnapply<false,true,false><<<NB_BA,256,0,stream>>>(hbuf,scl,shf,nullptr,nullptr,xb,wd_as2,a_i,N);

  // ---- layer 2 (residual = xb, bf16) ----
  k_gemm1<true><<<gg,256,0,stream>>>(xb,Wsb2T,ad2,a_j,ysb,N);
  k_agg<<<aggGrid,256,0,stream>>>(row_off,stP,eaPb,a_i,a_j,v_e2,t_a2,ysb,aggb,N);
  k_gemm_ln<true><<<nbLN,256,0,stream>>>(aggb,Wob2T,bo2,b2,(const void*)xb,lg2,lb2,hbuf,psum,psq,N);
  k_bnfin<<<DD,256,0,stream>>>(psum,psq,bng2,bnb2,scl,shf,N,nbLN);
  k_bnapply<true,false,true><<<NB_BA,256,0,stream>>>(hbuf,scl,shf,x,(float*)d_out,nullptr,nullptr,nullptr,N);
}

// Round 21
// 286.486 us; speedup vs baseline: 1.1512x; 1.0150x over previous
//
#include <hip/hip_runtime.h>

#define DD 256
#define HH 8
#define CC 32

typedef __attribute__((ext_vector_type(8))) short short8;
typedef __attribute__((ext_vector_type(4))) float f32x4;

static __device__ __forceinline__ unsigned short f2b(float f){
  unsigned u = __float_as_uint(f);
  u = u + 0x7FFFu + ((u >> 16) & 1u);          // RNE
  return (unsigned short)(u >> 16);
}
static __device__ __forceinline__ float b2f(unsigned short s){
  return __uint_as_float(((unsigned)s) << 16);
}

// global->LDS direct DMA: 16B/lane, wave-uniform LDS base, lane l lands at base+l*16.
static __device__ __forceinline__ void gload16(const void* g, void* l){
  using gpt = const __attribute__((address_space(1))) unsigned int*;
  using lpt = __attribute__((address_space(3))) unsigned int*;
  __builtin_amdgcn_global_load_lds((gpt)(unsigned long long)g, (lpt)(unsigned long long)l, 16, 0, 0);
}

// ---------------- CSR build ----------------
__global__ void k_count(const int* __restrict__ dstE, int E, int N, int* cnt){
  int e=blockIdx.x*blockDim.x+threadIdx.x;
  if(e<E+N){ int d=(e<E)? dstE[e] : (e-E); atomicAdd(&cnt[d],1); }
}

__global__ __launch_bounds__(1024) void k_scan(const int* __restrict__ cnt, int N, int* row_off, int* cursor){
  __shared__ int part[1024];
  int t=threadIdx.x;
  int chunk=(N+1023)>>10;
  int s=0;
  for(int j=0;j<chunk;j++){ int i=t*chunk+j; if(i<N) s+=cnt[i]; }
  part[t]=s; __syncthreads();
  for(int off=1; off<1024; off<<=1){
    int v=(t>=off)? part[t-off]:0;
    __syncthreads();
    part[t]+=v;
    __syncthreads();
  }
  int run=(t==0)?0:part[t-1];
  for(int j=0;j<chunk;j++){ int i=t*chunk+j; if(i<N){ row_off[i]=run; cursor[i]=run; run+=cnt[i]; } }
  if(t==1023) row_off[N]=part[1023];
}

// fill CSR: scatter packed src|type and bf16 edge-attr into CSR (dst-sorted) order.
__global__ void k_fill(const int* __restrict__ srcE, const int* __restrict__ dstE,
                       const float* __restrict__ ea, const int* __restrict__ et,
                       int E, int N, int* cursor,
                       int* stP, unsigned short* eaPb){
  int e=blockIdx.x*blockDim.x+threadIdx.x;
  if(e>=E+N) return;
  int s,d,ty;
  float q[16];
  if(e<E){
    s=srcE[e]; d=dstE[e]; ty=et[e];
    float4 q0=*(const float4*)&ea[(size_t)e*16+0];
    float4 q1=*(const float4*)&ea[(size_t)e*16+4];
    float4 q2=*(const float4*)&ea[(size_t)e*16+8];
    float4 q3=*(const float4*)&ea[(size_t)e*16+12];
    q[0]=q0.x;q[1]=q0.y;q[2]=q0.z;q[3]=q0.w;
    q[4]=q1.x;q[5]=q1.y;q[6]=q1.z;q[7]=q1.w;
    q[8]=q2.x;q[9]=q2.y;q[10]=q2.z;q[11]=q2.w;
    q[12]=q3.x;q[13]=q3.y;q[14]=q3.z;q[15]=q3.w;
  }else{
    s=e-E; d=s; ty=6;
    #pragma unroll
    for(int j=0;j<16;j++) q[j]=1.f;
  }
  int pos=atomicAdd(&cursor[d],1);
  stP[pos]= s | (ty<<24);               // N << 2^24
  short8 o0,o1;
  #pragma unroll
  for(int j=0;j<8;j++){ o0[j]=(short)f2b(q[j]); o1[j]=(short)f2b(q[8+j]); }
  *(short8*)&eaPb[(size_t)pos*16]=o0;
  *(short8*)&eaPb[(size_t)pos*16+8]=o1;
}

// ---------------- 4x weight transpose + bf16 convert in one launch ----------------
__global__ void k_cvt_wT4(const float* __restrict__ W0, const float* __restrict__ W1,
                          const float* __restrict__ W2, const float* __restrict__ W3,
                          unsigned short* __restrict__ T0, unsigned short* __restrict__ T1,
                          unsigned short* __restrict__ T2, unsigned short* __restrict__ T3){
  int m=blockIdx.y, c=blockIdx.x, k=threadIdx.x;
  const float* W = (m==0)?W0:(m==1)?W1:(m==2)?W2:W3;
  unsigned short* T = (m==0)?T0:(m==1)?T1:(m==2)?T2:T3;
  T[(size_t)c*DD+k] = f2b(W[(size_t)k*DD+c]);
}

// ---------------- folded logit weights (both layers) ----------------
__global__ void k_pre2(const float* __restrict__ Wd1, const float* __restrict__ as1,
                       const float* __restrict__ We1, const float* __restrict__ ae1,
                       const float* __restrict__ te1,
                       const float* __restrict__ Wd2, const float* __restrict__ as2,
                       const float* __restrict__ We2, const float* __restrict__ ae2,
                       const float* __restrict__ te2,
                       float* wd_as1, float* v_e1, float* t_a1,
                       float* wd_as2, float* v_e2, float* t_a2){
  int L=blockIdx.x;
  const float* Wd=L?Wd2:Wd1; const float* as_=L?as2:as1;
  const float* We=L?We2:We1; const float* ae=L?ae2:ae1; const float* te=L?te2:te1;
  float* wd_as=L?wd_as2:wd_as1; float* v_e=L?v_e2:v_e1; float* t_a=L?t_a2:t_a1;
  int t=threadIdx.x;
  for(int idx=t; idx<DD*HH; idx+=256){
    int k=idx>>3, h=idx&7;
    const float* w=&Wd[k*DD+h*CC]; const float* a=&as_[h*CC];
    float s=0;
    #pragma unroll
    for(int c=0;c<CC;c++) s+=w[c]*a[c];
    wd_as[idx]=s;
  }
  for(int idx=t; idx<16*HH; idx+=256){
    int k=idx>>3, h=idx&7;
    const float* w=&We[k*DD+h*CC]; const float* a=&ae[h*CC];
    float s=0;
    #pragma unroll
    for(int c=0;c<CC;c++) s+=w[c]*a[c];
    v_e[idx]=s;
  }
  for(int idx=t; idx<7*HH; idx+=256){
    int k=idx>>3, h=idx&7;
    const float* w=&te[k*DD+h*CC]; const float* a=&ae[h*CC];
    float s=0;
    #pragma unroll
    for(int c=0;c<CC;c++) s+=w[c]*a[c];
    t_a[idx]=s;
  }
}

// ---------------- x -> bf16 + a_i (wave-per-row, float4, shuffle reduce) ----------------
#define NB_BA 1024
__global__ __launch_bounds__(256) void k_cvt_x2(const float* __restrict__ xin, const float* __restrict__ wd_as,
                         unsigned short* __restrict__ xb, float* __restrict__ a_i, int N){
  int b=blockIdx.x, tid=threadIdx.x, wv=tid>>6, l=tid&63;
  int c0=4*l;
  float wa[4][8];
  #pragma unroll
  for(int j=0;j<4;j++)
    #pragma unroll
    for(int h=0;h<8;h++) wa[j][h]=wd_as[(c0+j)*8+h];
  for(int n=b*4+wv; n<N; n+=NB_BA*4){
    float4 v=*(const float4*)&xin[(size_t)n*DD+c0];
    ushort4 xo; xo.x=f2b(v.x); xo.y=f2b(v.y); xo.z=f2b(v.z); xo.w=f2b(v.w);
    *(ushort4*)&xb[(size_t)n*DD+c0]=xo;
    float ai[8];
    #pragma unroll
    for(int h=0;h<8;h++) ai[h]=v.x*wa[0][h]+v.y*wa[1][h]+v.z*wa[2][h]+v.w*wa[3][h];
    #pragma unroll
    for(int off=1;off<64;off<<=1){
      #pragma unroll
      for(int h=0;h<8;h++) ai[h]+=__shfl_xor(ai[h],off);
    }
    if(l==0){
      float4 A; A.x=ai[0];A.y=ai[1];A.z=ai[2];A.w=ai[3];
      float4 B; B.x=ai[4];B.y=ai[5];B.z=ai[6];B.w=ai[7];
      *(float4*)&a_i[(size_t)n*HH]=A;
      *(float4*)&a_i[(size_t)n*HH+4]=B;
    }
  }
}

// ---------------- GEMM1: C[N,256]=A@B, bf16 out + fused a_j ----------------
template<bool AJ>
__global__ __launch_bounds__(256) void k_gemm1(const unsigned short* __restrict__ A,
                                               const unsigned short* __restrict__ Bt,
                                               const float* __restrict__ ad, float* __restrict__ a_j,
                                               unsigned short* __restrict__ Cout, int N){
  __shared__ char lds[2*12288];   // per buf: A 64x32 (4KB) + B 128x32 (8KB)
  int tid=threadIdx.x;
  int w=tid>>6, l=tid&63;
  int row0=blockIdx.y*64, col0=blockIdx.x*128;

  int lr=l>>2;
  int kc=(l&3)^((l>>3)&3);
  const unsigned short* ga  = &A [(size_t)(row0+16*w+lr)*DD + kc*8];
  const unsigned short* gb0 = &Bt[(size_t)(col0+32*w+lr)*DD + kc*8];
  const unsigned short* gb1 = &Bt[(size_t)(col0+32*w+16+lr)*DD + kc*8];
  int laoff =      w*1024;
  int lboff0=4096+(32*w)*64;
  int lboff1=4096+(32*w+16)*64;

  int x15=l&15;
  int lp=x15*64 + ((l>>4)^((x15>>1)&3))*16;

  f32x4 acc[4][2];
  #pragma unroll
  for(int i=0;i<4;i++){ acc[i][0]=(f32x4)0.f; acc[i][1]=(f32x4)0.f; }

  gload16(ga,  lds+laoff);
  gload16(gb0, lds+lboff0);
  gload16(gb1, lds+lboff1);
  __syncthreads();
  int cur=0;
  for(int kt=0;kt<DD;kt+=32){
    int nxt=cur^1;
    if(kt+32<DD){
      gload16(ga +kt+32, lds+nxt*12288+laoff);
      gload16(gb0+kt+32, lds+nxt*12288+lboff0);
      gload16(gb1+kt+32, lds+nxt*12288+lboff1);
    }
    char* base=lds+cur*12288;
    short8 af[4], bf[2];
    #pragma unroll
    for(int mf=0;mf<4;mf++) af[mf]=*(short8*)(base + mf*1024 + lp);
    #pragma unroll
    for(int nf=0;nf<2;nf++) bf[nf]=*(short8*)(base + 4096 + (32*w+16*nf)*64 + lp);
    #pragma unroll
    for(int mf=0;mf<4;mf++)
      #pragma unroll
      for(int nf=0;nf<2;nf++)
        acc[mf][nf]=__builtin_amdgcn_mfma_f32_16x16x32_bf16(af[mf],bf[nf],acc[mf][nf],0,0,0);
    __syncthreads();
    cur=nxt;
  }

  int lcol=x15, lrow4=(l>>4)*4;
  float ad0=0.f, ad1=0.f;
  if(AJ){ ad0=ad[col0+32*w+lcol]; ad1=ad[col0+32*w+16+lcol]; }
  int head=(col0>>5)+w;
  #pragma unroll
  for(int mf=0;mf<4;mf++){
    #pragma unroll
    for(int nf=0;nf<2;nf++){
      int col=col0 + 32*w + 16*nf + lcol;
      #pragma unroll
      for(int rr=0;rr<4;rr++){
        int row=row0 + 16*mf + lrow4 + rr;
        if(row<N) Cout[(size_t)row*DD+col]=f2b(acc[mf][nf][rr]);
      }
    }
    if(AJ){
      #pragma unroll
      for(int rr=0;rr<4;rr++){
        float t=acc[mf][0][rr]*ad0 + acc[mf][1][rr]*ad1;
        t+=__shfl_xor(t,1); t+=__shfl_xor(t,2);
        t+=__shfl_xor(t,4); t+=__shfl_xor(t,8);
        int row=row0 + 16*mf + lrow4 + rr;
        if(x15==0 && row<N) a_j[(size_t)row*HH+head]=t;
      }
    }
  }
}

// ---------------- GEMM2 fused: bias + LayerNorm + residual + BN partials --------
// RESBF16: residual stream is bf16 (layer 2 uses xb written by layer-1 bnapply).
template<bool RESBF16>
__global__ __launch_bounds__(256) void k_gemm_ln(const unsigned short* __restrict__ A,
                                                 const unsigned short* __restrict__ Bt,
                                                 const float* __restrict__ bo, const float* __restrict__ bvec,
                                                 const void* __restrict__ xin,
                                                 const float* __restrict__ lg, const float* __restrict__ lb,
                                                 float* __restrict__ hout,
                                                 float* __restrict__ psum, float* __restrict__ psq, int N){
  __shared__ char lds[2*18432];   // per buf: A 32x32 (2KB) + B 256x32 (16KB)
  int tid=threadIdx.x;
  int w=tid>>6, l=tid&63;
  int row0=blockIdx.x*32;

  int lr=l>>2;
  int kc=(l&3)^((l>>3)&3);
  const unsigned short* ga = &A[(size_t)(row0+16*w+lr)*DD + kc*8];   // waves 0,1 only
  const unsigned short* gb0=&Bt[(size_t)(64*w   +lr)*DD + kc*8];
  const unsigned short* gb1=&Bt[(size_t)(64*w+16+lr)*DD + kc*8];
  const unsigned short* gb2=&Bt[(size_t)(64*w+32+lr)*DD + kc*8];
  const unsigned short* gb3=&Bt[(size_t)(64*w+48+lr)*DD + kc*8];
  int laoff =      w*1024;
  int lboff0=2048+(64*w   )*64;
  int lboff1=2048+(64*w+16)*64;
  int lboff2=2048+(64*w+32)*64;
  int lboff3=2048+(64*w+48)*64;

  int x15=l&15;
  int lp=x15*64 + ((l>>4)^((x15>>1)&3))*16;

  f32x4 acc[2][4];
  #pragma unroll
  for(int i=0;i<2;i++)
    #pragma unroll
    for(int j=0;j<4;j++) acc[i][j]=(f32x4)0.f;

  if(w<2) gload16(ga, lds+laoff);
  gload16(gb0, lds+lboff0);
  gload16(gb1, lds+lboff1);
  gload16(gb2, lds+lboff2);
  gload16(gb3, lds+lboff3);
  __syncthreads();
  int cur=0;
  for(int kt=0;kt<DD;kt+=32){
    int nxt=cur^1;
    if(kt+32<DD){
      char* nb=lds+nxt*18432;
      if(w<2) gload16(ga+kt+32, nb+laoff);
      gload16(gb0+kt+32, nb+lboff0);
      gload16(gb1+kt+32, nb+lboff1);
      gload16(gb2+kt+32, nb+lboff2);
      gload16(gb3+kt+32, nb+lboff3);
    }
    char* base=lds+cur*18432;
    short8 af[2], bf[4];
    #pragma unroll
    for(int mf=0;mf<2;mf++) af[mf]=*(short8*)(base + mf*1024 + lp);
    #pragma unroll
    for(int nf=0;nf<4;nf++) bf[nf]=*(short8*)(base + 2048 + (64*w+16*nf)*64 + lp);
    #pragma unroll
    for(int mf=0;mf<2;mf++)
      #pragma unroll
      for(int nf=0;nf<4;nf++)
        acc[mf][nf]=__builtin_amdgcn_mfma_f32_16x16x32_bf16(af[mf],bf[nf],acc[mf][nf],0,0,0);
    __syncthreads();
    cur=nxt;
  }

  // ---- epilogue ----
  int lrow4=(l>>4)*4;
  float lgv[4], lbv[4];
  #pragma unroll
  for(int nf=0;nf<4;nf++){
    int col=64*w+16*nf+x15;
    float badd=bo[col]+bvec[col];
    lgv[nf]=lg[col]; lbv[nf]=lb[col];
    #pragma unroll
    for(int mf=0;mf<2;mf++)
      #pragma unroll
      for(int rr=0;rr<4;rr++) acc[mf][nf][rr]+=badd;
  }
  __syncthreads();   // GEMM LDS dead; repurpose
  float* rs   =(float*)lds;            // [4][32]
  float* rq   =(float*)(lds+512);      // [4][32]
  float* mus  =(float*)(lds+1024);     // [32]
  float* rstds=(float*)(lds+1152);     // [32]
  #pragma unroll
  for(int mf=0;mf<2;mf++){
    #pragma unroll
    for(int rr=0;rr<4;rr++){
      float t=acc[mf][0][rr]+acc[mf][1][rr]+acc[mf][2][rr]+acc[mf][3][rr];
      float q=acc[mf][0][rr]*acc[mf][0][rr]+acc[mf][1][rr]*acc[mf][1][rr]
             +acc[mf][2][rr]*acc[mf][2][rr]+acc[mf][3][rr]*acc[mf][3][rr];
      t+=__shfl_xor(t,1); q+=__shfl_xor(q,1);
      t+=__shfl_xor(t,2); q+=__shfl_xor(q,2);
      t+=__shfl_xor(t,4); q+=__shfl_xor(q,4);
      t+=__shfl_xor(t,8); q+=__shfl_xor(q,8);
      if(x15==0){
        int row=16*mf+lrow4+rr;
        rs[w*32+row]=t; rq[w*32+row]=q;
      }
    }
  }
  __syncthreads();
  if(tid<32){
    float S=rs[tid]+rs[32+tid]+rs[64+tid]+rs[96+tid];
    float Q=rq[tid]+rq[32+tid]+rq[64+tid]+rq[96+tid];
    float mu=S*(1.f/DD);
    float var=Q*(1.f/DD)-mu*mu;
    mus[tid]=mu;
    rstds[tid]=rsqrtf(var+1e-5f);
  }
  __syncthreads();
  float cps[4]={0.f,0.f,0.f,0.f}, cqs[4]={0.f,0.f,0.f,0.f};
  #pragma unroll
  for(int mf=0;mf<2;mf++){
    #pragma unroll
    for(int rr=0;rr<4;rr++){
      int row=16*mf+lrow4+rr;
      int grow=row0+row;
      bool ok=(grow<N);
      float mu=mus[row], rstd=rstds[row];
      #pragma unroll
      for(int nf=0;nf<4;nf++){
        int col=64*w+16*nf+x15;
        float h=0.f;
        if(ok){
          float r = RESBF16 ? b2f(((const unsigned short*)xin)[(size_t)grow*DD+col])
                            : ((const float*)xin)[(size_t)grow*DD+col];
          h=(acc[mf][nf][rr]-mu)*rstd*lgv[nf]+lbv[nf]+r;
          hout[(size_t)grow*DD+col]=h;
        }
        cps[nf]+=h; cqs[nf]+=h*h;
      }
    }
  }
  #pragma unroll
  for(int nf=0;nf<4;nf++){
    cps[nf]+=__shfl_xor(cps[nf],16); cqs[nf]+=__shfl_xor(cqs[nf],16);
    cps[nf]+=__shfl_xor(cps[nf],32); cqs[nf]+=__shfl_xor(cqs[nf],32);
  }
  if(l<16){
    #pragma unroll
    for(int nf=0;nf<4;nf++){
      int col=64*w+16*nf+l;
      psum[(size_t)blockIdx.x*DD+col]=cps[nf];
      psq [(size_t)blockIdx.x*DD+col]=cqs[nf];
    }
  }
}

// ---------------- FUSED edge-logit + online softmax + aggregation ----------------
// ONE WAVE PER BLOCK (block=64, grid=N): each node's wave retires independently,
// eliminating the max-of-4-degrees block-residency tail. Metadata + ysb rows
// prefetched one chunk ahead; all shuffles in uniform control flow.
__global__ __launch_bounds__(64) void k_agg(const int* __restrict__ row_off,
                      const int* __restrict__ stP, const unsigned short* __restrict__ eaPb,
                      const float* __restrict__ a_i, const float* __restrict__ a_j,
                      const float* __restrict__ v_e, const float* __restrict__ t_a,
                      const unsigned short* __restrict__ ysb, unsigned short* __restrict__ aggb, int N){
  int l=threadIdx.x;
  int n=blockIdx.x;
  if(n>=N) return;
  int beg=row_off[n], deg=row_off[n+1]-beg;
  int slotL=l>>3, headL=l&7;
  int half=l>>5, lk=l&31;
  int hh=lk>>2;
  float veh[16];
  #pragma unroll
  for(int k=0;k<16;k++) veh[k]=v_e[k*8+headL];
  float aih=a_i[(size_t)n*HH+headL];
  float m=-3e38f, ssum=0.f;
  float acc[8];
  #pragma unroll
  for(int j=0;j<8;j++) acc[j]=0.f;

  // prefetch chunk 0: metadata + gather rows (deg>=1: self-loop; clamped idx valid)
  int ic0 = (slotL<deg)? slotL : (deg-1);
  size_t pos0=(size_t)(beg+ic0);
  int st_c = stP[pos0];
  short8 e0_c=*(const short8*)&eaPb[pos0*16];
  short8 e1_c=*(const short8*)&eaPb[pos0*16+8];
  float aj_c = a_j[(size_t)(st_c&0xFFFFFF)*HH+headL];
  short8 ybuf_c[4];
  {
    int src0 = st_c & 0xFFFFFF;
    #pragma unroll
    for(int u=0;u<4;u++){
      int si=__shfl(src0,((2*u+half)<<3));
      ybuf_c[u]=*(const short8*)&ysb[(size_t)si*DD+8*lk];
    }
  }

  for(int base=0;base<deg;base+=8){
    bool ok=(base+slotL)<deg;
    // prefetch next chunk: metadata + gather rows (addresses from st_n)
    int in_=base+8+slotL;
    int icn=(in_<deg)? in_ : (deg-1);
    size_t posn=(size_t)(beg+icn);
    int st_n = stP[posn];
    short8 e0_n=*(const short8*)&eaPb[posn*16];
    short8 e1_n=*(const short8*)&eaPb[posn*16+8];
    float aj_n = a_j[(size_t)(st_n&0xFFFFFF)*HH+headL];
    int src_n = st_n & 0xFFFFFF;
    short8 ybuf_n[4];
    #pragma unroll
    for(int u=0;u<4;u++){
      int si=__shfl(src_n,((2*u+half)<<3));
      ybuf_n[u]=*(const short8*)&ysb[(size_t)si*DD+8*lk];
    }
    // logit for current chunk
    int src = st_c & 0xFFFFFF;
    int ty  = ((unsigned)st_c) >> 24;
    float t = aih + aj_c + t_a[ty*8+headL];
    #pragma unroll
    for(int j=0;j<8;j++) t += b2f((unsigned short)e0_c[j])*veh[j];
    #pragma unroll
    for(int j=0;j<8;j++) t += b2f((unsigned short)e1_c[j])*veh[8+j];
    t=(t>=0.f)? t : 0.2f*t;
    float v = ok ? t : -3e38f;
    // per-head chunk max (butterfly over slot bits); uniform exec
    float cm=v;
    cm=fmaxf(cm,__shfl_xor(cm,8));
    cm=fmaxf(cm,__shfl_xor(cm,16));
    cm=fmaxf(cm,__shfl_xor(cm,32));
    float cmg=__shfl(cm,hh);
    float mnew=fmaxf(m,cmg);
    float f=__expf(m-mnew);
    ssum*=f;
    #pragma unroll
    for(int j=0;j<8;j++) acc[j]*=f;
    m=mnew;
    int cnt=min(8,deg-base);
    // weights via shuffles (uniform), then FMA tail on prefetched rows
    float vus[4];
    #pragma unroll
    for(int u=0;u<4;u++){
      int e=2*u+half;
      vus[u]=__shfl(v,(e<<3)|hh);
    }
    #pragma unroll
    for(int u=0;u<4;u++){
      int e=2*u+half;
      if(e<cnt){
        float wgt=__expf(vus[u]-m);
        ssum+=wgt;
        #pragma unroll
        for(int j=0;j<8;j++) acc[j]+=wgt*b2f((unsigned short)ybuf_c[u][j]);
      }
    }
    st_c=st_n; e0_c=e0_n; e1_c=e1_n; aj_c=aj_n;
    #pragma unroll
    for(int u=0;u<4;u++) ybuf_c[u]=ybuf_n[u];
  }
  // merge halves (same m on both -> plain add); uniform exec
  ssum+=__shfl_xor(ssum,32);
  #pragma unroll
  for(int j=0;j<8;j++) acc[j]+=__shfl_xor(acc[j],32);
  if(half==0){
    float inv=1.f/(ssum+1e-16f);
    short8 o;
    #pragma unroll
    for(int j=0;j<8;j++) o[j]=(short)f2b(acc[j]*inv);
    *(short8*)&aggb[(size_t)n*DD+8*lk]=o;
  }
}

// ---------------- BN finalize from nb per-block partials: one block PER COLUMN ----------------
__global__ __launch_bounds__(256) void k_bnfin(const float* __restrict__ psum, const float* __restrict__ psq,
                        const float* __restrict__ g, const float* __restrict__ b,
                        float* scale, float* shift, int N, int nb){
  __shared__ float rs[256], rq[256];
  int c=blockIdx.x, tid=threadIdx.x;
  float s=0.f,q=0.f;
  for(int i=tid;i<nb;i+=256){ s+=psum[(size_t)i*DD+c]; q+=psq[(size_t)i*DD+c]; }
  rs[tid]=s; rq[tid]=q;
  __syncthreads();
  #pragma unroll
  for(int off=128;off>0;off>>=1){
    if(tid<off){ rs[tid]+=rs[tid+off]; rq[tid]+=rq[tid+off]; }
    __syncthreads();
  }
  if(tid==0){
    float inv=1.f/(float)N;
    float mu=rs[0]*inv;
    float var=rq[0]*inv - mu*mu;
    float sc=g[c]*rsqrtf(var+1e-5f);
    scale[c]=sc;
    shift[c]=b[c]-mu*sc;
  }
}

// out = relu(h*scale + shift [+ res]); wave-per-row, float4, shuffle-reduced a_i.
// WOUT: write f32 output stream; CVT: write bf16 copy + next-layer a_i.
template<bool RES, bool CVT, bool WOUT>
__global__ __launch_bounds__(256) void k_bnapply(const float* __restrict__ hm, const float* __restrict__ scale,
                          const float* __restrict__ shift, const float* __restrict__ res,
                          float* __restrict__ outp, unsigned short* __restrict__ xb,
                          const float* __restrict__ wd_as, float* __restrict__ a_i, int N){
  int b=blockIdx.x, tid=threadIdx.x, wv=tid>>6, l=tid&63;
  int c0=4*l;
  float4 sc=*(const float4*)&scale[c0];
  float4 sh=*(const float4*)&shift[c0];
  float wa[4][8];
  if(CVT){
    #pragma unroll
    for(int j=0;j<4;j++)
      #pragma unroll
      for(int h=0;h<8;h++) wa[j][h]=wd_as[(c0+j)*8+h];
  }
  for(int n=b*4+wv; n<N; n+=NB_BA*4){
    float4 v=*(const float4*)&hm[(size_t)n*DD+c0];
    v.x=v.x*sc.x+sh.x; v.y=v.y*sc.y+sh.y; v.z=v.z*sc.z+sh.z; v.w=v.w*sc.w+sh.w;
    if(RES){
      float4 rr=*(const float4*)&res[(size_t)n*DD+c0];
      v.x+=rr.x; v.y+=rr.y; v.z+=rr.z; v.w+=rr.w;
    }
    v.x=fmaxf(v.x,0.f); v.y=fmaxf(v.y,0.f); v.z=fmaxf(v.z,0.f); v.w=fmaxf(v.w,0.f);
    if(WOUT) *(float4*)&outp[(size_t)n*DD+c0]=v;
    if(CVT){
      ushort4 xo; xo.x=f2b(v.x); xo.y=f2b(v.y); xo.z=f2b(v.z); xo.w=f2b(v.w);
      *(ushort4*)&xb[(size_t)n*DD+c0]=xo;
      float ai[8];
      #pragma unroll
      for(int h=0;h<8;h++) ai[h]=v.x*wa[0][h]+v.y*wa[1][h]+v.z*wa[2][h]+v.w*wa[3][h];
      #pragma unroll
      for(int off=1;off<64;off<<=1){
        #pragma unroll
        for(int h=0;h<8;h++) ai[h]+=__shfl_xor(ai[h],off);
      }
      if(l==0){
        float4 A; A.x=ai[0];A.y=ai[1];A.z=ai[2];A.w=ai[3];
        float4 B; B.x=ai[4];B.y=ai[5];B.z=ai[6];B.w=ai[7];
        *(float4*)&a_i[(size_t)n*HH]=A;
        *(float4*)&a_i[(size_t)n*HH+4]=B;
      }
    }
  }
}

extern "C" void kernel_launch(void* const* d_in, const int* in_sizes, int n_in,
                              void* d_out, int out_size, void* d_ws, size_t ws_size,
                              hipStream_t stream) {
  const float* x  = (const float*)d_in[0];
  const int*   ei = (const int*)d_in[1];
  const float* ea = (const float*)d_in[2];
  const int*   et = (const int*)d_in[3];
  int N = in_sizes[0]/DD;
  int E = in_sizes[3];
  int Etot = E+N;
  const int* srcE = ei;
  const int* dstE = ei + E;

  const float* Ws1=(const float*)d_in[4];  const float* Wd1=(const float*)d_in[5];
  const float* as1=(const float*)d_in[6];  const float* ad1=(const float*)d_in[7];
  const float* We1=(const float*)d_in[8];  const float* ae1=(const float*)d_in[9];
  const float* te1=(const float*)d_in[10]; const float* Wo1=(const float*)d_in[11];
  const float* bo1=(const float*)d_in[12]; const float* b1 =(const float*)d_in[13];
  const float* lg1=(const float*)d_in[14]; const float* lb1=(const float*)d_in[15];
  const float* Ws2=(const float*)d_in[16]; const float* Wd2=(const float*)d_in[17];
  const float* as2=(const float*)d_in[18]; const float* ad2=(const float*)d_in[19];
  const float* We2=(const float*)d_in[20]; const float* ae2=(const float*)d_in[21];
  const float* te2=(const float*)d_in[22]; const float* Wo2=(const float*)d_in[23];
  const float* bo2=(const float*)d_in[24]; const float* b2 =(const float*)d_in[25];
  const float* lg2=(const float*)d_in[26]; const float* lb2=(const float*)d_in[27];
  const float* bng1=(const float*)d_in[28]; const float* bnb1=(const float*)d_in[29];
  const float* bng2=(const float*)d_in[30]; const float* bnb2=(const float*)d_in[31];

  char* p=(char*)d_ws;
  auto alloc=[&](size_t bytes)->void*{ void* r=(void*)p; p+=(bytes+255)&~(size_t)255; return r; };
  unsigned short* xb   =(unsigned short*)alloc((size_t)N*DD*2);
  unsigned short* ysb  =(unsigned short*)alloc((size_t)N*DD*2);
  unsigned short* aggb =(unsigned short*)alloc((size_t)N*DD*2);
  unsigned short* eaPb =(unsigned short*)alloc((size_t)Etot*16*2);
  int*   stP   =(int*)alloc((size_t)Etot*4);
  float* a_i   =(float*)alloc((size_t)N*HH*4);
  float* a_j   =(float*)alloc((size_t)N*HH*4);
  float* wd_as1=(float*)alloc(DD*HH*4);
  float* v_e1  =(float*)alloc(16*HH*4);
  float* t_a1  =(float*)alloc(7*HH*4);
  float* wd_as2=(float*)alloc(DD*HH*4);
  float* v_e2  =(float*)alloc(16*HH*4);
  float* t_a2  =(float*)alloc(7*HH*4);
  int nbLN=(N+31)/32;
  float* psum  =(float*)alloc((size_t)nbLN*DD*4);
  float* psq   =(float*)alloc((size_t)nbLN*DD*4);
  float* scl   =(float*)alloc(256*4);
  float* shf   =(float*)alloc(256*4);
  unsigned short* Wsb1T=(unsigned short*)alloc((size_t)DD*DD*2);
  unsigned short* Wob1T=(unsigned short*)alloc((size_t)DD*DD*2);
  unsigned short* Wsb2T=(unsigned short*)alloc((size_t)DD*DD*2);
  unsigned short* Wob2T=(unsigned short*)alloc((size_t)DD*DD*2);
  int* cnt     =(int*)alloc((size_t)N*4);
  int* row_off =(int*)alloc((size_t)(N+1)*4);
  int* cursor  =(int*)alloc((size_t)N*4);
  float* hbuf  =(float*)d_out;

  dim3 gg(2,(N+63)/64);

  // upfront: CSR (with packed+bf16 edge data) + weight prep (both layers)
  hipMemsetAsync(cnt, 0, (size_t)N*4, stream);
  k_count<<<(Etot+255)/256,256,0,stream>>>(dstE,E,N,cnt);
  k_scan<<<1,1024,0,stream>>>(cnt,N,row_off,cursor);
  k_fill<<<(Etot+255)/256,256,0,stream>>>(srcE,dstE,ea,et,E,N,cursor,stP,eaPb);
  k_cvt_wT4<<<dim3(DD,4),DD,0,stream>>>(Ws1,Wo1,Ws2,Wo2,Wsb1T,Wob1T,Wsb2T,Wob2T);
  k_pre2<<<2,256,0,stream>>>(Wd1,as1,We1,ae1,te1,Wd2,as2,We2,ae2,te2,
                             wd_as1,v_e1,t_a1,wd_as2,v_e2,t_a2);

  // ---- layer 1 ----
  k_cvt_x2<<<NB_BA,256,0,stream>>>(x,wd_as1,xb,a_i,N);
  k_gemm1<true><<<gg,256,0,stream>>>(xb,Wsb1T,ad1,a_j,ysb,N);
  k_agg<<<N,64,0,stream>>>(row_off,stP,eaPb,a_i,a_j,v_e1,t_a1,ysb,aggb,N);
  k_gemm_ln<false><<<nbLN,256,0,stream>>>(aggb,Wob1T,bo1,b1,(const void*)x,lg1,lb1,hbuf,psum,psq,N);
  k_bnfin<<<DD,256,0,stream>>>(psum,psq,bng1,bnb1,scl,shf,N,nbLN);
  // layer-1 BN apply: bf16 copy (xb) + next-layer a_i only; no f32 output stream
  k_bnapply<false,true,false><<<NB_BA,256,0,stream>>>(hbuf,scl,shf,nullptr,nullptr,xb,wd_as2,a_i,N);

  // ---- layer 2 (residual = xb, bf16) ----
  k_gemm1<true><<<gg,256,0,stream>>>(xb,Wsb2T,ad2,a_j,ysb,N);
  k_agg<<<N,64,0,stream>>>(row_off,stP,eaPb,a_i,a_j,v_e2,t_a2,ysb,aggb,N);
  k_gemm_ln<true><<<nbLN,256,0,stream>>>(aggb,Wob2T,bo2,b2,(const void*)xb,lg2,lb2,hbuf,psum,psq,N);
  k_bnfin<<<DD,256,0,stream>>>(psum,psq,bng2,bnb2,scl,shf,N,nbLN);
  k_bnapply<true,false,true><<<NB_BA,256,0,stream>>>(hbuf,scl,shf,x,(float*)d_out,nullptr,nullptr,nullptr,N);
}

// Round 22
// 285.213 us; speedup vs baseline: 1.1563x; 1.0045x over previous
//
#include <hip/hip_runtime.h>

#define DD 256
#define HH 8
#define CC 32

typedef __attribute__((ext_vector_type(8))) short short8;
typedef __attribute__((ext_vector_type(4))) float f32x4;
typedef _Float16 h2 __attribute__((ext_vector_type(2)));

static __device__ __forceinline__ unsigned short f2b(float f){
  unsigned u = __float_as_uint(f);
  u = u + 0x7FFFu + ((u >> 16) & 1u);          // RNE
  return (unsigned short)(u >> 16);
}
static __device__ __forceinline__ float b2f(unsigned short s){
  return __uint_as_float(((unsigned)s) << 16);
}
static __device__ __forceinline__ short f2h_bits(float f){
  union { _Float16 h; short s; } cv; cv.h=(_Float16)f; return cv.s;
}

// global->LDS direct DMA: 16B/lane, wave-uniform LDS base, lane l lands at base+l*16.
static __device__ __forceinline__ void gload16(const void* g, void* l){
  using gpt = const __attribute__((address_space(1))) unsigned int*;
  using lpt = __attribute__((address_space(3))) unsigned int*;
  __builtin_amdgcn_global_load_lds((gpt)(unsigned long long)g, (lpt)(unsigned long long)l, 16, 0, 0);
}

// ---------------- CSR build ----------------
__global__ void k_count(const int* __restrict__ dstE, int E, int N, int* cnt){
  int e=blockIdx.x*blockDim.x+threadIdx.x;
  if(e<E+N){ int d=(e<E)? dstE[e] : (e-E); atomicAdd(&cnt[d],1); }
}

__global__ __launch_bounds__(1024) void k_scan(const int* __restrict__ cnt, int N, int* row_off, int* cursor){
  __shared__ int part[1024];
  int t=threadIdx.x;
  int chunk=(N+1023)>>10;
  int s=0;
  for(int j=0;j<chunk;j++){ int i=t*chunk+j; if(i<N) s+=cnt[i]; }
  part[t]=s; __syncthreads();
  for(int off=1; off<1024; off<<=1){
    int v=(t>=off)? part[t-off]:0;
    __syncthreads();
    part[t]+=v;
    __syncthreads();
  }
  int run=(t==0)?0:part[t-1];
  for(int j=0;j<chunk;j++){ int i=t*chunk+j; if(i<N){ row_off[i]=run; cursor[i]=run; run+=cnt[i]; } }
  if(t==1023) row_off[N]=part[1023];
}

// fill CSR: scatter packed src|type and f16 edge-attr into CSR (dst-sorted) order.
__global__ void k_fill(const int* __restrict__ srcE, const int* __restrict__ dstE,
                       const float* __restrict__ ea, const int* __restrict__ et,
                       int E, int N, int* cursor,
                       int* stP, unsigned short* eaPh){
  int e=blockIdx.x*blockDim.x+threadIdx.x;
  if(e>=E+N) return;
  int s,d,ty;
  float q[16];
  if(e<E){
    s=srcE[e]; d=dstE[e]; ty=et[e];
    float4 q0=*(const float4*)&ea[(size_t)e*16+0];
    float4 q1=*(const float4*)&ea[(size_t)e*16+4];
    float4 q2=*(const float4*)&ea[(size_t)e*16+8];
    float4 q3=*(const float4*)&ea[(size_t)e*16+12];
    q[0]=q0.x;q[1]=q0.y;q[2]=q0.z;q[3]=q0.w;
    q[4]=q1.x;q[5]=q1.y;q[6]=q1.z;q[7]=q1.w;
    q[8]=q2.x;q[9]=q2.y;q[10]=q2.z;q[11]=q2.w;
    q[12]=q3.x;q[13]=q3.y;q[14]=q3.z;q[15]=q3.w;
  }else{
    s=e-E; d=s; ty=6;
    #pragma unroll
    for(int j=0;j<16;j++) q[j]=1.f;
  }
  int pos=atomicAdd(&cursor[d],1);
  stP[pos]= s | (ty<<24);               // N << 2^24
  short8 o0,o1;
  #pragma unroll
  for(int j=0;j<8;j++){ o0[j]=f2h_bits(q[j]); o1[j]=f2h_bits(q[8+j]); }
  *(short8*)&eaPh[(size_t)pos*16]=o0;
  *(short8*)&eaPh[(size_t)pos*16+8]=o1;
}

// ---------------- 4x weight transpose + bf16 convert in one launch ----------------
__global__ void k_cvt_wT4(const float* __restrict__ W0, const float* __restrict__ W1,
                          const float* __restrict__ W2, const float* __restrict__ W3,
                          unsigned short* __restrict__ T0, unsigned short* __restrict__ T1,
                          unsigned short* __restrict__ T2, unsigned short* __restrict__ T3){
  int m=blockIdx.y, c=blockIdx.x, k=threadIdx.x;
  const float* W = (m==0)?W0:(m==1)?W1:(m==2)?W2:W3;
  unsigned short* T = (m==0)?T0:(m==1)?T1:(m==2)?T2:T3;
  T[(size_t)c*DD+k] = f2b(W[(size_t)k*DD+c]);
}

// ---------------- folded logit weights (both layers) ----------------
// v_e packed into f16 pairs veP[h*8+j] = (f16(v_e[2j][h]), f16(v_e[2j+1][h])).
__global__ void k_pre2(const float* __restrict__ Wd1, const float* __restrict__ as1,
                       const float* __restrict__ We1, const float* __restrict__ ae1,
                       const float* __restrict__ te1,
                       const float* __restrict__ Wd2, const float* __restrict__ as2,
                       const float* __restrict__ We2, const float* __restrict__ ae2,
                       const float* __restrict__ te2,
                       float* wd_as1, unsigned* veP1, float* t_a1,
                       float* wd_as2, unsigned* veP2, float* t_a2){
  __shared__ float sve[16*HH];
  int L=blockIdx.x;
  const float* Wd=L?Wd2:Wd1; const float* as_=L?as2:as1;
  const float* We=L?We2:We1; const float* ae=L?ae2:ae1; const float* te=L?te2:te1;
  float* wd_as=L?wd_as2:wd_as1; unsigned* veP=L?veP2:veP1; float* t_a=L?t_a2:t_a1;
  int t=threadIdx.x;
  for(int idx=t; idx<DD*HH; idx+=256){
    int k=idx>>3, h=idx&7;
    const float* w=&Wd[k*DD+h*CC]; const float* a=&as_[h*CC];
    float s=0;
    #pragma unroll
    for(int c=0;c<CC;c++) s+=w[c]*a[c];
    wd_as[idx]=s;
  }
  for(int idx=t; idx<16*HH; idx+=256){
    int k=idx>>3, h=idx&7;
    const float* w=&We[k*DD+h*CC]; const float* a=&ae[h*CC];
    float s=0;
    #pragma unroll
    for(int c=0;c<CC;c++) s+=w[c]*a[c];
    sve[idx]=s;
  }
  for(int idx=t; idx<7*HH; idx+=256){
    int k=idx>>3, h=idx&7;
    const float* w=&te[k*DD+h*CC]; const float* a=&ae[h*CC];
    float s=0;
    #pragma unroll
    for(int c=0;c<CC;c++) s+=w[c]*a[c];
    t_a[idx]=s;
  }
  __syncthreads();
  if(t<64){
    int h=t>>3, j=t&7;
    union { h2 h; unsigned u; } cv;
    cv.h[0]=(_Float16)sve[(2*j)*HH+h];
    cv.h[1]=(_Float16)sve[(2*j+1)*HH+h];
    veP[h*8+j]=cv.u;
  }
}

// ---------------- x -> bf16 + a_i (wave-per-row, float4, shuffle reduce) ----------------
#define NB_BA 1024
__global__ __launch_bounds__(256) void k_cvt_x2(const float* __restrict__ xin, const float* __restrict__ wd_as,
                         unsigned short* __restrict__ xb, float* __restrict__ a_i, int N){
  int b=blockIdx.x, tid=threadIdx.x, wv=tid>>6, l=tid&63;
  int c0=4*l;
  float wa[4][8];
  #pragma unroll
  for(int j=0;j<4;j++)
    #pragma unroll
    for(int h=0;h<8;h++) wa[j][h]=wd_as[(c0+j)*8+h];
  for(int n=b*4+wv; n<N; n+=NB_BA*4){
    float4 v=*(const float4*)&xin[(size_t)n*DD+c0];
    ushort4 xo; xo.x=f2b(v.x); xo.y=f2b(v.y); xo.z=f2b(v.z); xo.w=f2b(v.w);
    *(ushort4*)&xb[(size_t)n*DD+c0]=xo;
    float ai[8];
    #pragma unroll
    for(int h=0;h<8;h++) ai[h]=v.x*wa[0][h]+v.y*wa[1][h]+v.z*wa[2][h]+v.w*wa[3][h];
    #pragma unroll
    for(int off=1;off<64;off<<=1){
      #pragma unroll
      for(int h=0;h<8;h++) ai[h]+=__shfl_xor(ai[h],off);
    }
    if(l==0){
      float4 A; A.x=ai[0];A.y=ai[1];A.z=ai[2];A.w=ai[3];
      float4 B; B.x=ai[4];B.y=ai[5];B.z=ai[6];B.w=ai[7];
      *(float4*)&a_i[(size_t)n*HH]=A;
      *(float4*)&a_i[(size_t)n*HH+4]=B;
    }
  }
}

// ---------------- GEMM1: C[N,256]=A@B, bf16 out + fused a_j ----------------
template<bool AJ>
__global__ __launch_bounds__(256) void k_gemm1(const unsigned short* __restrict__ A,
                                               const unsigned short* __restrict__ Bt,
                                               const float* __restrict__ ad, float* __restrict__ a_j,
                                               unsigned short* __restrict__ Cout, int N){
  __shared__ char lds[2*12288];   // per buf: A 64x32 (4KB) + B 128x32 (8KB)
  int tid=threadIdx.x;
  int w=tid>>6, l=tid&63;
  int row0=blockIdx.y*64, col0=blockIdx.x*128;

  int lr=l>>2;
  int kc=(l&3)^((l>>3)&3);
  const unsigned short* ga  = &A [(size_t)(row0+16*w+lr)*DD + kc*8];
  const unsigned short* gb0 = &Bt[(size_t)(col0+32*w+lr)*DD + kc*8];
  const unsigned short* gb1 = &Bt[(size_t)(col0+32*w+16+lr)*DD + kc*8];
  int laoff =      w*1024;
  int lboff0=4096+(32*w)*64;
  int lboff1=4096+(32*w+16)*64;

  int x15=l&15;
  int lp=x15*64 + ((l>>4)^((x15>>1)&3))*16;

  f32x4 acc[4][2];
  #pragma unroll
  for(int i=0;i<4;i++){ acc[i][0]=(f32x4)0.f; acc[i][1]=(f32x4)0.f; }

  gload16(ga,  lds+laoff);
  gload16(gb0, lds+lboff0);
  gload16(gb1, lds+lboff1);
  __syncthreads();
  int cur=0;
  for(int kt=0;kt<DD;kt+=32){
    int nxt=cur^1;
    if(kt+32<DD){
      gload16(ga +kt+32, lds+nxt*12288+laoff);
      gload16(gb0+kt+32, lds+nxt*12288+lboff0);
      gload16(gb1+kt+32, lds+nxt*12288+lboff1);
    }
    char* base=lds+cur*12288;
    short8 af[4], bf[2];
    #pragma unroll
    for(int mf=0;mf<4;mf++) af[mf]=*(short8*)(base + mf*1024 + lp);
    #pragma unroll
    for(int nf=0;nf<2;nf++) bf[nf]=*(short8*)(base + 4096 + (32*w+16*nf)*64 + lp);
    #pragma unroll
    for(int mf=0;mf<4;mf++)
      #pragma unroll
      for(int nf=0;nf<2;nf++)
        acc[mf][nf]=__builtin_amdgcn_mfma_f32_16x16x32_bf16(af[mf],bf[nf],acc[mf][nf],0,0,0);
    __syncthreads();
    cur=nxt;
  }

  int lcol=x15, lrow4=(l>>4)*4;
  float ad0=0.f, ad1=0.f;
  if(AJ){ ad0=ad[col0+32*w+lcol]; ad1=ad[col0+32*w+16+lcol]; }
  int head=(col0>>5)+w;
  #pragma unroll
  for(int mf=0;mf<4;mf++){
    #pragma unroll
    for(int nf=0;nf<2;nf++){
      int col=col0 + 32*w + 16*nf + lcol;
      #pragma unroll
      for(int rr=0;rr<4;rr++){
        int row=row0 + 16*mf + lrow4 + rr;
        if(row<N) Cout[(size_t)row*DD+col]=f2b(acc[mf][nf][rr]);
      }
    }
    if(AJ){
      #pragma unroll
      for(int rr=0;rr<4;rr++){
        float t=acc[mf][0][rr]*ad0 + acc[mf][1][rr]*ad1;
        t+=__shfl_xor(t,1); t+=__shfl_xor(t,2);
        t+=__shfl_xor(t,4); t+=__shfl_xor(t,8);
        int row=row0 + 16*mf + lrow4 + rr;
        if(x15==0 && row<N) a_j[(size_t)row*HH+head]=t;
      }
    }
  }
}

// ---------------- GEMM2 fused: bias + LayerNorm + residual + BN partials --------
// RESBF16: residual stream is bf16 (layer 2 uses xb written by layer-1 bnapply).
template<bool RESBF16>
__global__ __launch_bounds__(256) void k_gemm_ln(const unsigned short* __restrict__ A,
                                                 const unsigned short* __restrict__ Bt,
                                                 const float* __restrict__ bo, const float* __restrict__ bvec,
                                                 const void* __restrict__ xin,
                                                 const float* __restrict__ lg, const float* __restrict__ lb,
                                                 float* __restrict__ hout,
                                                 float* __restrict__ psum, float* __restrict__ psq, int N){
  __shared__ char lds[2*18432];   // per buf: A 32x32 (2KB) + B 256x32 (16KB)
  int tid=threadIdx.x;
  int w=tid>>6, l=tid&63;
  int row0=blockIdx.x*32;

  int lr=l>>2;
  int kc=(l&3)^((l>>3)&3);
  const unsigned short* ga = &A[(size_t)(row0+16*w+lr)*DD + kc*8];   // waves 0,1 only
  const unsigned short* gb0=&Bt[(size_t)(64*w   +lr)*DD + kc*8];
  const unsigned short* gb1=&Bt[(size_t)(64*w+16+lr)*DD + kc*8];
  const unsigned short* gb2=&Bt[(size_t)(64*w+32+lr)*DD + kc*8];
  const unsigned short* gb3=&Bt[(size_t)(64*w+48+lr)*DD + kc*8];
  int laoff =      w*1024;
  int lboff0=2048+(64*w   )*64;
  int lboff1=2048+(64*w+16)*64;
  int lboff2=2048+(64*w+32)*64;
  int lboff3=2048+(64*w+48)*64;

  int x15=l&15;
  int lp=x15*64 + ((l>>4)^((x15>>1)&3))*16;

  f32x4 acc[2][4];
  #pragma unroll
  for(int i=0;i<2;i++)
    #pragma unroll
    for(int j=0;j<4;j++) acc[i][j]=(f32x4)0.f;

  if(w<2) gload16(ga, lds+laoff);
  gload16(gb0, lds+lboff0);
  gload16(gb1, lds+lboff1);
  gload16(gb2, lds+lboff2);
  gload16(gb3, lds+lboff3);
  __syncthreads();
  int cur=0;
  for(int kt=0;kt<DD;kt+=32){
    int nxt=cur^1;
    if(kt+32<DD){
      char* nb=lds+nxt*18432;
      if(w<2) gload16(ga+kt+32, nb+laoff);
      gload16(gb0+kt+32, nb+lboff0);
      gload16(gb1+kt+32, nb+lboff1);
      gload16(gb2+kt+32, nb+lboff2);
      gload16(gb3+kt+32, nb+lboff3);
    }
    char* base=lds+cur*18432;
    short8 af[2], bf[4];
    #pragma unroll
    for(int mf=0;mf<2;mf++) af[mf]=*(short8*)(base + mf*1024 + lp);
    #pragma unroll
    for(int nf=0;nf<4;nf++) bf[nf]=*(short8*)(base + 2048 + (64*w+16*nf)*64 + lp);
    #pragma unroll
    for(int mf=0;mf<2;mf++)
      #pragma unroll
      for(int nf=0;nf<4;nf++)
        acc[mf][nf]=__builtin_amdgcn_mfma_f32_16x16x32_bf16(af[mf],bf[nf],acc[mf][nf],0,0,0);
    __syncthreads();
    cur=nxt;
  }

  // ---- epilogue ----
  int lrow4=(l>>4)*4;
  float lgv[4], lbv[4];
  #pragma unroll
  for(int nf=0;nf<4;nf++){
    int col=64*w+16*nf+x15;
    float badd=bo[col]+bvec[col];
    lgv[nf]=lg[col]; lbv[nf]=lb[col];
    #pragma unroll
    for(int mf=0;mf<2;mf++)
      #pragma unroll
      for(int rr=0;rr<4;rr++) acc[mf][nf][rr]+=badd;
  }
  __syncthreads();   // GEMM LDS dead; repurpose
  float* rs   =(float*)lds;            // [4][32]
  float* rq   =(float*)(lds+512);      // [4][32]
  float* mus  =(float*)(lds+1024);     // [32]
  float* rstds=(float*)(lds+1152);     // [32]
  #pragma unroll
  for(int mf=0;mf<2;mf++){
    #pragma unroll
    for(int rr=0;rr<4;rr++){
      float t=acc[mf][0][rr]+acc[mf][1][rr]+acc[mf][2][rr]+acc[mf][3][rr];
      float q=acc[mf][0][rr]*acc[mf][0][rr]+acc[mf][1][rr]*acc[mf][1][rr]
             +acc[mf][2][rr]*acc[mf][2][rr]+acc[mf][3][rr]*acc[mf][3][rr];
      t+=__shfl_xor(t,1); q+=__shfl_xor(q,1);
      t+=__shfl_xor(t,2); q+=__shfl_xor(q,2);
      t+=__shfl_xor(t,4); q+=__shfl_xor(q,4);
      t+=__shfl_xor(t,8); q+=__shfl_xor(q,8);
      if(x15==0){
        int row=16*mf+lrow4+rr;
        rs[w*32+row]=t; rq[w*32+row]=q;
      }
    }
  }
  __syncthreads();
  if(tid<32){
    float S=rs[tid]+rs[32+tid]+rs[64+tid]+rs[96+tid];
    float Q=rq[tid]+rq[32+tid]+rq[64+tid]+rq[96+tid];
    float mu=S*(1.f/DD);
    float var=Q*(1.f/DD)-mu*mu;
    mus[tid]=mu;
    rstds[tid]=rsqrtf(var+1e-5f);
  }
  __syncthreads();
  float cps[4]={0.f,0.f,0.f,0.f}, cqs[4]={0.f,0.f,0.f,0.f};
  #pragma unroll
  for(int mf=0;mf<2;mf++){
    #pragma unroll
    for(int rr=0;rr<4;rr++){
      int row=16*mf+lrow4+rr;
      int grow=row0+row;
      bool ok=(grow<N);
      float mu=mus[row], rstd=rstds[row];
      #pragma unroll
      for(int nf=0;nf<4;nf++){
        int col=64*w+16*nf+x15;
        float h=0.f;
        if(ok){
          float r = RESBF16 ? b2f(((const unsigned short*)xin)[(size_t)grow*DD+col])
                            : ((const float*)xin)[(size_t)grow*DD+col];
          h=(acc[mf][nf][rr]-mu)*rstd*lgv[nf]+lbv[nf]+r;
          hout[(size_t)grow*DD+col]=h;
        }
        cps[nf]+=h; cqs[nf]+=h*h;
      }
    }
  }
  #pragma unroll
  for(int nf=0;nf<4;nf++){
    cps[nf]+=__shfl_xor(cps[nf],16); cqs[nf]+=__shfl_xor(cqs[nf],16);
    cps[nf]+=__shfl_xor(cps[nf],32); cqs[nf]+=__shfl_xor(cqs[nf],32);
  }
  if(l<16){
    #pragma unroll
    for(int nf=0;nf<4;nf++){
      int col=64*w+16*nf+l;
      psum[(size_t)blockIdx.x*DD+col]=cps[nf];
      psq [(size_t)blockIdx.x*DD+col]=cqs[nf];
    }
  }
}

// ---------------- FUSED edge-logit + online softmax + aggregation ----------------
// ONE WAVE PER BLOCK. Metadata + ysb rows prefetched one chunk ahead. Edge-attr
// logit uses hardware v_dot2_f32_f16 on packed f16 pairs (eaPh x veP).
__global__ __launch_bounds__(64) void k_agg(const int* __restrict__ row_off,
                      const int* __restrict__ stP, const unsigned short* __restrict__ eaPh,
                      const float* __restrict__ a_i, const float* __restrict__ a_j,
                      const unsigned* __restrict__ veP, const float* __restrict__ t_a,
                      const unsigned short* __restrict__ ysb, unsigned short* __restrict__ aggb, int N){
  int l=threadIdx.x;
  int n=blockIdx.x;
  if(n>=N) return;
  int beg=row_off[n], deg=row_off[n+1]-beg;
  int slotL=l>>3, headL=l&7;
  int half=l>>5, lk=l&31;
  int hh=lk>>2;
  h2 vehp[8];
  #pragma unroll
  for(int k=0;k<8;k++){
    union { unsigned u; h2 h; } cv; cv.u=veP[headL*8+k]; vehp[k]=cv.h;
  }
  float aih=a_i[(size_t)n*HH+headL];
  float m=-3e38f, ssum=0.f;
  float acc[8];
  #pragma unroll
  for(int j=0;j<8;j++) acc[j]=0.f;

  // prefetch chunk 0: metadata + gather rows (deg>=1: self-loop; clamped idx valid)
  int ic0 = (slotL<deg)? slotL : (deg-1);
  size_t pos0=(size_t)(beg+ic0);
  int st_c = stP[pos0];
  short8 e0_c=*(const short8*)&eaPh[pos0*16];
  short8 e1_c=*(const short8*)&eaPh[pos0*16+8];
  float aj_c = a_j[(size_t)(st_c&0xFFFFFF)*HH+headL];
  short8 ybuf_c[4];
  {
    int src0 = st_c & 0xFFFFFF;
    #pragma unroll
    for(int u=0;u<4;u++){
      int si=__shfl(src0,((2*u+half)<<3));
      ybuf_c[u]=*(const short8*)&ysb[(size_t)si*DD+8*lk];
    }
  }

  for(int base=0;base<deg;base+=8){
    bool ok=(base+slotL)<deg;
    // prefetch next chunk: metadata + gather rows (addresses from st_n)
    int in_=base+8+slotL;
    int icn=(in_<deg)? in_ : (deg-1);
    size_t posn=(size_t)(beg+icn);
    int st_n = stP[posn];
    short8 e0_n=*(const short8*)&eaPh[posn*16];
    short8 e1_n=*(const short8*)&eaPh[posn*16+8];
    float aj_n = a_j[(size_t)(st_n&0xFFFFFF)*HH+headL];
    int src_n = st_n & 0xFFFFFF;
    short8 ybuf_n[4];
    #pragma unroll
    for(int u=0;u<4;u++){
      int si=__shfl(src_n,((2*u+half)<<3));
      ybuf_n[u]=*(const short8*)&ysb[(size_t)si*DD+8*lk];
    }
    // logit for current chunk: f16 dot2 pairs, f32 accumulate
    int src = st_c & 0xFFFFFF;
    int ty  = ((unsigned)st_c) >> 24;
    float t = aih + aj_c + t_a[ty*8+headL];
    {
      union { short8 s; h2 h[4]; } u0, u1;
      u0.s=e0_c; u1.s=e1_c;
      #pragma unroll
      for(int j=0;j<4;j++) t=__builtin_amdgcn_fdot2(u0.h[j],vehp[j],t,false);
      #pragma unroll
      for(int j=0;j<4;j++) t=__builtin_amdgcn_fdot2(u1.h[j],vehp[4+j],t,false);
    }
    t=(t>=0.f)? t : 0.2f*t;
    float v = ok ? t : -3e38f;
    // per-head chunk max (butterfly over slot bits); uniform exec
    float cm=v;
    cm=fmaxf(cm,__shfl_xor(cm,8));
    cm=fmaxf(cm,__shfl_xor(cm,16));
    cm=fmaxf(cm,__shfl_xor(cm,32));
    float cmg=__shfl(cm,hh);
    float mnew=fmaxf(m,cmg);
    float f=__expf(m-mnew);
    ssum*=f;
    #pragma unroll
    for(int j=0;j<8;j++) acc[j]*=f;
    m=mnew;
    int cnt=min(8,deg-base);
    // weights via shuffles (uniform), then FMA tail on prefetched rows
    float vus[4];
    #pragma unroll
    for(int u=0;u<4;u++){
      int e=2*u+half;
      vus[u]=__shfl(v,(e<<3)|hh);
    }
    #pragma unroll
    for(int u=0;u<4;u++){
      int e=2*u+half;
      if(e<cnt){
        float wgt=__expf(vus[u]-m);
        ssum+=wgt;
        #pragma unroll
        for(int j=0;j<8;j++) acc[j]+=wgt*b2f((unsigned short)ybuf_c[u][j]);
      }
    }
    st_c=st_n; e0_c=e0_n; e1_c=e1_n; aj_c=aj_n;
    #pragma unroll
    for(int u=0;u<4;u++) ybuf_c[u]=ybuf_n[u];
  }
  // merge halves (same m on both -> plain add); uniform exec
  ssum+=__shfl_xor(ssum,32);
  #pragma unroll
  for(int j=0;j<8;j++) acc[j]+=__shfl_xor(acc[j],32);
  if(half==0){
    float inv=1.f/(ssum+1e-16f);
    short8 o;
    #pragma unroll
    for(int j=0;j<8;j++) o[j]=(short)f2b(acc[j]*inv);
    *(short8*)&aggb[(size_t)n*DD+8*lk]=o;
  }
}

// ---------------- BN finalize from nb per-block partials: one block PER COLUMN ----------------
__global__ __launch_bounds__(256) void k_bnfin(const float* __restrict__ psum, const float* __restrict__ psq,
                        const float* __restrict__ g, const float* __restrict__ b,
                        float* scale, float* shift, int N, int nb){
  __shared__ float rs[256], rq[256];
  int c=blockIdx.x, tid=threadIdx.x;
  float s=0.f,q=0.f;
  for(int i=tid;i<nb;i+=256){ s+=psum[(size_t)i*DD+c]; q+=psq[(size_t)i*DD+c]; }
  rs[tid]=s; rq[tid]=q;
  __syncthreads();
  #pragma unroll
  for(int off=128;off>0;off>>=1){
    if(tid<off){ rs[tid]+=rs[tid+off]; rq[tid]+=rq[tid+off]; }
    __syncthreads();
  }
  if(tid==0){
    float inv=1.f/(float)N;
    float mu=rs[0]*inv;
    float var=rq[0]*inv - mu*mu;
    float sc=g[c]*rsqrtf(var+1e-5f);
    scale[c]=sc;
    shift[c]=b[c]-mu*sc;
  }
}

// out = relu(h*scale + shift [+ res]); wave-per-row, float4, shuffle-reduced a_i.
// WOUT: write f32 output stream; CVT: write bf16 copy + next-layer a_i.
template<bool RES, bool CVT, bool WOUT>
__global__ __launch_bounds__(256) void k_bnapply(const float* __restrict__ hm, const float* __restrict__ scale,
                          const float* __restrict__ shift, const float* __restrict__ res,
                          float* __restrict__ outp, unsigned short* __restrict__ xb,
                          const float* __restrict__ wd_as, float* __restrict__ a_i, int N){
  int b=blockIdx.x, tid=threadIdx.x, wv=tid>>6, l=tid&63;
  int c0=4*l;
  float4 sc=*(const float4*)&scale[c0];
  float4 sh=*(const float4*)&shift[c0];
  float wa[4][8];
  if(CVT){
    #pragma unroll
    for(int j=0;j<4;j++)
      #pragma unroll
      for(int h=0;h<8;h++) wa[j][h]=wd_as[(c0+j)*8+h];
  }
  for(int n=b*4+wv; n<N; n+=NB_BA*4){
    float4 v=*(const float4*)&hm[(size_t)n*DD+c0];
    v.x=v.x*sc.x+sh.x; v.y=v.y*sc.y+sh.y; v.z=v.z*sc.z+sh.z; v.w=v.w*sc.w+sh.w;
    if(RES){
      float4 rr=*(const float4*)&res[(size_t)n*DD+c0];
      v.x+=rr.x; v.y+=rr.y; v.z+=rr.z; v.w+=rr.w;
    }
    v.x=fmaxf(v.x,0.f); v.y=fmaxf(v.y,0.f); v.z=fmaxf(v.z,0.f); v.w=fmaxf(v.w,0.f);
    if(WOUT) *(float4*)&outp[(size_t)n*DD+c0]=v;
    if(CVT){
      ushort4 xo; xo.x=f2b(v.x); xo.y=f2b(v.y); xo.z=f2b(v.z); xo.w=f2b(v.w);
      *(ushort4*)&xb[(size_t)n*DD+c0]=xo;
      float ai[8];
      #pragma unroll
      for(int h=0;h<8;h++) ai[h]=v.x*wa[0][h]+v.y*wa[1][h]+v.z*wa[2][h]+v.w*wa[3][h];
      #pragma unroll
      for(int off=1;off<64;off<<=1){
        #pragma unroll
        for(int h=0;h<8;h++) ai[h]+=__shfl_xor(ai[h],off);
      }
      if(l==0){
        float4 A; A.x=ai[0];A.y=ai[1];A.z=ai[2];A.w=ai[3];
        float4 B; B.x=ai[4];B.y=ai[5];B.z=ai[6];B.w=ai[7];
        *(float4*)&a_i[(size_t)n*HH]=A;
        *(float4*)&a_i[(size_t)n*HH+4]=B;
      }
    }
  }
}

extern "C" void kernel_launch(void* const* d_in, const int* in_sizes, int n_in,
                              void* d_out, int out_size, void* d_ws, size_t ws_size,
                              hipStream_t stream) {
  const float* x  = (const float*)d_in[0];
  const int*   ei = (const int*)d_in[1];
  const float* ea = (const float*)d_in[2];
  const int*   et = (const int*)d_in[3];
  int N = in_sizes[0]/DD;
  int E = in_sizes[3];
  int Etot = E+N;
  const int* srcE = ei;
  const int* dstE = ei + E;

  const float* Ws1=(const float*)d_in[4];  const float* Wd1=(const float*)d_in[5];
  const float* as1=(const float*)d_in[6];  const float* ad1=(const float*)d_in[7];
  const float* We1=(const float*)d_in[8];  const float* ae1=(const float*)d_in[9];
  const float* te1=(const float*)d_in[10]; const float* Wo1=(const float*)d_in[11];
  const float* bo1=(const float*)d_in[12]; const float* b1 =(const float*)d_in[13];
  const float* lg1=(const float*)d_in[14]; const float* lb1=(const float*)d_in[15];
  const float* Ws2=(const float*)d_in[16]; const float* Wd2=(const float*)d_in[17];
  const float* as2=(const float*)d_in[18]; const float* ad2=(const float*)d_in[19];
  const float* We2=(const float*)d_in[20]; const float* ae2=(const float*)d_in[21];
  const float* te2=(const float*)d_in[22]; const float* Wo2=(const float*)d_in[23];
  const float* bo2=(const float*)d_in[24]; const float* b2 =(const float*)d_in[25];
  const float* lg2=(const float*)d_in[26]; const float* lb2=(const float*)d_in[27];
  const float* bng1=(const float*)d_in[28]; const float* bnb1=(const float*)d_in[29];
  const float* bng2=(const float*)d_in[30]; const float* bnb2=(const float*)d_in[31];

  char* p=(char*)d_ws;
  auto alloc=[&](size_t bytes)->void*{ void* r=(void*)p; p+=(bytes+255)&~(size_t)255; return r; };
  unsigned short* xb   =(unsigned short*)alloc((size_t)N*DD*2);
  unsigned short* ysb  =(unsigned short*)alloc((size_t)N*DD*2);
  unsigned short* aggb =(unsigned short*)alloc((size_t)N*DD*2);
  unsigned short* eaPh =(unsigned short*)alloc((size_t)Etot*16*2);
  int*   stP   =(int*)alloc((size_t)Etot*4);
  float* a_i   =(float*)alloc((size_t)N*HH*4);
  float* a_j   =(float*)alloc((size_t)N*HH*4);
  float* wd_as1=(float*)alloc(DD*HH*4);
  unsigned* veP1=(unsigned*)alloc(64*4);
  float* t_a1  =(float*)alloc(7*HH*4);
  float* wd_as2=(float*)alloc(DD*HH*4);
  unsigned* veP2=(unsigned*)alloc(64*4);
  float* t_a2  =(float*)alloc(7*HH*4);
  int nbLN=(N+31)/32;
  float* psum  =(float*)alloc((size_t)nbLN*DD*4);
  float* psq   =(float*)alloc((size_t)nbLN*DD*4);
  float* scl   =(float*)alloc(256*4);
  float* shf   =(float*)alloc(256*4);
  unsigned short* Wsb1T=(unsigned short*)alloc((size_t)DD*DD*2);
  unsigned short* Wob1T=(unsigned short*)alloc((size_t)DD*DD*2);
  unsigned short* Wsb2T=(unsigned short*)alloc((size_t)DD*DD*2);
  unsigned short* Wob2T=(unsigned short*)alloc((size_t)DD*DD*2);
  int* cnt     =(int*)alloc((size_t)N*4);
  int* row_off =(int*)alloc((size_t)(N+1)*4);
  int* cursor  =(int*)alloc((size_t)N*4);
  float* hbuf  =(float*)d_out;

  dim3 gg(2,(N+63)/64);

  // upfront: CSR (with packed+f16 edge data) + weight prep (both layers)
  hipMemsetAsync(cnt, 0, (size_t)N*4, stream);
  k_count<<<(Etot+255)/256,256,0,stream>>>(dstE,E,N,cnt);
  k_scan<<<1,1024,0,stream>>>(cnt,N,row_off,cursor);
  k_fill<<<(Etot+255)/256,256,0,stream>>>(srcE,dstE,ea,et,E,N,cursor,stP,eaPh);
  k_cvt_wT4<<<dim3(DD,4),DD,0,stream>>>(Ws1,Wo1,Ws2,Wo2,Wsb1T,Wob1T,Wsb2T,Wob2T);
  k_pre2<<<2,256,0,stream>>>(Wd1,as1,We1,ae1,te1,Wd2,as2,We2,ae2,te2,
                             wd_as1,veP1,t_a1,wd_as2,veP2,t_a2);

  // ---- layer 1 ----
  k_cvt_x2<<<NB_BA,256,0,stream>>>(x,wd_as1,xb,a_i,N);
  k_gemm1<true><<<gg,256,0,stream>>>(xb,Wsb1T,ad1,a_j,ysb,N);
  k_agg<<<N,64,0,stream>>>(row_off,stP,eaPh,a_i,a_j,veP1,t_a1,ysb,aggb,N);
  k_gemm_ln<false><<<nbLN,256,0,stream>>>(aggb,Wob1T,bo1,b1,(const void*)x,lg1,lb1,hbuf,psum,psq,N);
  k_bnfin<<<DD,256,0,stream>>>(psum,psq,bng1,bnb1,scl,shf,N,nbLN);
  // layer-1 BN apply: bf16 copy (xb) + next-layer a_i only; no f32 output stream
  k_bnapply<false,true,false><<<NB_BA,256,0,stream>>>(hbuf,scl,shf,nullptr,nullptr,xb,wd_as2,a_i,N);

  // ---- layer 2 (residual = xb, bf16) ----
  k_gemm1<true><<<gg,256,0,stream>>>(xb,Wsb2T,ad2,a_j,ysb,N);
  k_agg<<<N,64,0,stream>>>(row_off,stP,eaPh,a_i,a_j,veP2,t_a2,ysb,aggb,N);
  k_gemm_ln<true><<<nbLN,256,0,stream>>>(aggb,Wob2T,bo2,b2,(const void*)xb,lg2,lb2,hbuf,psum,psq,N);
  k_bnfin<<<DD,256,0,stream>>>(psum,psq,bng2,bnb2,scl,shf,N,nbLN);
  k_bnapply<true,false,true><<<NB_BA,256,0,stream>>>(hbuf,scl,shf,x,(float*)d_out,nullptr,nullptr,nullptr,N);
}

// Round 23
// 283.603 us; speedup vs baseline: 1.1629x; 1.0057x over previous
//
#include <hip/hip_runtime.h>

#define DD 256
#define HH 8
#define CC 32

typedef __attribute__((ext_vector_type(8))) short short8;
typedef __attribute__((ext_vector_type(4))) float f32x4;
typedef _Float16 h2 __attribute__((ext_vector_type(2)));

static __device__ __forceinline__ unsigned short f2b(float f){
  unsigned u = __float_as_uint(f);
  u = u + 0x7FFFu + ((u >> 16) & 1u);          // RNE
  return (unsigned short)(u >> 16);
}
static __device__ __forceinline__ float b2f(unsigned short s){
  return __uint_as_float(((unsigned)s) << 16);
}
static __device__ __forceinline__ short f2h_bits(float f){
  union { _Float16 h; short s; } cv; cv.h=(_Float16)f; return cv.s;
}
static __device__ __forceinline__ float h2f(unsigned short s){
  union { unsigned short u; _Float16 h; } cv; cv.u=s; return (float)cv.h;
}

// global->LDS direct DMA: 16B/lane, wave-uniform LDS base, lane l lands at base+l*16.
static __device__ __forceinline__ void gload16(const void* g, void* l){
  using gpt = const __attribute__((address_space(1))) unsigned int*;
  using lpt = __attribute__((address_space(3))) unsigned int*;
  __builtin_amdgcn_global_load_lds((gpt)(unsigned long long)g, (lpt)(unsigned long long)l, 16, 0, 0);
}

// ---------------- CSR build ----------------
__global__ void k_count(const int* __restrict__ dstE, int E, int N, int* cnt){
  int e=blockIdx.x*blockDim.x+threadIdx.x;
  if(e<E+N){ int d=(e<E)? dstE[e] : (e-E); atomicAdd(&cnt[d],1); }
}

__global__ __launch_bounds__(1024) void k_scan(const int* __restrict__ cnt, int N, int* row_off, int* cursor){
  __shared__ int part[1024];
  int t=threadIdx.x;
  int chunk=(N+1023)>>10;
  int s=0;
  for(int j=0;j<chunk;j++){ int i=t*chunk+j; if(i<N) s+=cnt[i]; }
  part[t]=s; __syncthreads();
  for(int off=1; off<1024; off<<=1){
    int v=(t>=off)? part[t-off]:0;
    __syncthreads();
    part[t]+=v;
    __syncthreads();
  }
  int run=(t==0)?0:part[t-1];
  for(int j=0;j<chunk;j++){ int i=t*chunk+j; if(i<N){ row_off[i]=run; cursor[i]=run; run+=cnt[i]; } }
  if(t==1023) row_off[N]=part[1023];
}

// fill CSR: scatter packed src|type and f16 edge-attr into CSR (dst-sorted) order.
__global__ void k_fill(const int* __restrict__ srcE, const int* __restrict__ dstE,
                       const float* __restrict__ ea, const int* __restrict__ et,
                       int E, int N, int* cursor,
                       int* stP, unsigned short* eaPh){
  int e=blockIdx.x*blockDim.x+threadIdx.x;
  if(e>=E+N) return;
  int s,d,ty;
  float q[16];
  if(e<E){
    s=srcE[e]; d=dstE[e]; ty=et[e];
    float4 q0=*(const float4*)&ea[(size_t)e*16+0];
    float4 q1=*(const float4*)&ea[(size_t)e*16+4];
    float4 q2=*(const float4*)&ea[(size_t)e*16+8];
    float4 q3=*(const float4*)&ea[(size_t)e*16+12];
    q[0]=q0.x;q[1]=q0.y;q[2]=q0.z;q[3]=q0.w;
    q[4]=q1.x;q[5]=q1.y;q[6]=q1.z;q[7]=q1.w;
    q[8]=q2.x;q[9]=q2.y;q[10]=q2.z;q[11]=q2.w;
    q[12]=q3.x;q[13]=q3.y;q[14]=q3.z;q[15]=q3.w;
  }else{
    s=e-E; d=s; ty=6;
    #pragma unroll
    for(int j=0;j<16;j++) q[j]=1.f;
  }
  int pos=atomicAdd(&cursor[d],1);
  stP[pos]= s | (ty<<24);               // N << 2^24
  short8 o0,o1;
  #pragma unroll
  for(int j=0;j<8;j++){ o0[j]=f2h_bits(q[j]); o1[j]=f2h_bits(q[8+j]); }
  *(short8*)&eaPh[(size_t)pos*16]=o0;
  *(short8*)&eaPh[(size_t)pos*16+8]=o1;
}

// ---------------- 4x weight transpose + bf16 convert in one launch ----------------
__global__ void k_cvt_wT4(const float* __restrict__ W0, const float* __restrict__ W1,
                          const float* __restrict__ W2, const float* __restrict__ W3,
                          unsigned short* __restrict__ T0, unsigned short* __restrict__ T1,
                          unsigned short* __restrict__ T2, unsigned short* __restrict__ T3){
  int m=blockIdx.y, c=blockIdx.x, k=threadIdx.x;
  const float* W = (m==0)?W0:(m==1)?W1:(m==2)?W2:W3;
  unsigned short* T = (m==0)?T0:(m==1)?T1:(m==2)?T2:T3;
  T[(size_t)c*DD+k] = f2b(W[(size_t)k*DD+c]);
}

// ---------------- folded logit weights (both layers) ----------------
// v_e packed into f16 pairs veP[h*8+j] = (f16(v_e[2j][h]), f16(v_e[2j+1][h])).
__global__ void k_pre2(const float* __restrict__ Wd1, const float* __restrict__ as1,
                       const float* __restrict__ We1, const float* __restrict__ ae1,
                       const float* __restrict__ te1,
                       const float* __restrict__ Wd2, const float* __restrict__ as2,
                       const float* __restrict__ We2, const float* __restrict__ ae2,
                       const float* __restrict__ te2,
                       float* wd_as1, unsigned* veP1, float* t_a1,
                       float* wd_as2, unsigned* veP2, float* t_a2){
  __shared__ float sve[16*HH];
  int L=blockIdx.x;
  const float* Wd=L?Wd2:Wd1; const float* as_=L?as2:as1;
  const float* We=L?We2:We1; const float* ae=L?ae2:ae1; const float* te=L?te2:te1;
  float* wd_as=L?wd_as2:wd_as1; unsigned* veP=L?veP2:veP1; float* t_a=L?t_a2:t_a1;
  int t=threadIdx.x;
  for(int idx=t; idx<DD*HH; idx+=256){
    int k=idx>>3, h=idx&7;
    const float* w=&Wd[k*DD+h*CC]; const float* a=&as_[h*CC];
    float s=0;
    #pragma unroll
    for(int c=0;c<CC;c++) s+=w[c]*a[c];
    wd_as[idx]=s;
  }
  for(int idx=t; idx<16*HH; idx+=256){
    int k=idx>>3, h=idx&7;
    const float* w=&We[k*DD+h*CC]; const float* a=&ae[h*CC];
    float s=0;
    #pragma unroll
    for(int c=0;c<CC;c++) s+=w[c]*a[c];
    sve[idx]=s;
  }
  for(int idx=t; idx<7*HH; idx+=256){
    int k=idx>>3, h=idx&7;
    const float* w=&te[k*DD+h*CC]; const float* a=&ae[h*CC];
    float s=0;
    #pragma unroll
    for(int c=0;c<CC;c++) s+=w[c]*a[c];
    t_a[idx]=s;
  }
  __syncthreads();
  if(t<64){
    int h=t>>3, j=t&7;
    union { h2 h; unsigned u; } cv;
    cv.h[0]=(_Float16)sve[(2*j)*HH+h];
    cv.h[1]=(_Float16)sve[(2*j+1)*HH+h];
    veP[h*8+j]=cv.u;
  }
}

// ---------------- x -> bf16 + a_i (wave-per-row, float4, shuffle reduce) ----------------
#define NB_BA 1024
__global__ __launch_bounds__(256) void k_cvt_x2(const float* __restrict__ xin, const float* __restrict__ wd_as,
                         unsigned short* __restrict__ xb, float* __restrict__ a_i, int N){
  int b=blockIdx.x, tid=threadIdx.x, wv=tid>>6, l=tid&63;
  int c0=4*l;
  float wa[4][8];
  #pragma unroll
  for(int j=0;j<4;j++)
    #pragma unroll
    for(int h=0;h<8;h++) wa[j][h]=wd_as[(c0+j)*8+h];
  for(int n=b*4+wv; n<N; n+=NB_BA*4){
    float4 v=*(const float4*)&xin[(size_t)n*DD+c0];
    ushort4 xo; xo.x=f2b(v.x); xo.y=f2b(v.y); xo.z=f2b(v.z); xo.w=f2b(v.w);
    *(ushort4*)&xb[(size_t)n*DD+c0]=xo;
    float ai[8];
    #pragma unroll
    for(int h=0;h<8;h++) ai[h]=v.x*wa[0][h]+v.y*wa[1][h]+v.z*wa[2][h]+v.w*wa[3][h];
    #pragma unroll
    for(int off=1;off<64;off<<=1){
      #pragma unroll
      for(int h=0;h<8;h++) ai[h]+=__shfl_xor(ai[h],off);
    }
    if(l==0){
      float4 A; A.x=ai[0];A.y=ai[1];A.z=ai[2];A.w=ai[3];
      float4 B; B.x=ai[4];B.y=ai[5];B.z=ai[6];B.w=ai[7];
      *(float4*)&a_i[(size_t)n*HH]=A;
      *(float4*)&a_i[(size_t)n*HH+4]=B;
    }
  }
}

// ---------------- GEMM1: C[N,256]=A@B, f16 out (ysb feeds k_agg only) + fused a_j ----------------
template<bool AJ>
__global__ __launch_bounds__(256) void k_gemm1(const unsigned short* __restrict__ A,
                                               const unsigned short* __restrict__ Bt,
                                               const float* __restrict__ ad, float* __restrict__ a_j,
                                               unsigned short* __restrict__ Cout, int N){
  __shared__ char lds[2*12288];   // per buf: A 64x32 (4KB) + B 128x32 (8KB)
  int tid=threadIdx.x;
  int w=tid>>6, l=tid&63;
  int row0=blockIdx.y*64, col0=blockIdx.x*128;

  int lr=l>>2;
  int kc=(l&3)^((l>>3)&3);
  const unsigned short* ga  = &A [(size_t)(row0+16*w+lr)*DD + kc*8];
  const unsigned short* gb0 = &Bt[(size_t)(col0+32*w+lr)*DD + kc*8];
  const unsigned short* gb1 = &Bt[(size_t)(col0+32*w+16+lr)*DD + kc*8];
  int laoff =      w*1024;
  int lboff0=4096+(32*w)*64;
  int lboff1=4096+(32*w+16)*64;

  int x15=l&15;
  int lp=x15*64 + ((l>>4)^((x15>>1)&3))*16;

  f32x4 acc[4][2];
  #pragma unroll
  for(int i=0;i<4;i++){ acc[i][0]=(f32x4)0.f; acc[i][1]=(f32x4)0.f; }

  gload16(ga,  lds+laoff);
  gload16(gb0, lds+lboff0);
  gload16(gb1, lds+lboff1);
  __syncthreads();
  int cur=0;
  for(int kt=0;kt<DD;kt+=32){
    int nxt=cur^1;
    if(kt+32<DD){
      gload16(ga +kt+32, lds+nxt*12288+laoff);
      gload16(gb0+kt+32, lds+nxt*12288+lboff0);
      gload16(gb1+kt+32, lds+nxt*12288+lboff1);
    }
    char* base=lds+cur*12288;
    short8 af[4], bf[2];
    #pragma unroll
    for(int mf=0;mf<4;mf++) af[mf]=*(short8*)(base + mf*1024 + lp);
    #pragma unroll
    for(int nf=0;nf<2;nf++) bf[nf]=*(short8*)(base + 4096 + (32*w+16*nf)*64 + lp);
    #pragma unroll
    for(int mf=0;mf<4;mf++)
      #pragma unroll
      for(int nf=0;nf<2;nf++)
        acc[mf][nf]=__builtin_amdgcn_mfma_f32_16x16x32_bf16(af[mf],bf[nf],acc[mf][nf],0,0,0);
    __syncthreads();
    cur=nxt;
  }

  int lcol=x15, lrow4=(l>>4)*4;
  float ad0=0.f, ad1=0.f;
  if(AJ){ ad0=ad[col0+32*w+lcol]; ad1=ad[col0+32*w+16+lcol]; }
  int head=(col0>>5)+w;
  #pragma unroll
  for(int mf=0;mf<4;mf++){
    #pragma unroll
    for(int nf=0;nf<2;nf++){
      int col=col0 + 32*w + 16*nf + lcol;
      #pragma unroll
      for(int rr=0;rr<4;rr++){
        int row=row0 + 16*mf + lrow4 + rr;
        if(row<N) Cout[(size_t)row*DD+col]=(unsigned short)f2h_bits(acc[mf][nf][rr]);
      }
    }
    if(AJ){
      #pragma unroll
      for(int rr=0;rr<4;rr++){
        float t=acc[mf][0][rr]*ad0 + acc[mf][1][rr]*ad1;
        t+=__shfl_xor(t,1); t+=__shfl_xor(t,2);
        t+=__shfl_xor(t,4); t+=__shfl_xor(t,8);
        int row=row0 + 16*mf + lrow4 + rr;
        if(x15==0 && row<N) a_j[(size_t)row*HH+head]=t;
      }
    }
  }
}

// ---------------- GEMM2 fused: bias + LayerNorm + residual + BN partials --------
// RESBF16: residual stream is bf16 (layer 2 uses xb written by layer-1 bnapply).
template<bool RESBF16>
__global__ __launch_bounds__(256) void k_gemm_ln(const unsigned short* __restrict__ A,
                                                 const unsigned short* __restrict__ Bt,
                                                 const float* __restrict__ bo, const float* __restrict__ bvec,
                                                 const void* __restrict__ xin,
                                                 const float* __restrict__ lg, const float* __restrict__ lb,
                                                 float* __restrict__ hout,
                                                 float* __restrict__ psum, float* __restrict__ psq, int N){
  __shared__ char lds[2*18432];   // per buf: A 32x32 (2KB) + B 256x32 (16KB)
  int tid=threadIdx.x;
  int w=tid>>6, l=tid&63;
  int row0=blockIdx.x*32;

  int lr=l>>2;
  int kc=(l&3)^((l>>3)&3);
  const unsigned short* ga = &A[(size_t)(row0+16*w+lr)*DD + kc*8];   // waves 0,1 only
  const unsigned short* gb0=&Bt[(size_t)(64*w   +lr)*DD + kc*8];
  const unsigned short* gb1=&Bt[(size_t)(64*w+16+lr)*DD + kc*8];
  const unsigned short* gb2=&Bt[(size_t)(64*w+32+lr)*DD + kc*8];
  const unsigned short* gb3=&Bt[(size_t)(64*w+48+lr)*DD + kc*8];
  int laoff =      w*1024;
  int lboff0=2048+(64*w   )*64;
  int lboff1=2048+(64*w+16)*64;
  int lboff2=2048+(64*w+32)*64;
  int lboff3=2048+(64*w+48)*64;

  int x15=l&15;
  int lp=x15*64 + ((l>>4)^((x15>>1)&3))*16;

  f32x4 acc[2][4];
  #pragma unroll
  for(int i=0;i<2;i++)
    #pragma unroll
    for(int j=0;j<4;j++) acc[i][j]=(f32x4)0.f;

  if(w<2) gload16(ga, lds+laoff);
  gload16(gb0, lds+lboff0);
  gload16(gb1, lds+lboff1);
  gload16(gb2, lds+lboff2);
  gload16(gb3, lds+lboff3);
  __syncthreads();
  int cur=0;
  for(int kt=0;kt<DD;kt+=32){
    int nxt=cur^1;
    if(kt+32<DD){
      char* nb=lds+nxt*18432;
      if(w<2) gload16(ga+kt+32, nb+laoff);
      gload16(gb0+kt+32, nb+lboff0);
      gload16(gb1+kt+32, nb+lboff1);
      gload16(gb2+kt+32, nb+lboff2);
      gload16(gb3+kt+32, nb+lboff3);
    }
    char* base=lds+cur*18432;
    short8 af[2], bf[4];
    #pragma unroll
    for(int mf=0;mf<2;mf++) af[mf]=*(short8*)(base + mf*1024 + lp);
    #pragma unroll
    for(int nf=0;nf<4;nf++) bf[nf]=*(short8*)(base + 2048 + (64*w+16*nf)*64 + lp);
    #pragma unroll
    for(int mf=0;mf<2;mf++)
      #pragma unroll
      for(int nf=0;nf<4;nf++)
        acc[mf][nf]=__builtin_amdgcn_mfma_f32_16x16x32_bf16(af[mf],bf[nf],acc[mf][nf],0,0,0);
    __syncthreads();
    cur=nxt;
  }

  // ---- epilogue ----
  int lrow4=(l>>4)*4;
  float lgv[4], lbv[4];
  #pragma unroll
  for(int nf=0;nf<4;nf++){
    int col=64*w+16*nf+x15;
    float badd=bo[col]+bvec[col];
    lgv[nf]=lg[col]; lbv[nf]=lb[col];
    #pragma unroll
    for(int mf=0;mf<2;mf++)
      #pragma unroll
      for(int rr=0;rr<4;rr++) acc[mf][nf][rr]+=badd;
  }
  __syncthreads();   // GEMM LDS dead; repurpose
  float* rs   =(float*)lds;            // [4][32]
  float* rq   =(float*)(lds+512);      // [4][32]
  float* mus  =(float*)(lds+1024);     // [32]
  float* rstds=(float*)(lds+1152);     // [32]
  #pragma unroll
  for(int mf=0;mf<2;mf++){
    #pragma unroll
    for(int rr=0;rr<4;rr++){
      float t=acc[mf][0][rr]+acc[mf][1][rr]+acc[mf][2][rr]+acc[mf][3][rr];
      float q=acc[mf][0][rr]*acc[mf][0][rr]+acc[mf][1][rr]*acc[mf][1][rr]
             +acc[mf][2][rr]*acc[mf][2][rr]+acc[mf][3][rr]*acc[mf][3][rr];
      t+=__shfl_xor(t,1); q+=__shfl_xor(q,1);
      t+=__shfl_xor(t,2); q+=__shfl_xor(q,2);
      t+=__shfl_xor(t,4); q+=__shfl_xor(q,4);
      t+=__shfl_xor(t,8); q+=__shfl_xor(q,8);
      if(x15==0){
        int row=16*mf+lrow4+rr;
        rs[w*32+row]=t; rq[w*32+row]=q;
      }
    }
  }
  __syncthreads();
  if(tid<32){
    float S=rs[tid]+rs[32+tid]+rs[64+tid]+rs[96+tid];
    float Q=rq[tid]+rq[32+tid]+rq[64+tid]+rq[96+tid];
    float mu=S*(1.f/DD);
    float var=Q*(1.f/DD)-mu*mu;
    mus[tid]=mu;
    rstds[tid]=rsqrtf(var+1e-5f);
  }
  __syncthreads();
  float cps[4]={0.f,0.f,0.f,0.f}, cqs[4]={0.f,0.f,0.f,0.f};
  #pragma unroll
  for(int mf=0;mf<2;mf++){
    #pragma unroll
    for(int rr=0;rr<4;rr++){
      int row=16*mf+lrow4+rr;
      int grow=row0+row;
      bool ok=(grow<N);
      float mu=mus[row], rstd=rstds[row];
      #pragma unroll
      for(int nf=0;nf<4;nf++){
        int col=64*w+16*nf+x15;
        float h=0.f;
        if(ok){
          float r = RESBF16 ? b2f(((const unsigned short*)xin)[(size_t)grow*DD+col])
                            : ((const float*)xin)[(size_t)grow*DD+col];
          h=(acc[mf][nf][rr]-mu)*rstd*lgv[nf]+lbv[nf]+r;
          hout[(size_t)grow*DD+col]=h;
        }
        cps[nf]+=h; cqs[nf]+=h*h;
      }
    }
  }
  #pragma unroll
  for(int nf=0;nf<4;nf++){
    cps[nf]+=__shfl_xor(cps[nf],16); cqs[nf]+=__shfl_xor(cqs[nf],16);
    cps[nf]+=__shfl_xor(cps[nf],32); cqs[nf]+=__shfl_xor(cqs[nf],32);
  }
  if(l<16){
    #pragma unroll
    for(int nf=0;nf<4;nf++){
      int col=64*w+16*nf+l;
      psum[(size_t)blockIdx.x*DD+col]=cps[nf];
      psq [(size_t)blockIdx.x*DD+col]=cqs[nf];
    }
  }
}

// ---------------- FUSED edge-logit + online softmax + aggregation ----------------
// ONE WAVE PER BLOCK. Metadata + ysb rows prefetched one chunk ahead. f16 dot2
// logits; f16 gather rows (fma_mix-able); T13 defer-max rescale (threshold 8).
__global__ __launch_bounds__(64) void k_agg(const int* __restrict__ row_off,
                      const int* __restrict__ stP, const unsigned short* __restrict__ eaPh,
                      const float* __restrict__ a_i, const float* __restrict__ a_j,
                      const unsigned* __restrict__ veP, const float* __restrict__ t_a,
                      const unsigned short* __restrict__ ysh, unsigned short* __restrict__ aggb, int N){
  int l=threadIdx.x;
  int n=blockIdx.x;
  if(n>=N) return;
  int beg=row_off[n], deg=row_off[n+1]-beg;
  int slotL=l>>3, headL=l&7;
  int half=l>>5, lk=l&31;
  int hh=lk>>2;
  h2 vehp[8];
  #pragma unroll
  for(int k=0;k<8;k++){
    union { unsigned u; h2 h; } cv; cv.u=veP[headL*8+k]; vehp[k]=cv.h;
  }
  float aih=a_i[(size_t)n*HH+headL];
  float m=-3e38f, ssum=0.f;
  float acc[8];
  #pragma unroll
  for(int j=0;j<8;j++) acc[j]=0.f;

  // prefetch chunk 0: metadata + gather rows (deg>=1: self-loop; clamped idx valid)
  int ic0 = (slotL<deg)? slotL : (deg-1);
  size_t pos0=(size_t)(beg+ic0);
  int st_c = stP[pos0];
  short8 e0_c=*(const short8*)&eaPh[pos0*16];
  short8 e1_c=*(const short8*)&eaPh[pos0*16+8];
  float aj_c = a_j[(size_t)(st_c&0xFFFFFF)*HH+headL];
  short8 ybuf_c[4];
  {
    int src0 = st_c & 0xFFFFFF;
    #pragma unroll
    for(int u=0;u<4;u++){
      int si=__shfl(src0,((2*u+half)<<3));
      ybuf_c[u]=*(const short8*)&ysh[(size_t)si*DD+8*lk];
    }
  }

  for(int base=0;base<deg;base+=8){
    bool ok=(base+slotL)<deg;
    // prefetch next chunk: metadata + gather rows (addresses from st_n)
    int in_=base+8+slotL;
    int icn=(in_<deg)? in_ : (deg-1);
    size_t posn=(size_t)(beg+icn);
    int st_n = stP[posn];
    short8 e0_n=*(const short8*)&eaPh[posn*16];
    short8 e1_n=*(const short8*)&eaPh[posn*16+8];
    float aj_n = a_j[(size_t)(st_n&0xFFFFFF)*HH+headL];
    int src_n = st_n & 0xFFFFFF;
    short8 ybuf_n[4];
    #pragma unroll
    for(int u=0;u<4;u++){
      int si=__shfl(src_n,((2*u+half)<<3));
      ybuf_n[u]=*(const short8*)&ysh[(size_t)si*DD+8*lk];
    }
    // logit for current chunk: f16 dot2 pairs, f32 accumulate
    int src = st_c & 0xFFFFFF;
    int ty  = ((unsigned)st_c) >> 24;
    float t = aih + aj_c + t_a[ty*8+headL];
    {
      union { short8 s; h2 h[4]; } u0, u1;
      u0.s=e0_c; u1.s=e1_c;
      #pragma unroll
      for(int j=0;j<4;j++) t=__builtin_amdgcn_fdot2(u0.h[j],vehp[j],t,false);
      #pragma unroll
      for(int j=0;j<4;j++) t=__builtin_amdgcn_fdot2(u1.h[j],vehp[4+j],t,false);
    }
    t=(t>=0.f)? t : 0.2f*t;
    float v = ok ? t : -3e38f;
    // per-head chunk max (butterfly over slot bits); uniform exec
    float cm=v;
    cm=fmaxf(cm,__shfl_xor(cm,8));
    cm=fmaxf(cm,__shfl_xor(cm,16));
    cm=fmaxf(cm,__shfl_xor(cm,32));
    float cmg=__shfl(cm,hh);
    // T13 defer-max: only rescale when some head's max grew beyond threshold 8.
    // Weights then bounded by e^8 (~3e3); f32 state tolerates; final normalize exact.
    if(__any((cmg - m) > 8.f)){
      float mnew=fmaxf(m,cmg);
      float f=__expf(m-mnew);          // first chunk: exp(-inf)=0, state already 0
      ssum*=f;
      #pragma unroll
      for(int j=0;j<8;j++) acc[j]*=f;
      m=mnew;
    }
    int cnt=min(8,deg-base);
    // weights via shuffles (uniform), then FMA tail on prefetched f16 rows
    float vus[4];
    #pragma unroll
    for(int u=0;u<4;u++){
      int e=2*u+half;
      vus[u]=__shfl(v,(e<<3)|hh);
    }
    #pragma unroll
    for(int u=0;u<4;u++){
      int e=2*u+half;
      if(e<cnt){
        float wgt=__expf(vus[u]-m);
        ssum+=wgt;
        #pragma unroll
        for(int j=0;j<8;j++) acc[j]+=wgt*h2f((unsigned short)ybuf_c[u][j]);
      }
    }
    st_c=st_n; e0_c=e0_n; e1_c=e1_n; aj_c=aj_n;
    #pragma unroll
    for(int u=0;u<4;u++) ybuf_c[u]=ybuf_n[u];
  }
  // merge halves (same m on both -> plain add); uniform exec
  ssum+=__shfl_xor(ssum,32);
  #pragma unroll
  for(int j=0;j<8;j++) acc[j]+=__shfl_xor(acc[j],32);
  if(half==0){
    float inv=1.f/(ssum+1e-16f);
    short8 o;
    #pragma unroll
    for(int j=0;j<8;j++) o[j]=(short)f2b(acc[j]*inv);
    *(short8*)&aggb[(size_t)n*DD+8*lk]=o;
  }
}

// ---------------- BN finalize from nb per-block partials: one block PER COLUMN ----------------
__global__ __launch_bounds__(256) void k_bnfin(const float* __restrict__ psum, const float* __restrict__ psq,
                        const float* __restrict__ g, const float* __restrict__ b,
                        float* scale, float* shift, int N, int nb){
  __shared__ float rs[256], rq[256];
  int c=blockIdx.x, tid=threadIdx.x;
  float s=0.f,q=0.f;
  for(int i=tid;i<nb;i+=256){ s+=psum[(size_t)i*DD+c]; q+=psq[(size_t)i*DD+c]; }
  rs[tid]=s; rq[tid]=q;
  __syncthreads();
  #pragma unroll
  for(int off=128;off>0;off>>=1){
    if(tid<off){ rs[tid]+=rs[tid+off]; rq[tid]+=rq[tid+off]; }
    __syncthreads();
  }
  if(tid==0){
    float inv=1.f/(float)N;
    float mu=rs[0]*inv;
    float var=rq[0]*inv - mu*mu;
    float sc=g[c]*rsqrtf(var+1e-5f);
    scale[c]=sc;
    shift[c]=b[c]-mu*sc;
  }
}

// out = relu(h*scale + shift [+ res]); wave-per-row, float4, shuffle-reduced a_i.
// WOUT: write f32 output stream; CVT: write bf16 copy + next-layer a_i.
template<bool RES, bool CVT, bool WOUT>
__global__ __launch_bounds__(256) void k_bnapply(const float* __restrict__ hm, const float* __restrict__ scale,
                          const float* __restrict__ shift, const float* __restrict__ res,
                          float* __restrict__ outp, unsigned short* __restrict__ xb,
                          const float* __restrict__ wd_as, float* __restrict__ a_i, int N){
  int b=blockIdx.x, tid=threadIdx.x, wv=tid>>6, l=tid&63;
  int c0=4*l;
  float4 sc=*(const float4*)&scale[c0];
  float4 sh=*(const float4*)&shift[c0];
  float wa[4][8];
  if(CVT){
    #pragma unroll
    for(int j=0;j<4;j++)
      #pragma unroll
      for(int h=0;h<8;h++) wa[j][h]=wd_as[(c0+j)*8+h];
  }
  for(int n=b*4+wv; n<N; n+=NB_BA*4){
    float4 v=*(const float4*)&hm[(size_t)n*DD+c0];
    v.x=v.x*sc.x+sh.x; v.y=v.y*sc.y+sh.y; v.z=v.z*sc.z+sh.z; v.w=v.w*sc.w+sh.w;
    if(RES){
      float4 rr=*(const float4*)&res[(size_t)n*DD+c0];
      v.x+=rr.x; v.y+=rr.y; v.z+=rr.z; v.w+=rr.w;
    }
    v.x=fmaxf(v.x,0.f); v.y=fmaxf(v.y,0.f); v.z=fmaxf(v.z,0.f); v.w=fmaxf(v.w,0.f);
    if(WOUT) *(float4*)&outp[(size_t)n*DD+c0]=v;
    if(CVT){
      ushort4 xo; xo.x=f2b(v.x); xo.y=f2b(v.y); xo.z=f2b(v.z); xo.w=f2b(v.w);
      *(ushort4*)&xb[(size_t)n*DD+c0]=xo;
      float ai[8];
      #pragma unroll
      for(int h=0;h<8;h++) ai[h]=v.x*wa[0][h]+v.y*wa[1][h]+v.z*wa[2][h]+v.w*wa[3][h];
      #pragma unroll
      for(int off=1;off<64;off<<=1){
        #pragma unroll
        for(int h=0;h<8;h++) ai[h]+=__shfl_xor(ai[h],off);
      }
      if(l==0){
        float4 A; A.x=ai[0];A.y=ai[1];A.z=ai[2];A.w=ai[3];
        float4 B; B.x=ai[4];B.y=ai[5];B.z=ai[6];B.w=ai[7];
        *(float4*)&a_i[(size_t)n*HH]=A;
        *(float4*)&a_i[(size_t)n*HH+4]=B;
      }
    }
  }
}

extern "C" void kernel_launch(void* const* d_in, const int* in_sizes, int n_in,
                              void* d_out, int out_size, void* d_ws, size_t ws_size,
                              hipStream_t stream) {
  const float* x  = (const float*)d_in[0];
  const int*   ei = (const int*)d_in[1];
  const float* ea = (const float*)d_in[2];
  const int*   et = (const int*)d_in[3];
  int N = in_sizes[0]/DD;
  int E = in_sizes[3];
  int Etot = E+N;
  const int* srcE = ei;
  const int* dstE = ei + E;

  const float* Ws1=(const float*)d_in[4];  const float* Wd1=(const float*)d_in[5];
  const float* as1=(const float*)d_in[6];  const float* ad1=(const float*)d_in[7];
  const float* We1=(const float*)d_in[8];  const float* ae1=(const float*)d_in[9];
  const float* te1=(const float*)d_in[10]; const float* Wo1=(const float*)d_in[11];
  const float* bo1=(const float*)d_in[12]; const float* b1 =(const float*)d_in[13];
  const float* lg1=(const float*)d_in[14]; const float* lb1=(const float*)d_in[15];
  const float* Ws2=(const float*)d_in[16]; const float* Wd2=(const float*)d_in[17];
  const float* as2=(const float*)d_in[18]; const float* ad2=(const float*)d_in[19];
  const float* We2=(const float*)d_in[20]; const float* ae2=(const float*)d_in[21];
  const float* te2=(const float*)d_in[22]; const float* Wo2=(const float*)d_in[23];
  const float* bo2=(const float*)d_in[24]; const float* b2 =(const float*)d_in[25];
  const float* lg2=(const float*)d_in[26]; const float* lb2=(const float*)d_in[27];
  const float* bng1=(const float*)d_in[28]; const float* bnb1=(const float*)d_in[29];
  const float* bng2=(const float*)d_in[30]; const float* bnb2=(const float*)d_in[31];

  char* p=(char*)d_ws;
  auto alloc=[&](size_t bytes)->void*{ void* r=(void*)p; p+=(bytes+255)&~(size_t)255; return r; };
  unsigned short* xb   =(unsigned short*)alloc((size_t)N*DD*2);
  unsigned short* ysh  =(unsigned short*)alloc((size_t)N*DD*2);
  unsigned short* aggb =(unsigned short*)alloc((size_t)N*DD*2);
  unsigned short* eaPh =(unsigned short*)alloc((size_t)Etot*16*2);
  int*   stP   =(int*)alloc((size_t)Etot*4);
  float* a_i   =(float*)alloc((size_t)N*HH*4);
  float* a_j   =(float*)alloc((size_t)N*HH*4);
  float* wd_as1=(float*)alloc(DD*HH*4);
  unsigned* veP1=(unsigned*)alloc(64*4);
  float* t_a1  =(float*)alloc(7*HH*4);
  float* wd_as2=(float*)alloc(DD*HH*4);
  unsigned* veP2=(unsigned*)alloc(64*4);
  float* t_a2  =(float*)alloc(7*HH*4);
  int nbLN=(N+31)/32;
  float* psum  =(float*)alloc((size_t)nbLN*DD*4);
  float* psq   =(float*)alloc((size_t)nbLN*DD*4);
  float* scl   =(float*)alloc(256*4);
  float* shf   =(float*)alloc(256*4);
  unsigned short* Wsb1T=(unsigned short*)alloc((size_t)DD*DD*2);
  unsigned short* Wob1T=(unsigned short*)alloc((size_t)DD*DD*2);
  unsigned short* Wsb2T=(unsigned short*)alloc((size_t)DD*DD*2);
  unsigned short* Wob2T=(unsigned short*)alloc((size_t)DD*DD*2);
  int* cnt     =(int*)alloc((size_t)N*4);
  int* row_off =(int*)alloc((size_t)(N+1)*4);
  int* cursor  =(int*)alloc((size_t)N*4);
  float* hbuf  =(float*)d_out;

  dim3 gg(2,(N+63)/64);

  // upfront: CSR (with packed+f16 edge data) + weight prep (both layers)
  hipMemsetAsync(cnt, 0, (size_t)N*4, stream);
  k_count<<<(Etot+255)/256,256,0,stream>>>(dstE,E,N,cnt);
  k_scan<<<1,1024,0,stream>>>(cnt,N,row_off,cursor);
  k_fill<<<(Etot+255)/256,256,0,stream>>>(srcE,dstE,ea,et,E,N,cursor,stP,eaPh);
  k_cvt_wT4<<<dim3(DD,4),DD,0,stream>>>(Ws1,Wo1,Ws2,Wo2,Wsb1T,Wob1T,Wsb2T,Wob2T);
  k_pre2<<<2,256,0,stream>>>(Wd1,as1,We1,ae1,te1,Wd2,as2,We2,ae2,te2,
                             wd_as1,veP1,t_a1,wd_as2,veP2,t_a2);

  // ---- layer 1 ----
  k_cvt_x2<<<NB_BA,256,0,stream>>>(x,wd_as1,xb,a_i,N);
  k_gemm1<true><<<gg,256,0,stream>>>(xb,Wsb1T,ad1,a_j,ysh,N);
  k_agg<<<N,64,0,stream>>>(row_off,stP,eaPh,a_i,a_j,veP1,t_a1,ysh,aggb,N);
  k_gemm_ln<false><<<nbLN,256,0,stream>>>(aggb,Wob1T,bo1,b1,(const void*)x,lg1,lb1,hbuf,psum,psq,N);
  k_bnfin<<<DD,256,0,stream>>>(psum,psq,bng1,bnb1,scl,shf,N,nbLN);
  // layer-1 BN apply: bf16 copy (xb) + next-layer a_i only; no f32 output stream
  k_bnapply<false,true,false><<<NB_BA,256,0,stream>>>(hbuf,scl,shf,nullptr,nullptr,xb,wd_as2,a_i,N);

  // ---- layer 2 (residual = xb, bf16) ----
  k_gemm1<true><<<gg,256,0,stream>>>(xb,Wsb2T,ad2,a_j,ysh,N);
  k_agg<<<N,64,0,stream>>>(row_off,stP,eaPh,a_i,a_j,veP2,t_a2,ysh,aggb,N);
  k_gemm_ln<true><<<nbLN,256,0,stream>>>(aggb,Wob2T,bo2,b2,(const void*)xb,lg2,lb2,hbuf,psum,psq,N);
  k_bnfin<<<DD,256,0,stream>>>(psum,psq,bng2,bnb2,scl,shf,N,nbLN);
  k_bnapply<true,false,true><<<NB_BA,256,0,stream>>>(hbuf,scl,shf,x,(float*)d_out,nullptr,nullptr,nullptr,N);
}